// Round 1
// 6768.172 us; speedup vs baseline: 1.0338x; 1.0338x over previous
//
#include <hip/hip_runtime.h>
#include <hip/hip_bf16.h>
#include <math.h>

// ---------------------------------------------------------------------------
// DeepMonocularModel — r5:
//  * attention restructured for q-seq-len==1: K/V projections folded into
//    qw = Q·wk^T (per head) and o = (att·tokens)·wv + bv  (Σatt = 1).
//    Removes 8 large MFMA GEMMs + 8 transposes + 100MB K/V buffers per iter.
//  * chunked XCD swizzle on mfma_gemm_k (A-panel L2 reuse for the convs).
// ---------------------------------------------------------------------------

#define NB   32
#define ND   768
#define NTOK 1024
#define NKH  8
#define NHD  96
#define NL   4
#define NMLP 3072
#define NK   50
#define NT   30

typedef short  s8v __attribute__((ext_vector_type(8)));
typedef float  f4v __attribute__((ext_vector_type(4)));

__device__ __forceinline__ float gelu_f(float x) {
    return 0.5f * x * (1.0f + erff(x * 0.70710678118654752f));
}
__device__ __forceinline__ float softplus_f(float x) {
    return x > 0.f ? x + log1pf(expf(-x)) : log1pf(expf(x));
}
__device__ __forceinline__ float bf2f(unsigned short u) {
    unsigned int x = ((unsigned int)u) << 16;
    union { unsigned int i; float f; } c; c.i = x;
    return c.f;
}
__device__ __forceinline__ void gld_lds16(const void* g, void* l) {
    __builtin_amdgcn_global_load_lds(
        (const __attribute__((address_space(1))) void*)g,
        (__attribute__((address_space(3))) void*)l, 16, 0, 0);
}

// ---------------------------------------------------------------------------
// bf16 MFMA GEMM, 128x128 tile. C = act(A_view @ Bt^T + bias)
// AMODE 0: A plain bf16 [*][K]
// AMODE 1: A padded NHWC bf16 [b][34][34][768], 3x3 conv, K = tap*768+ci
// OUT 0: fp32 Cf | OUT 1: bf16 padded NHWC | OUT 2: bf16 plain
// OUT 3: conv2 special — bf16 padded NHWC feats + bf16 tokens w/ +pos
// Chunked XCD swizzle applied when gridsize % 8 == 0 (conv grids: 1536).
// ---------------------------------------------------------------------------
template<int AMODE, int ACT, int OUT>
__global__ __launch_bounds__(256) void mfma_gemm_k(
    const __hip_bfloat16* __restrict__ A,
    const __hip_bfloat16* __restrict__ Bt,
    const float* __restrict__ bias,
    float* __restrict__ Cf,
    __hip_bfloat16* __restrict__ Cb,
    __hip_bfloat16* __restrict__ Cpad,
    const float* __restrict__ pos,
    int M, int N, int K)
{
    __shared__ __hip_bfloat16 As[128 * 32];
    __shared__ __hip_bfloat16 Bs[128 * 32];
    const int tid  = threadIdx.x;
    const int lane = tid & 63;
    const int wave = tid >> 6;
    const int wm = wave >> 1, wn = wave & 1;
    // chunked XCD swizzle: consecutive dispatch ids (same XCD residency class)
    // map to consecutive tile ids -> the 6 n-tiles of one m-panel share an L2.
    int bxi = blockIdx.x, byi = blockIdx.y;
    {
        const int nbx = gridDim.x;
        const int nwg = nbx * gridDim.y;
        if ((nwg & 7) == 0) {
            int id = byi * nbx + bxi;
            const int cpx = nwg >> 3;
            id = (id & 7) * cpx + (id >> 3);
            bxi = id % nbx; byi = id / nbx;
        }
    }
    const int bm = byi * 128, bn = bxi * 128;
    const int r0 = tid >> 2;
    const int kb = (tid & 3) * 8;

    f4v acc[4][4];
#pragma unroll
    for (int i = 0; i < 4; i++)
#pragma unroll
        for (int j = 0; j < 4; j++) acc[i][j] = (f4v)0.f;

    int rr = 0, kin = 0;
    for (int k0 = 0; k0 < K; k0 += 32) {
#pragma unroll
        for (int c = 0; c < 2; c++) {
            const int row = r0 + c * 64;
            const __hip_bfloat16* ga;
            if constexpr (AMODE == 0) {
                ga = A + (size_t)(bm + row) * K + k0 + kb;
            } else {
                int gm = bm + row;
                int b = gm >> 10, y = (gm >> 5) & 31, x = gm & 31;
                int dy = rr / 3, dx = rr - dy * 3;
                ga = A + ((((size_t)b * 34 + y + dy) * 34 + (x + dx)) * 768 + kin + kb);
            }
            gld_lds16(ga, &As[row * 32 + kb]);
        }
#pragma unroll
        for (int c = 0; c < 2; c++) {
            const int row = r0 + c * 64;
            gld_lds16(Bt + (size_t)(bn + row) * K + k0 + kb, &Bs[row * 32 + kb]);
        }
        __syncthreads();
        const int koff = (lane >> 4) * 8;
        s8v af[4], bfv[4];
#pragma unroll
        for (int i = 0; i < 4; i++)
            af[i] = *(const s8v*)(&As[(wm * 64 + i * 16 + (lane & 15)) * 32 + koff]);
#pragma unroll
        for (int j = 0; j < 4; j++)
            bfv[j] = *(const s8v*)(&Bs[(wn * 64 + j * 16 + (lane & 15)) * 32 + koff]);
#pragma unroll
        for (int i = 0; i < 4; i++)
#pragma unroll
            for (int j = 0; j < 4; j++)
                acc[i][j] = __builtin_amdgcn_mfma_f32_16x16x32_bf16(af[i], bfv[j], acc[i][j], 0, 0, 0);
        __syncthreads();
        if constexpr (AMODE == 1) { kin += 32; if (kin == 768) { kin = 0; rr++; } }
    }
#pragma unroll
    for (int i = 0; i < 4; i++) {
        const int mbase = bm + wm * 64 + i * 16 + ((lane >> 4) << 2);
#pragma unroll
        for (int j = 0; j < 4; j++) {
            const int n = bn + wn * 64 + j * 16 + (lane & 15);
            const float bs = bias[n];
#pragma unroll
            for (int g = 0; g < 4; g++) {
                const int m = mbase + g;
                if (m >= M) continue;
                float v = acc[i][j][g] + bs;
                if constexpr (ACT == 1) v = gelu_f(v);
                if constexpr (OUT == 0) {
                    Cf[(size_t)m * N + n] = v;
                } else if constexpr (OUT == 1) {
                    int b = m >> 10, y = (m >> 5) & 31, x = m & 31;
                    Cpad[(((size_t)b * 34 + y + 1) * 34 + (x + 1)) * 768 + n] =
                        __float2bfloat16(v);
                } else if constexpr (OUT == 2) {
                    Cb[(size_t)m * N + n] = __float2bfloat16(v);
                } else {
                    int b = m >> 10, y = (m >> 5) & 31, x = m & 31;
                    Cpad[(((size_t)b * 34 + y + 1) * 34 + (x + 1)) * 768 + n] =
                        __float2bfloat16(v);
                    Cb[(size_t)m * 768 + n] =
                        __float2bfloat16(v + pos[(size_t)(m & 1023) * 768 + n]);
                }
            }
        }
    }
}

// ---------------------------------------------------------------------------
// dg1: 3x3 conv 768->64, gelu, in/out padded bf16. Tile 128(M)x64(N).
// ---------------------------------------------------------------------------
__global__ __launch_bounds__(256) void mfma_dg1_k(
    const __hip_bfloat16* __restrict__ A,
    const __hip_bfloat16* __restrict__ Bt,
    const float* __restrict__ bias,
    __hip_bfloat16* __restrict__ Dpad)
{
    __shared__ __hip_bfloat16 As[128 * 32];
    __shared__ __hip_bfloat16 Bs[64 * 32];
    const int tid = threadIdx.x, lane = tid & 63, wave = tid >> 6;
    const int wm = wave >> 1, wn = wave & 1;
    const int bm = blockIdx.x * 128;
    const int r0 = tid >> 2, kb = (tid & 3) * 8;
    f4v acc[4][2];
#pragma unroll
    for (int i = 0; i < 4; i++)
#pragma unroll
        for (int j = 0; j < 2; j++) acc[i][j] = (f4v)0.f;

    int rr = 0, kin = 0;
    for (int k0 = 0; k0 < 6912; k0 += 32) {
#pragma unroll
        for (int c = 0; c < 2; c++) {
            const int row = r0 + c * 64;
            int gm = bm + row;
            int b = gm >> 10, y = (gm >> 5) & 31, x = gm & 31;
            int dy = rr / 3, dx = rr - dy * 3;
            gld_lds16(A + ((((size_t)b * 34 + y + dy) * 34 + (x + dx)) * 768 + kin + kb),
                      &As[row * 32 + kb]);
        }
        gld_lds16(Bt + (size_t)r0 * 6912 + k0 + kb, &Bs[r0 * 32 + kb]);
        __syncthreads();
        const int koff = (lane >> 4) * 8;
        s8v af[4], bfv[2];
#pragma unroll
        for (int i = 0; i < 4; i++)
            af[i] = *(const s8v*)(&As[(wm * 64 + i * 16 + (lane & 15)) * 32 + koff]);
#pragma unroll
        for (int j = 0; j < 2; j++)
            bfv[j] = *(const s8v*)(&Bs[(wn * 32 + j * 16 + (lane & 15)) * 32 + koff]);
#pragma unroll
        for (int i = 0; i < 4; i++)
#pragma unroll
            for (int j = 0; j < 2; j++)
                acc[i][j] = __builtin_amdgcn_mfma_f32_16x16x32_bf16(af[i], bfv[j], acc[i][j], 0, 0, 0);
        __syncthreads();
        kin += 32; if (kin == 768) { kin = 0; rr++; }
    }
#pragma unroll
    for (int i = 0; i < 4; i++) {
        const int mbase = bm + wm * 64 + i * 16 + ((lane >> 4) << 2);
#pragma unroll
        for (int j = 0; j < 2; j++) {
            const int n = wn * 32 + j * 16 + (lane & 15);
            const float bs = bias[n];
#pragma unroll
            for (int g = 0; g < 4; g++) {
                const int m = mbase + g;
                float v = gelu_f(acc[i][j][g] + bs);
                int b = m >> 10, y = (m >> 5) & 31, x = m & 31;
                Dpad[(((size_t)b * 34 + y + 1) * 34 + (x + 1)) * 64 + n] =
                    __float2bfloat16(v);
            }
        }
    }
}

// ---------------------------------------------------------------------------
// dg2: up2 + 3x3 conv 64->32, gelu. Tile 128(M)x32(N). Output 64x64/batch.
// ---------------------------------------------------------------------------
__global__ __launch_bounds__(256) void mfma_dg2_k(
    const __hip_bfloat16* __restrict__ A,
    const __hip_bfloat16* __restrict__ Bt,
    const float* __restrict__ bias,
    float* __restrict__ D)
{
    __shared__ __hip_bfloat16 As[128 * 32];
    __shared__ __hip_bfloat16 Bs[32 * 32];
    const int tid = threadIdx.x, lane = tid & 63, wave = tid >> 6;
    const int bm = blockIdx.x * 128;
    const int r0 = tid >> 2, kb = (tid & 3) * 8;
    f4v acc[2][2];
#pragma unroll
    for (int i = 0; i < 2; i++)
#pragma unroll
        for (int j = 0; j < 2; j++) acc[i][j] = (f4v)0.f;

    int rr = 0, kin = 0;
    for (int k0 = 0; k0 < 576; k0 += 32) {
#pragma unroll
        for (int c = 0; c < 2; c++) {
            const int row = r0 + c * 64;
            int gm = bm + row;
            int b = gm >> 12, y = (gm >> 6) & 63, x = gm & 63;
            int dy = rr / 3, dx = rr - dy * 3;
            int iy = (y + dy + 1) >> 1, ix = (x + dx + 1) >> 1;
            gld_lds16(A + (((size_t)b * 34 + iy) * 34 + ix) * 64 + kin + kb,
                      &As[row * 32 + kb]);
        }
        if (tid < 128)
            gld_lds16(Bt + (size_t)r0 * 576 + k0 + kb, &Bs[r0 * 32 + kb]);
        __syncthreads();
        const int koff = (lane >> 4) * 8;
        s8v af[2], bfv[2];
#pragma unroll
        for (int i = 0; i < 2; i++)
            af[i] = *(const s8v*)(&As[(wave * 32 + i * 16 + (lane & 15)) * 32 + koff]);
#pragma unroll
        for (int j = 0; j < 2; j++)
            bfv[j] = *(const s8v*)(&Bs[(j * 16 + (lane & 15)) * 32 + koff]);
#pragma unroll
        for (int i = 0; i < 2; i++)
#pragma unroll
            for (int j = 0; j < 2; j++)
                acc[i][j] = __builtin_amdgcn_mfma_f32_16x16x32_bf16(af[i], bfv[j], acc[i][j], 0, 0, 0);
        __syncthreads();
        kin += 32; if (kin == 64) { kin = 0; rr++; }
    }
#pragma unroll
    for (int i = 0; i < 2; i++) {
        const int mbase = bm + wave * 32 + i * 16 + ((lane >> 4) << 2);
#pragma unroll
        for (int j = 0; j < 2; j++) {
            const int n = j * 16 + (lane & 15);
            const float bs = bias[n];
#pragma unroll
            for (int g = 0; g < 4; g++) {
                const int m = mbase + g;
                D[(size_t)m * 32 + n] = gelu_f(acc[i][j][g] + bs);
            }
        }
    }
}

// NCHW fp32 -> padded NHWC bf16 interior
__global__ void nchw2pad_bf_k(const float* __restrict__ src, __hip_bfloat16* __restrict__ dst)
{
    __shared__ float tile[32][33];
    int b = blockIdx.z, n0 = blockIdx.y * 32, c0 = blockIdx.x * 32;
    int tx = threadIdx.x, ty = threadIdx.y;
#pragma unroll
    for (int i = ty; i < 32; i += 8)
        tile[i][tx] = src[((size_t)b * ND + c0 + i) * NTOK + n0 + tx];
    __syncthreads();
#pragma unroll
    for (int i = ty; i < 32; i += 8) {
        int n = n0 + i, y = n >> 5, x = n & 31;
        dst[(((size_t)b * 34 + y + 1) * 34 + (x + 1)) * 768 + c0 + tx] =
            __float2bfloat16(tile[tx][i]);
    }
}

// zero borders of two padded-768 bf16 buffers
__global__ void pad_border_k(__hip_bfloat16* __restrict__ p1, __hip_bfloat16* __restrict__ p2)
{
    int idx = blockIdx.x * 256 + threadIdx.x;
    if (idx >= 32 * 132 * 192) return;
    int c4 = idx % 192;
    int cell = (idx / 192) % 132;
    int b = idx / (192 * 132);
    int yy, xx;
    if      (cell < 34)  { yy = 0;  xx = cell; }
    else if (cell < 68)  { yy = 33; xx = cell - 34; }
    else if (cell < 100) { yy = cell - 68 + 1;  xx = 0; }
    else                 { yy = cell - 100 + 1; xx = 33; }
    size_t o = (((size_t)b * 34 + yy) * 34 + xx) * 768 + c4 * 4;
    *reinterpret_cast<uint2*>(p1 + o) = make_uint2(0u, 0u);
    *reinterpret_cast<uint2*>(p2 + o) = make_uint2(0u, 0u);
}

// zero border of padded-64 bf16 buffer
__global__ void pad_border64_k(__hip_bfloat16* __restrict__ p)
{
    int idx = blockIdx.x * 256 + threadIdx.x;
    if (idx >= 32 * 132 * 16) return;
    int c4 = idx % 16;
    int cell = (idx / 16) % 132;
    int b = idx / (16 * 132);
    int yy, xx;
    if      (cell < 34)  { yy = 0;  xx = cell; }
    else if (cell < 68)  { yy = 33; xx = cell - 34; }
    else if (cell < 100) { yy = cell - 68 + 1;  xx = 0; }
    else                 { yy = cell - 100 + 1; xx = 33; }
    size_t o = (((size_t)b * 34 + yy) * 34 + xx) * 64 + c4 * 4;
    *reinterpret_cast<uint2*>(p + o) = make_uint2(0u, 0u);
}

// conv weight OIHW fp32 -> bf16 [n][tap*Cin+ci]
__global__ void convw_bf_k(const float* __restrict__ w, __hip_bfloat16* __restrict__ wT,
                           int Cout, int Cin)
{
    int idx = blockIdx.x * 256 + threadIdx.x;
    if (idx >= Cout * Cin * 9) return;
    int n = idx / (Cin * 9), k = idx - n * (Cin * 9);
    int r = k / Cin, ci = k - r * Cin;
    wT[idx] = __float2bfloat16(w[((size_t)n * Cin + ci) * 9 + r]);
}

// [K][N] fp32 -> [N][K] bf16, tiled transpose (K,N multiples of 32)
__global__ void wt_bf_k(const float* __restrict__ w, __hip_bfloat16* __restrict__ wT,
                        int K, int N)
{
    __shared__ float t[32][33];
    int k0 = blockIdx.y * 32, n0 = blockIdx.x * 32;
    int tx = threadIdx.x, ty = threadIdx.y;
#pragma unroll
    for (int i = ty; i < 32; i += 8)
        t[i][tx] = w[(size_t)(k0 + i) * N + n0 + tx];
    __syncthreads();
#pragma unroll
    for (int i = ty; i < 32; i += 8)
        wT[(size_t)(n0 + i) * K + k0 + tx] = __float2bfloat16(t[tx][i]);
}

// fp32 -> bf16 flat convert
__global__ void f2bf_k(const float* __restrict__ s, __hip_bfloat16* __restrict__ d, int n)
{
    int i = blockIdx.x * 256 + threadIdx.x;
    if (i < n) d[i] = __float2bfloat16(s[i]);
}

// catbf[r][0:768] = bf16(q[r/50]); catbf[r][768:1536] = tfbbf[r]; rows>=1600 -> 0
__global__ void cat_bf_k(const float* __restrict__ q, const __hip_bfloat16* __restrict__ tf,
                         __hip_bfloat16* __restrict__ cat)
{
    int idx = blockIdx.x * 256 + threadIdx.x;
    if (idx >= 1664 * 1536) return;
    int r = idx / 1536, c = idx - r * 1536;
    __hip_bfloat16 v;
    if (r < 1600)
        v = (c < 768) ? __float2bfloat16(q[(size_t)(r / 50) * 768 + c])
                      : tf[(size_t)r * 768 + (c - 768)];
    else v = __float2bfloat16(0.f);
    cat[idx] = v;
}

// ---------------------------------------------------------------------------
// fp32 tiled GEMM — small GEMMs only
// ---------------------------------------------------------------------------
template<int ACT, int RES>
__global__ __launch_bounds__(256) void gemm_k(
    const float* __restrict__ A, const float* __restrict__ Bw,
    const float* __restrict__ bias, const float* __restrict__ res,
    float* __restrict__ C, int M, int N, int K)
{
    __shared__ float As[16][68];
    __shared__ float Bs[16][68];
    const int tx = threadIdx.x, ty = threadIdx.y;
    const int tid = ty * 16 + tx;
    const int bm = blockIdx.y * 64, bn = blockIdx.x * 64;
    float acc[4][4] = {};

    for (int k0 = 0; k0 < K; k0 += 16) {
#pragma unroll
        for (int i = 0; i < 4; i++) {
            int idx = i * 256 + tid;
            int ml = idx >> 4, kl = idx & 15;
            int m = bm + ml, k = k0 + kl;
            As[kl][ml] = (m < M && k < K) ? A[(size_t)m * K + k] : 0.f;
        }
#pragma unroll
        for (int i = 0; i < 4; i++) {
            int idx = i * 256 + tid;
            int nl = idx & 63, kl = idx >> 6;
            int k = k0 + kl, n = bn + nl;
            Bs[kl][nl] = (k < K && n < N) ? Bw[(size_t)k * N + n] : 0.f;
        }
        __syncthreads();
#pragma unroll
        for (int kk = 0; kk < 16; kk++) {
            const float4 av = *reinterpret_cast<const float4*>(&As[kk][ty * 4]);
            const float4 bv = *reinterpret_cast<const float4*>(&Bs[kk][tx * 4]);
            const float a4[4] = {av.x, av.y, av.z, av.w};
            const float b4[4] = {bv.x, bv.y, bv.z, bv.w};
#pragma unroll
            for (int i = 0; i < 4; i++)
#pragma unroll
                for (int j = 0; j < 4; j++)
                    acc[i][j] = fmaf(a4[i], b4[j], acc[i][j]);
        }
        __syncthreads();
    }
#pragma unroll
    for (int i = 0; i < 4; i++) {
        int m = bm + ty * 4 + i;
        if (m >= M) continue;
#pragma unroll
        for (int j = 0; j < 4; j++) {
            int n = bn + tx * 4 + j;
            if (n >= N) continue;
            float v = acc[i][j] + bias[n];
            if constexpr (ACT == 1) v = gelu_f(v);
            if constexpr (RES == 1) v += res[(size_t)m * N + n];
            C[(size_t)m * N + n] = v;
        }
    }
}

__global__ void depth_k(const float* __restrict__ d2,
                        const float* __restrict__ w3, const float* __restrict__ b3,
                        float* __restrict__ out)
{
    int idx = blockIdx.x * 256 + threadIdx.x;
    if (idx >= NB * 128 * 128) return;
    int b = idx >> 14;
    int rem = idx & 16383;
    int y = rem >> 7, x = rem & 127;
    const float* base = d2 + (((size_t)b * 64 + (y >> 1)) * 64 + (x >> 1)) * 32;
    float acc = b3[0];
#pragma unroll
    for (int ci = 0; ci < 32; ci++) acc = fmaf(base[ci], w3[ci], acc);
    out[idx] = softplus_f(acc);
}

__global__ void ln_k(const float* __restrict__ x, const float* __restrict__ g,
                     const float* __restrict__ bb, float* __restrict__ y)
{
    int r = blockIdx.x, t = threadIdx.x;
    __shared__ float red[256];
    float v0 = x[(size_t)r * ND + t];
    float v1 = x[(size_t)r * ND + 256 + t];
    float v2 = x[(size_t)r * ND + 512 + t];
    red[t] = v0 + v1 + v2;
    __syncthreads();
    for (int s = 128; s > 0; s >>= 1) { if (t < s) red[t] += red[t + s]; __syncthreads(); }
    float mean = red[0] * (1.0f / ND);
    __syncthreads();
    float d0 = v0 - mean, d1 = v1 - mean, d2 = v2 - mean;
    red[t] = d0 * d0 + d1 * d1 + d2 * d2;
    __syncthreads();
    for (int s = 128; s > 0; s >>= 1) { if (t < s) red[t] += red[t + s]; __syncthreads(); }
    float inv = 1.0f / sqrtf(red[0] * (1.0f / ND) + 1e-5f);
    y[(size_t)r * ND + t]       = d0 * inv * g[t]       + bb[t];
    y[(size_t)r * ND + 256 + t] = d1 * inv * g[256 + t] + bb[256 + t];
    y[(size_t)r * ND + 512 + t] = d2 * inv * g[512 + t] + bb[512 + t];
}

// ---------------------------------------------------------------------------
// Attention with q-seq-len 1 (wk folded into Q, wv folded after averaging).
// qw[b,h,c] = sum_d Qp[b,h*96+d] * wk[c, h*96+d]
// ---------------------------------------------------------------------------
__global__ __launch_bounds__(128) void qw_k(
    const float* __restrict__ Qp, const float* __restrict__ wk,
    float* __restrict__ qw)
{
    int bh = blockIdx.x; int b = bh >> 3, h = bh & 7;
    __shared__ float qs[96];
    int t = threadIdx.x;
    if (t < 96) qs[t] = Qp[(size_t)b * ND + h * 96 + t];
    __syncthreads();
    for (int c = t; c < ND; c += 128) {
        const float* wr = wk + (size_t)c * ND + h * 96;
        float a = 0.f;
#pragma unroll 8
        for (int d = 0; d < 96; d++) a = fmaf(qs[d], wr[d], a);
        qw[(size_t)bh * ND + c] = a;
    }
}

// scores + softmax, all 8 heads, one block per batch; thread owns 4 tokens.
// s[h,k] = (tok[k,:]·qw[h,:] + Qp·bk_h) * scale
__global__ __launch_bounds__(256) void scores2_k(
    const __hip_bfloat16* __restrict__ tok, const float* __restrict__ qw,
    const float* __restrict__ Qp, const float* __restrict__ bk,
    float* __restrict__ att)
{
    int b = blockIdx.x, t = threadIdx.x;
    __shared__ float qws[8 * 768];   // 24 KB
    __shared__ float pv[768];
    __shared__ float qbk_s[8];
    __shared__ float red[32];        // 4 waves x 8 heads
    __shared__ float g8[8];
    for (int i = t; i < 6144; i += 256) qws[i] = qw[(size_t)b * 6144 + i];
    for (int i = t; i < 768; i += 256) pv[i] = Qp[(size_t)b * ND + i] * bk[i];
    __syncthreads();
    if (t < 8) {
        float s = 0.f;
        for (int d = 0; d < 96; d++) s += pv[t * 96 + d];
        qbk_s[t] = s;
    }
    float acc[8][4];
#pragma unroll
    for (int h = 0; h < 8; h++)
#pragma unroll
        for (int i = 0; i < 4; i++) acc[h][i] = 0.f;
    // token rows t, t+256, t+512, t+768
    const s8v* tr = (const s8v*)(tok + ((size_t)b * NTOK + t) * ND);
    for (int j = 0; j < 96; j++) {
        s8v v0 = tr[j], v1 = tr[24576 + j], v2 = tr[49152 + j], v3 = tr[73728 + j];
        float tv[4][8];
#pragma unroll
        for (int e = 0; e < 8; e++) {
            tv[0][e] = bf2f((unsigned short)v0[e]);
            tv[1][e] = bf2f((unsigned short)v1[e]);
            tv[2][e] = bf2f((unsigned short)v2[e]);
            tv[3][e] = bf2f((unsigned short)v3[e]);
        }
#pragma unroll
        for (int h = 0; h < 8; h++) {
            f4v qa = *(const f4v*)&qws[h * 768 + j * 8];
            f4v qb = *(const f4v*)&qws[h * 768 + j * 8 + 4];
#pragma unroll
            for (int e = 0; e < 4; e++) {
#pragma unroll
                for (int i = 0; i < 4; i++) {
                    acc[h][i] = fmaf(qa[e], tv[i][e], acc[h][i]);
                    acc[h][i] = fmaf(qb[e], tv[i][e + 4], acc[h][i]);
                }
            }
        }
    }
    __syncthreads();   // qbk_s ready
    const float scale = 0.1020620726159658f;
#pragma unroll
    for (int h = 0; h < 8; h++)
#pragma unroll
        for (int i = 0; i < 4; i++) acc[h][i] = (acc[h][i] + qbk_s[h]) * scale;
    int lane = t & 63, w = t >> 6;
    // global max per head
#pragma unroll
    for (int h = 0; h < 8; h++) {
        float m = fmaxf(fmaxf(acc[h][0], acc[h][1]), fmaxf(acc[h][2], acc[h][3]));
#pragma unroll
        for (int off = 32; off > 0; off >>= 1) m = fmaxf(m, __shfl_xor(m, off, 64));
        if (lane == 0) red[w * 8 + h] = m;
    }
    __syncthreads();
    if (t < 8) {
        float m = red[t];
        for (int w2 = 1; w2 < 4; w2++) m = fmaxf(m, red[w2 * 8 + t]);
        g8[t] = m;
    }
    __syncthreads();
#pragma unroll
    for (int h = 0; h < 8; h++)
#pragma unroll
        for (int i = 0; i < 4; i++) acc[h][i] = expf(acc[h][i] - g8[h]);
    // global sum per head
#pragma unroll
    for (int h = 0; h < 8; h++) {
        float s = acc[h][0] + acc[h][1] + acc[h][2] + acc[h][3];
#pragma unroll
        for (int off = 32; off > 0; off >>= 1) s += __shfl_xor(s, off, 64);
        if (lane == 0) red[w * 8 + h] = s;
    }
    __syncthreads();
    if (t < 8) {
        float s = 0.f;
        for (int w2 = 0; w2 < 4; w2++) s += red[w2 * 8 + t];
        g8[t] = 1.0f / s;
    }
    __syncthreads();
#pragma unroll
    for (int h = 0; h < 8; h++)
#pragma unroll
        for (int i = 0; i < 4; i++)
            att[(((size_t)b * 8 + h) << 10) + t + i * 256] = acc[h][i] * g8[h];
}

// ctx partial: ctxp[ks][b][h][c] = sum_{k in ks-chunk} att[b,h,k]*tok[b,k,c]
// grid (4 ksplit, 32 b), 384 threads; thread owns c-pair 2t.
__global__ __launch_bounds__(384) void ctx_k(
    const __hip_bfloat16* __restrict__ tok, const float* __restrict__ att,
    float* __restrict__ ctxp)
{
    int ks = blockIdx.x, b = blockIdx.y;
    int t = threadIdx.x;
    __shared__ float att_s[256 * 8];   // 8 KB
    for (int i = t; i < 2048; i += 384) {
        int h = i >> 8, kk = i & 255;
        att_s[kk * 8 + h] = att[(((size_t)b * 8 + h) << 10) + (ks << 8) + kk];
    }
    __syncthreads();
    float acc[8][2];
#pragma unroll
    for (int h = 0; h < 8; h++) { acc[h][0] = 0.f; acc[h][1] = 0.f; }
    for (int kk = 0; kk < 256; kk++) {
        int k = (ks << 8) + kk;
        unsigned int u = *(const unsigned int*)(tok + ((size_t)b * NTOK + k) * ND + (t << 1));
        float t0 = bf2f((unsigned short)(u & 0xffffu));
        float t1 = bf2f((unsigned short)(u >> 16));
        f4v aa = *(const f4v*)&att_s[kk * 8];
        f4v ab = *(const f4v*)&att_s[kk * 8 + 4];
#pragma unroll
        for (int h = 0; h < 4; h++) {
            acc[h][0] = fmaf(aa[h], t0, acc[h][0]);
            acc[h][1] = fmaf(aa[h], t1, acc[h][1]);
            acc[h + 4][0] = fmaf(ab[h], t0, acc[h + 4][0]);
            acc[h + 4][1] = fmaf(ab[h], t1, acc[h + 4][1]);
        }
    }
#pragma unroll
    for (int h = 0; h < 8; h++) {
        float2 v = make_float2(acc[h][0], acc[h][1]);
        *reinterpret_cast<float2*>(
            &ctxp[(((size_t)ks * 32 + b) * 8 + h) * ND + (t << 1)]) = v;
    }
}

// o[b, h*96+d] = sum_c ctx[b,h,c] * wv[c, h*96+d] + bv[h*96+d]
__global__ __launch_bounds__(128) void ovp_k(
    const float* __restrict__ ctxp, const float* __restrict__ wv,
    const float* __restrict__ bv, float* __restrict__ ob)
{
    int bh = blockIdx.x; int b = bh >> 3, h = bh & 7;
    __shared__ float cs[768];
    int t = threadIdx.x;
    for (int i = t; i < 768; i += 128) {
        float s = 0.f;
#pragma unroll
        for (int ks = 0; ks < 4; ks++)
            s += ctxp[(((size_t)ks * 32 + b) * 8 + h) * ND + i];
        cs[i] = s;
    }
    __syncthreads();
    if (t < 96) {
        const float* wp = wv + h * 96 + t;
        float a = bv[h * 96 + t];
#pragma unroll 8
        for (int c = 0; c < ND; c++)
            a = fmaf(cs[c], wp[(size_t)c * ND], a);
        ob[(size_t)b * ND + h * 96 + t] = a;
    }
}

__global__ void build_qa_k(const int* __restrict__ intent,
                           const float* __restrict__ past,
                           float* __restrict__ qA)
{
    int idx = blockIdx.x * 256 + threadIdx.x;
    if (idx >= NB * 99) return;
    int b = idx / 99, j = idx - b * 99;
    float v;
    if (j < 3) v = (intent[b] - 1 == j) ? 1.f : 0.f;
    else       v = past[b * 96 + (j - 3)];
    qA[idx] = v;
}

__global__ void integrate_k(const float* __restrict__ cp,
                            const float* __restrict__ past,
                            float* __restrict__ out)
{
    int idx = blockIdx.x * 256 + threadIdx.x;
    if (idx >= NB * NK) return;
    int b = idx / NK, k = idx - b * NK;
    const float* pl = past + b * 96 + 90;
    float x = pl[0], y = pl[1], vx = pl[2], vy = pl[3];
    float s  = sqrtf(vx * vx + vy * vy + 1e-6f);
    float hd = atan2f(vy, vx);
    const float* cpk = cp + (size_t)b * 3000 + k * 60;
    float* o0 = out +        (size_t)b * 3000 + k * 60;
    float* o1 = out + 96000 + (size_t)b * 3000 + k * 60;
    float* c5 = out + 1946688 + (size_t)b * 3000 + k * 60;
    float* c6 = out + 2042688 + (size_t)b * 3000 + k * 60;
    const float DT = 0.25f;
    for (int t = 0; t < NT; t++) {
        float a = tanhf(cpk[t * 2 + 0]) * 8.0f;
        float w = tanhf(cpk[t * 2 + 1]) * 1.0f;
        x += s * cosf(hd) * DT;
        y += s * sinf(hd) * DT;
        o0[t * 2 + 0] = x; o0[t * 2 + 1] = y;
        o1[t * 2 + 0] = x; o1[t * 2 + 1] = y;
        c5[t * 2 + 0] = a; c5[t * 2 + 1] = w;
        c6[t * 2 + 0] = a; c6[t * 2 + 1] = w;
        hd += w * DT;
        s = fmaxf(s + a * DT, 0.f);
    }
}

__global__ void qscore_k(const float* __restrict__ q, float* __restrict__ out2)
{
    int idx = blockIdx.x * 256 + threadIdx.x;
    if (idx >= NB * NK * ND) return;
    int r = idx / ND, d = idx - r * ND;
    int b = r / NK;
    out2[idx] = q[(size_t)b * ND + d];
}

__global__ void score_k(const float* __restrict__ sc2, const float* __restrict__ w,
                        const float* __restrict__ bias, float* __restrict__ out)
{
    int r = blockIdx.x * 4 + (threadIdx.x >> 6);
    int lane = threadIdx.x & 63;
    if (r >= NB * NK) return;
    float acc = 0.f;
    for (int d = lane; d < ND; d += 64) acc = fmaf(sc2[(size_t)r * ND + d], w[d], acc);
    for (int off = 32; off > 0; off >>= 1) acc += __shfl_down(acc, off, 64);
    if (lane == 0) out[r] = acc + bias[0];
}

// ---------------------------------------------------------------------------
static inline void gemm(hipStream_t st, int act, int hasres,
                        const float* A, const float* Bw, const float* bias,
                        const float* res, float* C, int M, int N, int K)
{
    dim3 blk(16, 16), grd((N + 63) / 64, (M + 63) / 64);
    if      (act == 0 && !hasres) gemm_k<0, 0><<<grd, blk, 0, st>>>(A, Bw, bias, res, C, M, N, K);
    else if (act == 0 &&  hasres) gemm_k<0, 1><<<grd, blk, 0, st>>>(A, Bw, bias, res, C, M, N, K);
    else                          gemm_k<1, 0><<<grd, blk, 0, st>>>(A, Bw, bias, res, C, M, N, K);
}

extern "C" void kernel_launch(void* const* d_in, const int* in_sizes, int n_in,
                              void* d_out, int out_size, void* d_ws, size_t ws_size,
                              hipStream_t stream)
{
    const float* feats_vit = (const float*)d_in[0];
    const float* past      = (const float*)d_in[1];
    const int*   intent    = (const int*)  d_in[2];
    const float* qi_w   = (const float*)d_in[3];
    const float* qi_b   = (const float*)d_in[4];
    const float* va1_w  = (const float*)d_in[5];
    const float* va1_b  = (const float*)d_in[6];
    const float* va2_w  = (const float*)d_in[7];
    const float* va2_b  = (const float*)d_in[8];
    const float* pos    = (const float*)d_in[9];
    const float* ln1_g  = (const float*)d_in[10];
    const float* ln1_b  = (const float*)d_in[11];
    const float* wq     = (const float*)d_in[12];
    const float* bq     = (const float*)d_in[13];
    const float* wk     = (const float*)d_in[14];
    const float* bk     = (const float*)d_in[15];
    const float* wv     = (const float*)d_in[16];
    const float* bv     = (const float*)d_in[17];
    const float* wo     = (const float*)d_in[18];
    const float* bo     = (const float*)d_in[19];
    const float* ln2_g  = (const float*)d_in[20];
    const float* ln2_b  = (const float*)d_in[21];
    const float* m1w    = (const float*)d_in[22];
    const float* m1b    = (const float*)d_in[23];
    const float* m2w    = (const float*)d_in[24];
    const float* m2b    = (const float*)d_in[25];
    const float* dg1w   = (const float*)d_in[26];
    const float* dg1b   = (const float*)d_in[27];
    const float* dg2w   = (const float*)d_in[28];
    const float* dg2b   = (const float*)d_in[29];
    const float* dg3w   = (const float*)d_in[30];
    const float* dg3b   = (const float*)d_in[31];
    const float* td1w   = (const float*)d_in[32];
    const float* td1b   = (const float*)d_in[33];
    const float* td2w   = (const float*)d_in[34];
    const float* td2b   = (const float*)d_in[35];
    const float* td3w   = (const float*)d_in[36];
    const float* td3b   = (const float*)d_in[37];
    const float* tf1w   = (const float*)d_in[38];
    const float* tf1b   = (const float*)d_in[39];
    const float* tf2w   = (const float*)d_in[40];
    const float* tf2b   = (const float*)d_in[41];
    const float* sd1w   = (const float*)d_in[42];
    const float* sd1b   = (const float*)d_in[43];
    const float* sd2w   = (const float*)d_in[44];
    const float* sd2b   = (const float*)d_in[45];
    const float* sd3w   = (const float*)d_in[46];
    const float* sd3b   = (const float*)d_in[47];

    float* out = (float*)d_out;
    float* ws  = (float*)d_ws;

    // workspace layout (float units)
    size_t off = 0;
    float* bufB    = ws + off; off += (size_t)NB * ND * NTOK;   // early: xpad2 alias; late: qw/ctxp
    float* xpad_f  = ws + off; off += 14201856;                 // input padded bf16 / tokens bf16
    float* c1pad_f = ws + off; off += 14201856;                 // conv1 out padded bf16 / late: score bufs + d1pad
    float* wTc_f   = ws + off; off += 2654208;                  // conv weights bf16 [768][6912]
    float* dg1wT_f = ws + off; off += 221184;                   // [64][6912] bf16
    float* dg2wT_f = ws + off; off += 9216;                     // [32][576]  bf16
    float* tf2wT_f = ws + off; off += 294912;
    float* sd1wT_f = ws + off; off += 589824;                   // [768][1536] bf16
    float* sd2wT_f = ws + off; off += 294912;
    float* d2      = ws + off; off += (size_t)NB * 4096 * 32;
    float* attb    = ws + off; off += (size_t)NB * NKH * NTOK;
    float* q       = ws + off; off += NB * ND;
    float* qn      = ws + off; off += NB * ND;
    float* Qp      = ws + off; off += NB * ND;
    float* ob      = ws + off; off += NB * ND;
    float* hm      = ws + off; off += NB * NMLP;
    float* qA      = ws + off; off += NB * 128;
    float* h1      = ws + off; off += NB * ND;
    float* h2      = ws + off; off += NB * ND;
    float* cp      = ws + off; off += NB * 3000;
    // bf16 aliases
    __hip_bfloat16* xpad   = (__hip_bfloat16*)xpad_f;
    __hip_bfloat16* c1pad  = (__hip_bfloat16*)c1pad_f;
    __hip_bfloat16* xpad2  = (__hip_bfloat16*)bufB;             // feats padded bf16 (pre-transformer only)
    __hip_bfloat16* tokbf  = (__hip_bfloat16*)xpad_f;           // tokens bf16 (after conv1 frees xpad)
    __hip_bfloat16* wTc    = (__hip_bfloat16*)wTc_f;
    __hip_bfloat16* dg1wT  = (__hip_bfloat16*)dg1wT_f;
    __hip_bfloat16* dg2wT  = (__hip_bfloat16*)dg2wT_f;
    __hip_bfloat16* tf2wT  = (__hip_bfloat16*)tf2wT_f;
    __hip_bfloat16* sd1wT  = (__hip_bfloat16*)sd1wT_f;
    __hip_bfloat16* sd2wT  = (__hip_bfloat16*)sd2wT_f;
    // attention scratch carved from bufB (xpad2 is dead after dg1)
    float* qwb  = bufB;                    // 256 x 768 fp32
    float* ctxp = bufB + 196608;           // 4 x 256 x 768 fp32 partials
    // score-head buffers carved from c1pad region (free after conv2)
    float* tfa            = c1pad_f;                            // 1600x768 fp32
    __hip_bfloat16* tfabf = (__hip_bfloat16*)(c1pad_f + 1228800);  // 1664x768
    __hip_bfloat16* tfbbf = (__hip_bfloat16*)(c1pad_f + 1867776);  // 1664x768
    __hip_bfloat16* catbf = (__hip_bfloat16*)(c1pad_f + 2506752);  // 1664x1536
    __hip_bfloat16* s1bf  = (__hip_bfloat16*)(c1pad_f + 3784704);  // 1664x768
    float* s2             = c1pad_f + 4423680;                     // 1664x768 fp32
    __hip_bfloat16* d1pad = (__hip_bfloat16*)(c1pad_f + 8000000);  // [32][34][34][64]
    (void)ws_size; (void)n_in; (void)in_sizes; (void)out_size;

    const int M_PIX = NB * 1024;

    // ---- prep: borders, input transpose, conv weights ----
    pad_border_k<<<(32 * 132 * 192 + 255) / 256, 256, 0, stream>>>(xpad, c1pad);
    pad_border_k<<<(32 * 132 * 192 + 255) / 256, 256, 0, stream>>>(xpad2, xpad2);
    pad_border64_k<<<(32 * 132 * 16 + 255) / 256, 256, 0, stream>>>(d1pad);
    nchw2pad_bf_k<<<dim3(ND / 32, NTOK / 32, NB), dim3(32, 8), 0, stream>>>(feats_vit, xpad);
    convw_bf_k<<<(768 * 768 * 9 + 255) / 256, 256, 0, stream>>>(va1_w, wTc, 768, 768);

    // ---- conv1 (gelu -> padded bf16) ----
    mfma_gemm_k<1, 1, 1><<<dim3(6, 256), 256, 0, stream>>>(
        xpad, wTc, va1_b, nullptr, nullptr, c1pad, nullptr, M_PIX, ND, ND * 9);
    convw_bf_k<<<(768 * 768 * 9 + 255) / 256, 256, 0, stream>>>(va2_w, wTc, 768, 768);
    // ---- conv2 (-> padded bf16 feats + bf16 tokens with +pos) ----
    mfma_gemm_k<1, 0, 3><<<dim3(6, 256), 256, 0, stream>>>(
        c1pad, wTc, va2_b, nullptr, tokbf, xpad2, pos, M_PIX, ND, ND * 9);

    // ---- depth branch (bf16 MFMA) ----
    convw_bf_k<<<(64 * 768 * 9 + 255) / 256, 256, 0, stream>>>(dg1w, dg1wT, 64, 768);
    mfma_dg1_k<<<256, 256, 0, stream>>>(xpad2, dg1wT, dg1b, d1pad);
    convw_bf_k<<<(32 * 64 * 9 + 255) / 256, 256, 0, stream>>>(dg2w, dg2wT, 32, 64);
    mfma_dg2_k<<<1024, 256, 0, stream>>>(d1pad, dg2wT, dg2b, d2);
    depth_k<<<(NB * 16384 + 255) / 256, 256, 0, stream>>>(d2, dg3w, dg3b, out + 1422400);

    // ---- q init ----
    build_qa_k<<<(NB * 99 + 255) / 256, 256, 0, stream>>>(intent, past, qA);
    gemm(stream, 0, 0, qA, qi_w, qi_b, nullptr, q, NB, ND, 99);

    // ---- transformer layers (seq-len-1 folded attention) ----
    for (int i = 0; i < NL; i++) {
        const size_t W = (size_t)i * ND * ND;
        ln_k<<<NB, 256, 0, stream>>>(q, ln1_g + i * ND, ln1_b + i * ND, qn);
        gemm(stream, 0, 0, qn, wq + W, bq + i * ND, nullptr, Qp, NB, ND, ND);
        qw_k<<<NB * NKH, 128, 0, stream>>>(Qp, wk + W, qwb);
        scores2_k<<<NB, 256, 0, stream>>>(tokbf, qwb, Qp, bk + i * ND, attb);
        ctx_k<<<dim3(4, NB), 384, 0, stream>>>(tokbf, attb, ctxp);
        ovp_k<<<NB * NKH, 128, 0, stream>>>(ctxp, wv + W, bv + i * ND, ob);
        gemm(stream, 0, 1, ob, wo + W, bo + i * ND, q, q, NB, ND, ND);
        ln_k<<<NB, 256, 0, stream>>>(q, ln2_g + i * ND, ln2_b + i * ND, qn);
        gemm(stream, 1, 0, qn, m1w + (size_t)i * ND * NMLP, m1b + i * NMLP,
             nullptr, hm, NB, NMLP, ND);
        gemm(stream, 0, 1, hm, m2w + (size_t)i * NMLP * ND, m2b + i * ND,
             q, q, NB, ND, NMLP);
    }

    // ---- trajectory decoder ----
    gemm(stream, 1, 0, q,  td1w, td1b, nullptr, h1, NB, ND, ND);
    gemm(stream, 1, 0, h1, td2w, td2b, nullptr, h2, NB, ND, ND);
    gemm(stream, 0, 0, h2, td3w, td3b, nullptr, cp, NB, 3000, ND);
    integrate_k<<<(NB * NK + 255) / 256, 256, 0, stream>>>(cp, past, out);

    // ---- score head ----
    qscore_k<<<(NB * NK * ND + 255) / 256, 256, 0, stream>>>(q, out + 192000);
    gemm(stream, 1, 0, out, tf1w, tf1b, nullptr, tfa, NB * NK, ND, 60);
    f2bf_k<<<(1600 * 768 + 255) / 256, 256, 0, stream>>>(tfa, tfabf, 1600 * 768);
    wt_bf_k<<<dim3(24, 24), dim3(32, 8), 0, stream>>>(tf2w, tf2wT, 768, 768);
    mfma_gemm_k<0, 1, 2><<<dim3(6, 13), 256, 0, stream>>>(
        tfabf, tf2wT, tf2b, nullptr, tfbbf, nullptr, nullptr, 1600, 768, 768);
    cat_bf_k<<<(1664 * 1536 + 255) / 256, 256, 0, stream>>>(q, tfbbf, catbf);
    wt_bf_k<<<dim3(24, 48), dim3(32, 8), 0, stream>>>(sd1w, sd1wT, 1536, 768);
    mfma_gemm_k<0, 1, 2><<<dim3(6, 13), 256, 0, stream>>>(
        catbf, sd1wT, sd1b, nullptr, s1bf, nullptr, nullptr, 1600, 768, 1536);
    wt_bf_k<<<dim3(24, 24), dim3(32, 8), 0, stream>>>(sd2w, sd2wT, 768, 768);
    mfma_gemm_k<0, 1, 0><<<dim3(6, 13), 256, 0, stream>>>(
        s1bf, sd2wT, sd2b, s2, nullptr, nullptr, nullptr, 1600, 768, 768);
    score_k<<<(NB * NK + 3) / 4, 256, 0, stream>>>(s2, sd3w, sd3b, out + 1420800);
}

// Round 3
// 2999.029 us; speedup vs baseline: 2.3331x; 2.2568x over previous
//
#include <hip/hip_runtime.h>
#include <hip/hip_bf16.h>
#include <math.h>

// ---------------------------------------------------------------------------
// DeepMonocularModel — r7 (= r6 with corrected workspace offsets):
//  * r6's qwbf/attbf regions were sized in float units but hold bf16 counts;
//    sraw overlapped qwbf (b>=16) and ctxf overlapped attbf -> NaN. Fixed.
//  * all M=32 fp32 GEMMs -> KSPLIT=16 partial+combine, transposed-A layout.
//  * attention scores & ctx via bf16 MFMA (heads padded to 16); softmax
//    standalone; Q·bk dropped (softmax-invariant). tokens transposed once.
// ---------------------------------------------------------------------------

#define NB   32
#define ND   768
#define NTOK 1024
#define NKH  8
#define NHD  96
#define NL   4
#define NMLP 3072
#define NK   50
#define NT   30

typedef short  s8v __attribute__((ext_vector_type(8)));
typedef float  f4v __attribute__((ext_vector_type(4)));

__device__ __forceinline__ float gelu_f(float x) {
    return 0.5f * x * (1.0f + erff(x * 0.70710678118654752f));
}
__device__ __forceinline__ float softplus_f(float x) {
    return x > 0.f ? x + log1pf(expf(-x)) : log1pf(expf(x));
}
__device__ __forceinline__ float bf2f(unsigned short u) {
    unsigned int x = ((unsigned int)u) << 16;
    union { unsigned int i; float f; } c; c.i = x;
    return c.f;
}
__device__ __forceinline__ void gld_lds16(const void* g, void* l) {
    __builtin_amdgcn_global_load_lds(
        (const __attribute__((address_space(1))) void*)g,
        (__attribute__((address_space(3))) void*)l, 16, 0, 0);
}

// ---------------------------------------------------------------------------
// bf16 MFMA GEMM, 128x128 tile. C = act(A_view @ Bt^T + bias)
// ---------------------------------------------------------------------------
template<int AMODE, int ACT, int OUT>
__global__ __launch_bounds__(256) void mfma_gemm_k(
    const __hip_bfloat16* __restrict__ A,
    const __hip_bfloat16* __restrict__ Bt,
    const float* __restrict__ bias,
    float* __restrict__ Cf,
    __hip_bfloat16* __restrict__ Cb,
    __hip_bfloat16* __restrict__ Cpad,
    const float* __restrict__ pos,
    int M, int N, int K)
{
    __shared__ __hip_bfloat16 As[128 * 32];
    __shared__ __hip_bfloat16 Bs[128 * 32];
    const int tid  = threadIdx.x;
    const int lane = tid & 63;
    const int wave = tid >> 6;
    const int wm = wave >> 1, wn = wave & 1;
    int bxi = blockIdx.x, byi = blockIdx.y;
    {
        const int nbx = gridDim.x;
        const int nwg = nbx * gridDim.y;
        if ((nwg & 7) == 0) {
            int id = byi * nbx + bxi;
            const int cpx = nwg >> 3;
            id = (id & 7) * cpx + (id >> 3);
            bxi = id % nbx; byi = id / nbx;
        }
    }
    const int bm = byi * 128, bn = bxi * 128;
    const int r0 = tid >> 2;
    const int kb = (tid & 3) * 8;

    f4v acc[4][4];
#pragma unroll
    for (int i = 0; i < 4; i++)
#pragma unroll
        for (int j = 0; j < 4; j++) acc[i][j] = (f4v)0.f;

    int rr = 0, kin = 0;
    for (int k0 = 0; k0 < K; k0 += 32) {
#pragma unroll
        for (int c = 0; c < 2; c++) {
            const int row = r0 + c * 64;
            const __hip_bfloat16* ga;
            if constexpr (AMODE == 0) {
                ga = A + (size_t)(bm + row) * K + k0 + kb;
            } else {
                int gm = bm + row;
                int b = gm >> 10, y = (gm >> 5) & 31, x = gm & 31;
                int dy = rr / 3, dx = rr - dy * 3;
                ga = A + ((((size_t)b * 34 + y + dy) * 34 + (x + dx)) * 768 + kin + kb);
            }
            gld_lds16(ga, &As[row * 32 + kb]);
        }
#pragma unroll
        for (int c = 0; c < 2; c++) {
            const int row = r0 + c * 64;
            gld_lds16(Bt + (size_t)(bn + row) * K + k0 + kb, &Bs[row * 32 + kb]);
        }
        __syncthreads();
        const int koff = (lane >> 4) * 8;
        s8v af[4], bfv[4];
#pragma unroll
        for (int i = 0; i < 4; i++)
            af[i] = *(const s8v*)(&As[(wm * 64 + i * 16 + (lane & 15)) * 32 + koff]);
#pragma unroll
        for (int j = 0; j < 4; j++)
            bfv[j] = *(const s8v*)(&Bs[(wn * 64 + j * 16 + (lane & 15)) * 32 + koff]);
#pragma unroll
        for (int i = 0; i < 4; i++)
#pragma unroll
            for (int j = 0; j < 4; j++)
                acc[i][j] = __builtin_amdgcn_mfma_f32_16x16x32_bf16(af[i], bfv[j], acc[i][j], 0, 0, 0);
        __syncthreads();
        if constexpr (AMODE == 1) { kin += 32; if (kin == 768) { kin = 0; rr++; } }
    }
#pragma unroll
    for (int i = 0; i < 4; i++) {
        const int mbase = bm + wm * 64 + i * 16 + ((lane >> 4) << 2);
#pragma unroll
        for (int j = 0; j < 4; j++) {
            const int n = bn + wn * 64 + j * 16 + (lane & 15);
            const float bs = bias[n];
#pragma unroll
            for (int g = 0; g < 4; g++) {
                const int m = mbase + g;
                if (m >= M) continue;
                float v = acc[i][j][g] + bs;
                if constexpr (ACT == 1) v = gelu_f(v);
                if constexpr (OUT == 0) {
                    Cf[(size_t)m * N + n] = v;
                } else if constexpr (OUT == 1) {
                    int b = m >> 10, y = (m >> 5) & 31, x = m & 31;
                    Cpad[(((size_t)b * 34 + y + 1) * 34 + (x + 1)) * 768 + n] =
                        __float2bfloat16(v);
                } else if constexpr (OUT == 2) {
                    Cb[(size_t)m * N + n] = __float2bfloat16(v);
                } else {
                    int b = m >> 10, y = (m >> 5) & 31, x = m & 31;
                    Cpad[(((size_t)b * 34 + y + 1) * 34 + (x + 1)) * 768 + n] =
                        __float2bfloat16(v);
                    Cb[(size_t)m * 768 + n] =
                        __float2bfloat16(v + pos[(size_t)(m & 1023) * 768 + n]);
                }
            }
        }
    }
}

// ---------------------------------------------------------------------------
// dg1: 3x3 conv 768->64, gelu, in/out padded bf16. Tile 128(M)x64(N).
// ---------------------------------------------------------------------------
__global__ __launch_bounds__(256) void mfma_dg1_k(
    const __hip_bfloat16* __restrict__ A,
    const __hip_bfloat16* __restrict__ Bt,
    const float* __restrict__ bias,
    __hip_bfloat16* __restrict__ Dpad)
{
    __shared__ __hip_bfloat16 As[128 * 32];
    __shared__ __hip_bfloat16 Bs[64 * 32];
    const int tid = threadIdx.x, lane = tid & 63, wave = tid >> 6;
    const int wm = wave >> 1, wn = wave & 1;
    const int bm = blockIdx.x * 128;
    const int r0 = tid >> 2, kb = (tid & 3) * 8;
    f4v acc[4][2];
#pragma unroll
    for (int i = 0; i < 4; i++)
#pragma unroll
        for (int j = 0; j < 2; j++) acc[i][j] = (f4v)0.f;

    int rr = 0, kin = 0;
    for (int k0 = 0; k0 < 6912; k0 += 32) {
#pragma unroll
        for (int c = 0; c < 2; c++) {
            const int row = r0 + c * 64;
            int gm = bm + row;
            int b = gm >> 10, y = (gm >> 5) & 31, x = gm & 31;
            int dy = rr / 3, dx = rr - dy * 3;
            gld_lds16(A + ((((size_t)b * 34 + y + dy) * 34 + (x + dx)) * 768 + kin + kb),
                      &As[row * 32 + kb]);
        }
        gld_lds16(Bt + (size_t)r0 * 6912 + k0 + kb, &Bs[r0 * 32 + kb]);
        __syncthreads();
        const int koff = (lane >> 4) * 8;
        s8v af[4], bfv[2];
#pragma unroll
        for (int i = 0; i < 4; i++)
            af[i] = *(const s8v*)(&As[(wm * 64 + i * 16 + (lane & 15)) * 32 + koff]);
#pragma unroll
        for (int j = 0; j < 2; j++)
            bfv[j] = *(const s8v*)(&Bs[(wn * 32 + j * 16 + (lane & 15)) * 32 + koff]);
#pragma unroll
        for (int i = 0; i < 4; i++)
#pragma unroll
            for (int j = 0; j < 2; j++)
                acc[i][j] = __builtin_amdgcn_mfma_f32_16x16x32_bf16(af[i], bfv[j], acc[i][j], 0, 0, 0);
        __syncthreads();
        kin += 32; if (kin == 768) { kin = 0; rr++; }
    }
#pragma unroll
    for (int i = 0; i < 4; i++) {
        const int mbase = bm + wm * 64 + i * 16 + ((lane >> 4) << 2);
#pragma unroll
        for (int j = 0; j < 2; j++) {
            const int n = wn * 32 + j * 16 + (lane & 15);
            const float bs = bias[n];
#pragma unroll
            for (int g = 0; g < 4; g++) {
                const int m = mbase + g;
                float v = gelu_f(acc[i][j][g] + bs);
                int b = m >> 10, y = (m >> 5) & 31, x = m & 31;
                Dpad[(((size_t)b * 34 + y + 1) * 34 + (x + 1)) * 64 + n] =
                    __float2bfloat16(v);
            }
        }
    }
}

// ---------------------------------------------------------------------------
// dg2: up2 + 3x3 conv 64->32, gelu. Tile 128(M)x32(N).
// ---------------------------------------------------------------------------
__global__ __launch_bounds__(256) void mfma_dg2_k(
    const __hip_bfloat16* __restrict__ A,
    const __hip_bfloat16* __restrict__ Bt,
    const float* __restrict__ bias,
    float* __restrict__ D)
{
    __shared__ __hip_bfloat16 As[128 * 32];
    __shared__ __hip_bfloat16 Bs[32 * 32];
    const int tid = threadIdx.x, lane = tid & 63, wave = tid >> 6;
    const int bm = blockIdx.x * 128;
    const int r0 = tid >> 2, kb = (tid & 3) * 8;
    f4v acc[2][2];
#pragma unroll
    for (int i = 0; i < 2; i++)
#pragma unroll
        for (int j = 0; j < 2; j++) acc[i][j] = (f4v)0.f;

    int rr = 0, kin = 0;
    for (int k0 = 0; k0 < 576; k0 += 32) {
#pragma unroll
        for (int c = 0; c < 2; c++) {
            const int row = r0 + c * 64;
            int gm = bm + row;
            int b = gm >> 12, y = (gm >> 6) & 63, x = gm & 63;
            int dy = rr / 3, dx = rr - dy * 3;
            int iy = (y + dy + 1) >> 1, ix = (x + dx + 1) >> 1;
            gld_lds16(A + (((size_t)b * 34 + iy) * 34 + ix) * 64 + kin + kb,
                      &As[row * 32 + kb]);
        }
        if (tid < 128)
            gld_lds16(Bt + (size_t)r0 * 576 + k0 + kb, &Bs[r0 * 32 + kb]);
        __syncthreads();
        const int koff = (lane >> 4) * 8;
        s8v af[2], bfv[2];
#pragma unroll
        for (int i = 0; i < 2; i++)
            af[i] = *(const s8v*)(&As[(wave * 32 + i * 16 + (lane & 15)) * 32 + koff]);
#pragma unroll
        for (int j = 0; j < 2; j++)
            bfv[j] = *(const s8v*)(&Bs[(j * 16 + (lane & 15)) * 32 + koff]);
#pragma unroll
        for (int i = 0; i < 2; i++)
#pragma unroll
            for (int j = 0; j < 2; j++)
                acc[i][j] = __builtin_amdgcn_mfma_f32_16x16x32_bf16(af[i], bfv[j], acc[i][j], 0, 0, 0);
        __syncthreads();
        kin += 32; if (kin == 64) { kin = 0; rr++; }
    }
#pragma unroll
    for (int i = 0; i < 2; i++) {
        const int mbase = bm + wave * 32 + i * 16 + ((lane >> 4) << 2);
#pragma unroll
        for (int j = 0; j < 2; j++) {
            const int n = j * 16 + (lane & 15);
            const float bs = bias[n];
#pragma unroll
            for (int g = 0; g < 4; g++) {
                const int m = mbase + g;
                D[(size_t)m * 32 + n] = gelu_f(acc[i][j][g] + bs);
            }
        }
    }
}

// NCHW fp32 -> padded NHWC bf16 interior
__global__ void nchw2pad_bf_k(const float* __restrict__ src, __hip_bfloat16* __restrict__ dst)
{
    __shared__ float tile[32][33];
    int b = blockIdx.z, n0 = blockIdx.y * 32, c0 = blockIdx.x * 32;
    int tx = threadIdx.x, ty = threadIdx.y;
#pragma unroll
    for (int i = ty; i < 32; i += 8)
        tile[i][tx] = src[((size_t)b * ND + c0 + i) * NTOK + n0 + tx];
    __syncthreads();
#pragma unroll
    for (int i = ty; i < 32; i += 8) {
        int n = n0 + i, y = n >> 5, x = n & 31;
        dst[(((size_t)b * 34 + y + 1) * 34 + (x + 1)) * 768 + c0 + tx] =
            __float2bfloat16(tile[tx][i]);
    }
}

// zero borders of two padded-768 bf16 buffers
__global__ void pad_border_k(__hip_bfloat16* __restrict__ p1, __hip_bfloat16* __restrict__ p2)
{
    int idx = blockIdx.x * 256 + threadIdx.x;
    if (idx >= 32 * 132 * 192) return;
    int c4 = idx % 192;
    int cell = (idx / 192) % 132;
    int b = idx / (192 * 132);
    int yy, xx;
    if      (cell < 34)  { yy = 0;  xx = cell; }
    else if (cell < 68)  { yy = 33; xx = cell - 34; }
    else if (cell < 100) { yy = cell - 68 + 1;  xx = 0; }
    else                 { yy = cell - 100 + 1; xx = 33; }
    size_t o = (((size_t)b * 34 + yy) * 34 + xx) * 768 + c4 * 4;
    *reinterpret_cast<uint2*>(p1 + o) = make_uint2(0u, 0u);
    *reinterpret_cast<uint2*>(p2 + o) = make_uint2(0u, 0u);
}

// zero border of padded-64 bf16 buffer
__global__ void pad_border64_k(__hip_bfloat16* __restrict__ p)
{
    int idx = blockIdx.x * 256 + threadIdx.x;
    if (idx >= 32 * 132 * 16) return;
    int c4 = idx % 16;
    int cell = (idx / 16) % 132;
    int b = idx / (16 * 132);
    int yy, xx;
    if      (cell < 34)  { yy = 0;  xx = cell; }
    else if (cell < 68)  { yy = 33; xx = cell - 34; }
    else if (cell < 100) { yy = cell - 68 + 1;  xx = 0; }
    else                 { yy = cell - 100 + 1; xx = 33; }
    size_t o = (((size_t)b * 34 + yy) * 34 + xx) * 64 + c4 * 4;
    *reinterpret_cast<uint2*>(p + o) = make_uint2(0u, 0u);
}

// conv weight OIHW fp32 -> bf16 [n][tap*Cin+ci]
__global__ void convw_bf_k(const float* __restrict__ w, __hip_bfloat16* __restrict__ wT,
                           int Cout, int Cin)
{
    int idx = blockIdx.x * 256 + threadIdx.x;
    if (idx >= Cout * Cin * 9) return;
    int n = idx / (Cin * 9), k = idx - n * (Cin * 9);
    int r = k / Cin, ci = k - r * Cin;
    wT[idx] = __float2bfloat16(w[((size_t)n * Cin + ci) * 9 + r]);
}

// [K][N] fp32 -> [N][K] bf16, tiled transpose
__global__ void wt_bf_k(const float* __restrict__ w, __hip_bfloat16* __restrict__ wT,
                        int K, int N)
{
    __shared__ float t[32][33];
    int k0 = blockIdx.y * 32, n0 = blockIdx.x * 32;
    int tx = threadIdx.x, ty = threadIdx.y;
#pragma unroll
    for (int i = ty; i < 32; i += 8)
        t[i][tx] = w[(size_t)(k0 + i) * N + n0 + tx];
    __syncthreads();
#pragma unroll
    for (int i = ty; i < 32; i += 8)
        wT[(size_t)(n0 + i) * K + k0 + tx] = __float2bfloat16(t[tx][i]);
}

// tokens [b][1024][768] bf16 -> tokT [b][768][1024] bf16
__global__ void tokT_k(const __hip_bfloat16* __restrict__ tok, __hip_bfloat16* __restrict__ tokT)
{
    __shared__ __hip_bfloat16 tl[32][33];
    int b = blockIdx.z, k0 = blockIdx.y * 32, c0 = blockIdx.x * 32;
    int tx = threadIdx.x, ty = threadIdx.y;
#pragma unroll
    for (int i = ty; i < 32; i += 8)
        tl[i][tx] = tok[((size_t)(b * 1024 + k0 + i)) * 768 + c0 + tx];
    __syncthreads();
#pragma unroll
    for (int i = ty; i < 32; i += 8)
        tokT[((size_t)(b * 768 + c0 + i)) * 1024 + k0 + tx] = tl[tx][i];
}

// fp32 -> bf16 flat convert
__global__ void f2bf_k(const float* __restrict__ s, __hip_bfloat16* __restrict__ d, int n)
{
    int i = blockIdx.x * 256 + threadIdx.x;
    if (i < n) d[i] = __float2bfloat16(s[i]);
}

// catbf[r][0:768] = bf16(q[r/50]); catbf[r][768:1536] = tfbbf[r]; rows>=1600 -> 0
__global__ void cat_bf_k(const float* __restrict__ q, const __hip_bfloat16* __restrict__ tf,
                         __hip_bfloat16* __restrict__ cat)
{
    int idx = blockIdx.x * 256 + threadIdx.x;
    if (idx >= 1664 * 1536) return;
    int r = idx / 1536, c = idx - r * 1536;
    __hip_bfloat16 v;
    if (r < 1600)
        v = (c < 768) ? __float2bfloat16(q[(size_t)(r / 50) * 768 + c])
                      : tf[(size_t)r * 768 + (c - 768)];
    else v = __float2bfloat16(0.f);
    cat[idx] = v;
}

// ---------------------------------------------------------------------------
// fp32 tiled GEMM — kept for qi (K=99) and tf1 (M=1600)
// ---------------------------------------------------------------------------
template<int ACT, int RES>
__global__ __launch_bounds__(256) void gemm_k(
    const float* __restrict__ A, const float* __restrict__ Bw,
    const float* __restrict__ bias, const float* __restrict__ res,
    float* __restrict__ C, int M, int N, int K)
{
    __shared__ float As[16][68];
    __shared__ float Bs[16][68];
    const int tx = threadIdx.x, ty = threadIdx.y;
    const int tid = ty * 16 + tx;
    const int bm = blockIdx.y * 64, bn = blockIdx.x * 64;
    float acc[4][4] = {};

    for (int k0 = 0; k0 < K; k0 += 16) {
#pragma unroll
        for (int i = 0; i < 4; i++) {
            int idx = i * 256 + tid;
            int ml = idx >> 4, kl = idx & 15;
            int m = bm + ml, k = k0 + kl;
            As[kl][ml] = (m < M && k < K) ? A[(size_t)m * K + k] : 0.f;
        }
#pragma unroll
        for (int i = 0; i < 4; i++) {
            int idx = i * 256 + tid;
            int nl = idx & 63, kl = idx >> 6;
            int k = k0 + kl, n = bn + nl;
            Bs[kl][nl] = (k < K && n < N) ? Bw[(size_t)k * N + n] : 0.f;
        }
        __syncthreads();
#pragma unroll
        for (int kk = 0; kk < 16; kk++) {
            const float4 av = *reinterpret_cast<const float4*>(&As[kk][ty * 4]);
            const float4 bv = *reinterpret_cast<const float4*>(&Bs[kk][tx * 4]);
            const float a4[4] = {av.x, av.y, av.z, av.w};
            const float b4[4] = {bv.x, bv.y, bv.z, bv.w};
#pragma unroll
            for (int i = 0; i < 4; i++)
#pragma unroll
                for (int j = 0; j < 4; j++)
                    acc[i][j] = fmaf(a4[i], b4[j], acc[i][j]);
        }
        __syncthreads();
    }
#pragma unroll
    for (int i = 0; i < 4; i++) {
        int m = bm + ty * 4 + i;
        if (m >= M) continue;
#pragma unroll
        for (int j = 0; j < 4; j++) {
            int n = bn + tx * 4 + j;
            if (n >= N) continue;
            float v = acc[i][j] + bias[n];
            if constexpr (ACT == 1) v = gelu_f(v);
            if constexpr (RES == 1) v += res[(size_t)m * N + n];
            C[(size_t)m * N + n] = v;
        }
    }
}

// ---------------------------------------------------------------------------
// Skinny fp32 GEMM, M=32, KSPLIT partials. A transposed: At[K][32].
// ---------------------------------------------------------------------------
__global__ __launch_bounds__(256) void skinny_part_k(
    const float* __restrict__ At, const float* __restrict__ Bw,
    float* __restrict__ P, int N, int Kc)
{
    const int bn = blockIdx.x * 128;
    const int s  = blockIdx.y;
    const int k0 = s * Kc;
    const int t = threadIdx.x, tn = t & 63, tm = t >> 6;
    const int n0 = bn + tn * 2;
    float2 acc[8];
#pragma unroll
    for (int i = 0; i < 8; i++) { acc[i].x = 0.f; acc[i].y = 0.f; }

    if (n0 + 2 <= N) {
#pragma unroll 2
        for (int k = 0; k < Kc; k++) {
            const float* ar = At + (size_t)(k0 + k) * 32 + tm * 8;
            f4v a0 = *(const f4v*)ar;
            f4v a1 = *(const f4v*)(ar + 4);
            float2 bv = *(const float2*)&Bw[(size_t)(k0 + k) * N + n0];
#pragma unroll
            for (int i = 0; i < 4; i++) {
                acc[i].x     = fmaf(a0[i], bv.x, acc[i].x);
                acc[i].y     = fmaf(a0[i], bv.y, acc[i].y);
                acc[i + 4].x = fmaf(a1[i], bv.x, acc[i + 4].x);
                acc[i + 4].y = fmaf(a1[i], bv.y, acc[i + 4].y);
            }
        }
#pragma unroll
        for (int i = 0; i < 8; i++)
            *(float2*)&P[((size_t)s * 32 + tm * 8 + i) * N + n0] = acc[i];
    } else {
        if (n0 >= N) return;
        bool v1 = (n0 + 1) < N;
        for (int k = 0; k < Kc; k++) {
            const float* ar = At + (size_t)(k0 + k) * 32 + tm * 8;
            f4v a0 = *(const f4v*)ar;
            f4v a1 = *(const f4v*)(ar + 4);
            float b0 = Bw[(size_t)(k0 + k) * N + n0];
            float b1 = v1 ? Bw[(size_t)(k0 + k) * N + n0 + 1] : 0.f;
#pragma unroll
            for (int i = 0; i < 4; i++) {
                acc[i].x     = fmaf(a0[i], b0, acc[i].x);
                acc[i].y     = fmaf(a0[i], b1, acc[i].y);
                acc[i + 4].x = fmaf(a1[i], b0, acc[i + 4].x);
                acc[i + 4].y = fmaf(a1[i], b1, acc[i + 4].y);
            }
        }
        for (int i = 0; i < 8; i++) {
            P[((size_t)s * 32 + tm * 8 + i) * N + n0] = acc[i].x;
            if (v1) P[((size_t)s * 32 + tm * 8 + i) * N + n0 + 1] = acc[i].y;
        }
    }
}

// combine partials: C[32][N] = act(sum_s P + bias) [+res]; optional CT[N][32]
template<int ACT, int RES>
__global__ void comb_k(const float* __restrict__ P, const float* __restrict__ bias,
                       const float* res, float* C, float* CT, int N, int KS)
{
    int idx = blockIdx.x * 256 + threadIdx.x;
    if (idx >= 32 * N) return;
    int m = idx / N, n = idx - m * N;
    float v = bias[n];
    for (int ss = 0; ss < KS; ss++) v += P[((size_t)ss * 32 + m) * N + n];
    if constexpr (ACT == 1) v = gelu_f(v);
    if constexpr (RES == 1) v += res[idx];
    C[idx] = v;
    if (CT) CT[(size_t)n * 32 + m] = v;
}

__global__ void depth_k(const float* __restrict__ d2,
                        const float* __restrict__ w3, const float* __restrict__ b3,
                        float* __restrict__ out)
{
    int idx = blockIdx.x * 256 + threadIdx.x;
    if (idx >= NB * 128 * 128) return;
    int b = idx >> 14;
    int rem = idx & 16383;
    int y = rem >> 7, x = rem & 127;
    const float* base = d2 + (((size_t)b * 64 + (y >> 1)) * 64 + (x >> 1)) * 32;
    float acc = b3[0];
#pragma unroll
    for (int ci = 0; ci < 32; ci++) acc = fmaf(base[ci], w3[ci], acc);
    out[idx] = softplus_f(acc);
}

// layernorm row; writes y [32][768] and yT [768][32]
__global__ void ln_k(const float* __restrict__ x, const float* __restrict__ g,
                     const float* __restrict__ bb, float* __restrict__ y,
                     float* __restrict__ yT)
{
    int r = blockIdx.x, t = threadIdx.x;
    __shared__ float red[256];
    float v0 = x[(size_t)r * ND + t];
    float v1 = x[(size_t)r * ND + 256 + t];
    float v2 = x[(size_t)r * ND + 512 + t];
    red[t] = v0 + v1 + v2;
    __syncthreads();
    for (int s = 128; s > 0; s >>= 1) { if (t < s) red[t] += red[t + s]; __syncthreads(); }
    float mean = red[0] * (1.0f / ND);
    __syncthreads();
    float d0 = v0 - mean, d1 = v1 - mean, d2 = v2 - mean;
    red[t] = d0 * d0 + d1 * d1 + d2 * d2;
    __syncthreads();
    for (int s = 128; s > 0; s >>= 1) { if (t < s) red[t] += red[t + s]; __syncthreads(); }
    float inv = 1.0f / sqrtf(red[0] * (1.0f / ND) + 1e-5f);
    float o0 = d0 * inv * g[t]       + bb[t];
    float o1 = d1 * inv * g[256 + t] + bb[256 + t];
    float o2 = d2 * inv * g[512 + t] + bb[512 + t];
    y[(size_t)r * ND + t]       = o0;
    y[(size_t)r * ND + 256 + t] = o1;
    y[(size_t)r * ND + 512 + t] = o2;
    yT[(size_t)t * 32 + r]         = o0;
    yT[(size_t)(256 + t) * 32 + r] = o1;
    yT[(size_t)(512 + t) * 32 + r] = o2;
}

// ---------------------------------------------------------------------------
// Attention (q-seq-len 1, wk/wv folded).
// ---------------------------------------------------------------------------
__global__ __launch_bounds__(256) void qw2_k(const float* __restrict__ Qp,
                                             const float* __restrict__ wk,
                                             __hip_bfloat16* __restrict__ qwbf)
{
    int c0 = blockIdx.x * 32, h = blockIdx.y;
    int t = threadIdx.x;
    if (h >= 8) {
        for (int i = t; i < 32 * 32; i += 256) {
            int b = i >> 5, c = i & 31;
            qwbf[((size_t)(b * 16 + h)) * 768 + c0 + c] = __float2bfloat16(0.f);
        }
        return;
    }
    __shared__ float Qps[32][100];
    __shared__ float wks[32][100];
    for (int i = t; i < 32 * 96; i += 256) {
        int b = i / 96, d = i - b * 96;
        Qps[b][d] = Qp[(size_t)b * 768 + h * 96 + d];
    }
    for (int i = t; i < 32 * 96; i += 256) {
        int c = i / 96, d = i - c * 96;
        wks[c][d] = wk[(size_t)(c0 + c) * 768 + h * 96 + d];
    }
    __syncthreads();
    int b = t & 31, cl = t >> 5;
#pragma unroll
    for (int cc = 0; cc < 4; cc++) {
        int c = cl * 4 + cc;
        float a = 0.f;
#pragma unroll
        for (int d = 0; d < 96; d += 4) {
            f4v qv = *(const f4v*)&Qps[b][d];
            f4v wv2 = *(const f4v*)&wks[c][d];
            a += qv[0] * wv2[0] + qv[1] * wv2[1] + qv[2] * wv2[2] + qv[3] * wv2[3];
        }
        qwbf[((size_t)(b * 16 + h)) * 768 + c0 + c] = __float2bfloat16(a);
    }
}

// scores: sraw[b][h][k] = tok[b,k,:]·qw[b,h,:]  (MFMA, 128 tok x 16 heads)
__global__ __launch_bounds__(256) void scores_mfma_k(
    const __hip_bfloat16* __restrict__ tok, const __hip_bfloat16* __restrict__ qwbf,
    float* __restrict__ sraw, __hip_bfloat16* __restrict__ attbf)
{
    __shared__ __hip_bfloat16 As[128 * 32];
    __shared__ __hip_bfloat16 Bs[16 * 32];
    const int b = blockIdx.y, bm = blockIdx.x * 128;
    const int tid = threadIdx.x, lane = tid & 63, wave = tid >> 6;
    const int r0 = tid >> 2, kb = (tid & 3) * 8;
    f4v acc[2];
    acc[0] = (f4v)0.f; acc[1] = (f4v)0.f;
    for (int k0 = 0; k0 < 768; k0 += 32) {
#pragma unroll
        for (int c = 0; c < 2; c++) {
            const int row = r0 + c * 64;
            gld_lds16(tok + ((size_t)(b * 1024 + bm + row)) * 768 + k0 + kb,
                      &As[row * 32 + kb]);
        }
        if (tid < 64)
            gld_lds16(qwbf + ((size_t)(b * 16 + (tid >> 2))) * 768 + k0 + (tid & 3) * 8,
                      &Bs[(tid >> 2) * 32 + (tid & 3) * 8]);
        __syncthreads();
        const int koff = (lane >> 4) * 8;
        s8v bf = *(const s8v*)&Bs[(lane & 15) * 32 + koff];
#pragma unroll
        for (int i = 0; i < 2; i++) {
            s8v af = *(const s8v*)&As[(wave * 32 + i * 16 + (lane & 15)) * 32 + koff];
            acc[i] = __builtin_amdgcn_mfma_f32_16x16x32_bf16(af, bf, acc[i], 0, 0, 0);
        }
        __syncthreads();
    }
    const int n = lane & 15;
#pragma unroll
    for (int i = 0; i < 2; i++) {
        const int mb = bm + wave * 32 + i * 16 + ((lane >> 4) << 2);
#pragma unroll
        for (int g = 0; g < 4; g++) {
            const int m = mb + g;
            if (n < 8)
                sraw[(((size_t)(b * 16 + n)) << 10) + m] = acc[i][g];
            else
                attbf[(((size_t)(b * 16 + n)) << 10) + m] = __float2bfloat16(0.f);
        }
    }
}

// softmax over k for one (b,h) row; writes attbf bf16
__global__ __launch_bounds__(256) void softmax_row_k(
    const float* __restrict__ sraw, __hip_bfloat16* __restrict__ attbf)
{
    int r = blockIdx.x;
    int b = r >> 3, h = r & 7;
    size_t base = ((size_t)(b * 16 + h)) << 10;
    int t = threadIdx.x, lane = t & 63, w = t >> 6;
    const float scale = 0.1020620726159658f;
    f4v v = *(const f4v*)&sraw[base + (t << 2)];
    float x0 = v[0] * scale, x1 = v[1] * scale, x2 = v[2] * scale, x3 = v[3] * scale;
    __shared__ float red[4];
    __shared__ float gm, gs;
    float m = fmaxf(fmaxf(x0, x1), fmaxf(x2, x3));
#pragma unroll
    for (int off = 32; off > 0; off >>= 1) m = fmaxf(m, __shfl_xor(m, off, 64));
    if (lane == 0) red[w] = m;
    __syncthreads();
    if (t == 0) gm = fmaxf(fmaxf(red[0], red[1]), fmaxf(red[2], red[3]));
    __syncthreads();
    float M = gm;
    float e0 = expf(x0 - M), e1 = expf(x1 - M), e2 = expf(x2 - M), e3 = expf(x3 - M);
    float s = e0 + e1 + e2 + e3;
#pragma unroll
    for (int off = 32; off > 0; off >>= 1) s += __shfl_xor(s, off, 64);
    __syncthreads();
    if (lane == 0) red[w] = s;
    __syncthreads();
    if (t == 0) gs = 1.0f / (red[0] + red[1] + red[2] + red[3]);
    __syncthreads();
    float inv = gs;
    union { __hip_bfloat16 h4[4]; short4 s4; } u;
    u.h4[0] = __float2bfloat16(e0 * inv);
    u.h4[1] = __float2bfloat16(e1 * inv);
    u.h4[2] = __float2bfloat16(e2 * inv);
    u.h4[3] = __float2bfloat16(e3 * inv);
    *(short4*)&attbf[base + (t << 2)] = u.s4;
}

// ctx^T: ctxf[b][h][c] = sum_k att[b,h,k] * tokT[b,c,k]  (MFMA, 128 c x 16 h)
__global__ __launch_bounds__(256) void ctxT_mfma_k(
    const __hip_bfloat16* __restrict__ tokT, const __hip_bfloat16* __restrict__ attbf,
    float* __restrict__ ctxf)
{
    __shared__ __hip_bfloat16 As[128 * 32];
    __shared__ __hip_bfloat16 Bs[16 * 32];
    const int b = blockIdx.y, bm = blockIdx.x * 128;
    const int tid = threadIdx.x, lane = tid & 63, wave = tid >> 6;
    const int r0 = tid >> 2, kb = (tid & 3) * 8;
    f4v acc[2];
    acc[0] = (f4v)0.f; acc[1] = (f4v)0.f;
    for (int k0 = 0; k0 < 1024; k0 += 32) {
#pragma unroll
        for (int c = 0; c < 2; c++) {
            const int row = r0 + c * 64;
            gld_lds16(tokT + ((size_t)(b * 768 + bm + row)) * 1024 + k0 + kb,
                      &As[row * 32 + kb]);
        }
        if (tid < 64)
            gld_lds16(attbf + ((size_t)(b * 16 + (tid >> 2))) * 1024 + k0 + (tid & 3) * 8,
                      &Bs[(tid >> 2) * 32 + (tid & 3) * 8]);
        __syncthreads();
        const int koff = (lane >> 4) * 8;
        s8v bf = *(const s8v*)&Bs[(lane & 15) * 32 + koff];
#pragma unroll
        for (int i = 0; i < 2; i++) {
            s8v af = *(const s8v*)&As[(wave * 32 + i * 16 + (lane & 15)) * 32 + koff];
            acc[i] = __builtin_amdgcn_mfma_f32_16x16x32_bf16(af, bf, acc[i], 0, 0, 0);
        }
        __syncthreads();
    }
    const int n = lane & 15;
    if (n < 8) {
#pragma unroll
        for (int i = 0; i < 2; i++) {
            const int mb = bm + wave * 32 + i * 16 + ((lane >> 4) << 2);
#pragma unroll
            for (int g = 0; g < 4; g++)
                ctxf[((size_t)(b * 8 + n)) * 768 + mb + g] = acc[i][g];
        }
    }
}

// o[b, h*96+d] = sum_c ctx[b,h,c] * wv[c, h*96+d] + bv; writes ob and obT
__global__ __launch_bounds__(128) void ovp_k(
    const float* __restrict__ ctxf, const float* __restrict__ wv,
    const float* __restrict__ bv, float* __restrict__ ob, float* __restrict__ obT)
{
    int bh = blockIdx.x; int b = bh >> 3, h = bh & 7;
    __shared__ float cs[768];
    int t = threadIdx.x;
    for (int i = t; i < 768; i += 128)
        cs[i] = ctxf[(size_t)(b * 8 + h) * 768 + i];
    __syncthreads();
    if (t < 96) {
        const float* wp = wv + h * 96 + t;
        float a = bv[h * 96 + t];
#pragma unroll 8
        for (int c = 0; c < ND; c++)
            a = fmaf(cs[c], wp[(size_t)c * ND], a);
        ob[(size_t)b * ND + h * 96 + t] = a;
        obT[(size_t)(h * 96 + t) * 32 + b] = a;
    }
}

__global__ void build_qa_k(const int* __restrict__ intent,
                           const float* __restrict__ past,
                           float* __restrict__ qA)
{
    int idx = blockIdx.x * 256 + threadIdx.x;
    if (idx >= NB * 99) return;
    int b = idx / 99, j = idx - b * 99;
    float v;
    if (j < 3) v = (intent[b] - 1 == j) ? 1.f : 0.f;
    else       v = past[b * 96 + (j - 3)];
    qA[idx] = v;
}

__global__ void integrate_k(const float* __restrict__ cp,
                            const float* __restrict__ past,
                            float* __restrict__ out)
{
    int idx = blockIdx.x * 256 + threadIdx.x;
    if (idx >= NB * NK) return;
    int b = idx / NK, k = idx - b * NK;
    const float* pl = past + b * 96 + 90;
    float x = pl[0], y = pl[1], vx = pl[2], vy = pl[3];
    float s  = sqrtf(vx * vx + vy * vy + 1e-6f);
    float hd = atan2f(vy, vx);
    const float* cpk = cp + (size_t)b * 3000 + k * 60;
    float* o0 = out +        (size_t)b * 3000 + k * 60;
    float* o1 = out + 96000 + (size_t)b * 3000 + k * 60;
    float* c5 = out + 1946688 + (size_t)b * 3000 + k * 60;
    float* c6 = out + 2042688 + (size_t)b * 3000 + k * 60;
    const float DT = 0.25f;
    for (int t = 0; t < NT; t++) {
        float a = tanhf(cpk[t * 2 + 0]) * 8.0f;
        float w = tanhf(cpk[t * 2 + 1]) * 1.0f;
        x += s * cosf(hd) * DT;
        y += s * sinf(hd) * DT;
        o0[t * 2 + 0] = x; o0[t * 2 + 1] = y;
        o1[t * 2 + 0] = x; o1[t * 2 + 1] = y;
        c5[t * 2 + 0] = a; c5[t * 2 + 1] = w;
        c6[t * 2 + 0] = a; c6[t * 2 + 1] = w;
        hd += w * DT;
        s = fmaxf(s + a * DT, 0.f);
    }
}

__global__ void qscore_k(const float* __restrict__ q, float* __restrict__ out2)
{
    int idx = blockIdx.x * 256 + threadIdx.x;
    if (idx >= NB * NK * ND) return;
    int r = idx / ND, d = idx - r * ND;
    int b = r / NK;
    out2[idx] = q[(size_t)b * ND + d];
}

__global__ void score_k(const float* __restrict__ sc2, const float* __restrict__ w,
                        const float* __restrict__ bias, float* __restrict__ out)
{
    int r = blockIdx.x * 4 + (threadIdx.x >> 6);
    int lane = threadIdx.x & 63;
    if (r >= NB * NK) return;
    float acc = 0.f;
    for (int d = lane; d < ND; d += 64) acc = fmaf(sc2[(size_t)r * ND + d], w[d], acc);
    for (int off = 32; off > 0; off >>= 1) acc += __shfl_down(acc, off, 64);
    if (lane == 0) out[r] = acc + bias[0];
}

// ---------------------------------------------------------------------------
static inline void gemm(hipStream_t st, int act, int hasres,
                        const float* A, const float* Bw, const float* bias,
                        const float* res, float* C, int M, int N, int K)
{
    dim3 blk(16, 16), grd((N + 63) / 64, (M + 63) / 64);
    if      (act == 0 && !hasres) gemm_k<0, 0><<<grd, blk, 0, st>>>(A, Bw, bias, res, C, M, N, K);
    else if (act == 0 &&  hasres) gemm_k<0, 1><<<grd, blk, 0, st>>>(A, Bw, bias, res, C, M, N, K);
    else                          gemm_k<1, 0><<<grd, blk, 0, st>>>(A, Bw, bias, res, C, M, N, K);
}

extern "C" void kernel_launch(void* const* d_in, const int* in_sizes, int n_in,
                              void* d_out, int out_size, void* d_ws, size_t ws_size,
                              hipStream_t stream)
{
    const float* feats_vit = (const float*)d_in[0];
    const float* past      = (const float*)d_in[1];
    const int*   intent    = (const int*)  d_in[2];
    const float* qi_w   = (const float*)d_in[3];
    const float* qi_b   = (const float*)d_in[4];
    const float* va1_w  = (const float*)d_in[5];
    const float* va1_b  = (const float*)d_in[6];
    const float* va2_w  = (const float*)d_in[7];
    const float* va2_b  = (const float*)d_in[8];
    const float* pos    = (const float*)d_in[9];
    const float* ln1_g  = (const float*)d_in[10];
    const float* ln1_b  = (const float*)d_in[11];
    const float* wq     = (const float*)d_in[12];
    const float* bq     = (const float*)d_in[13];
    const float* wk     = (const float*)d_in[14];
    const float* bk     = (const float*)d_in[15];
    const float* wv     = (const float*)d_in[16];
    const float* bv     = (const float*)d_in[17];
    const float* wo     = (const float*)d_in[18];
    const float* bo     = (const float*)d_in[19];
    const float* ln2_g  = (const float*)d_in[20];
    const float* ln2_b  = (const float*)d_in[21];
    const float* m1w    = (const float*)d_in[22];
    const float* m1b    = (const float*)d_in[23];
    const float* m2w    = (const float*)d_in[24];
    const float* m2b    = (const float*)d_in[25];
    const float* dg1w   = (const float*)d_in[26];
    const float* dg1b   = (const float*)d_in[27];
    const float* dg2w   = (const float*)d_in[28];
    const float* dg2b   = (const float*)d_in[29];
    const float* dg3w   = (const float*)d_in[30];
    const float* dg3b   = (const float*)d_in[31];
    const float* td1w   = (const float*)d_in[32];
    const float* td1b   = (const float*)d_in[33];
    const float* td2w   = (const float*)d_in[34];
    const float* td2b   = (const float*)d_in[35];
    const float* td3w   = (const float*)d_in[36];
    const float* td3b   = (const float*)d_in[37];
    const float* tf1w   = (const float*)d_in[38];
    const float* tf1b   = (const float*)d_in[39];
    const float* tf2w   = (const float*)d_in[40];
    const float* tf2b   = (const float*)d_in[41];
    const float* sd1w   = (const float*)d_in[42];
    const float* sd1b   = (const float*)d_in[43];
    const float* sd2w   = (const float*)d_in[44];
    const float* sd2b   = (const float*)d_in[45];
    const float* sd3w   = (const float*)d_in[46];
    const float* sd3b   = (const float*)d_in[47];

    float* out = (float*)d_out;
    float* ws  = (float*)d_ws;

    // workspace layout (float units)
    size_t off = 0;
    float* bufB    = ws + off; off += (size_t)NB * ND * NTOK;   // early: xpad2; late: tokT + attn scratch
    float* xpad_f  = ws + off; off += 14201856;                 // input padded bf16 / tokens bf16
    float* c1pad_f = ws + off; off += 14201856;                 // conv1 padded bf16 / late: score bufs + d1pad
    float* wTc_f   = ws + off; off += 2654208;
    float* dg1wT_f = ws + off; off += 221184;
    float* dg2wT_f = ws + off; off += 9216;
    float* tf2wT_f = ws + off; off += 294912;
    float* sd1wT_f = ws + off; off += 589824;
    float* sd2wT_f = ws + off; off += 294912;
    float* d2      = ws + off; off += (size_t)NB * 4096 * 32;
    float* q       = ws + off; off += NB * ND;
    float* qn      = ws + off; off += NB * ND;
    float* Qp      = ws + off; off += NB * ND;
    float* ob      = ws + off; off += NB * ND;
    float* hm      = ws + off; off += NB * NMLP;
    float* qA      = ws + off; off += NB * 128;
    float* h1      = ws + off; off += NB * ND;
    float* h2      = ws + off; off += NB * ND;
    float* cp      = ws + off; off += NB * 3000;
    // bf16 aliases
    __hip_bfloat16* xpad   = (__hip_bfloat16*)xpad_f;
    __hip_bfloat16* c1pad  = (__hip_bfloat16*)c1pad_f;
    __hip_bfloat16* xpad2  = (__hip_bfloat16*)bufB;             // feats padded bf16 (pre-transformer)
    __hip_bfloat16* tokbf  = (__hip_bfloat16*)xpad_f;           // tokens bf16 (after conv1 frees xpad)
    __hip_bfloat16* wTc    = (__hip_bfloat16*)wTc_f;
    __hip_bfloat16* dg1wT  = (__hip_bfloat16*)dg1wT_f;
    __hip_bfloat16* dg2wT  = (__hip_bfloat16*)dg2wT_f;
    __hip_bfloat16* tf2wT  = (__hip_bfloat16*)tf2wT_f;
    __hip_bfloat16* sd1wT  = (__hip_bfloat16*)sd1wT_f;
    __hip_bfloat16* sd2wT  = (__hip_bfloat16*)sd2wT_f;
    // attention + skinny scratch carved from bufB (xpad2 dead after dg1).
    // sizes in FLOAT units (bf16 buffers take elems/2 floats):
    //   tokT  [32][768][1024] bf16 -> 12,582,912 f   @ 0
    //   qwbf  [32][16][768]   bf16 ->    196,608 f   @ 12,582,912
    //   sraw  [32][16][1024]  f32  ->    524,288 f   @ 12,779,520
    //   attbf [32][16][1024]  bf16 ->    262,144 f   @ 13,303,808
    //   ctxf  [32][8][768]    f32  ->    196,608 f   @ 13,565,952
    //   Pb    16x32x3072      f32  ->  1,572,864 f   @ 13,762,560
    //   qnT/obT/qT/h1T/h2T 768x32, hmT 3072x32       @ 15,335,424 ..
    __hip_bfloat16* tokT  = (__hip_bfloat16*)bufB;
    __hip_bfloat16* qwbf  = (__hip_bfloat16*)(bufB + 12582912);
    float* sraw           = bufB + 12779520;
    __hip_bfloat16* attbf = (__hip_bfloat16*)(bufB + 13303808);
    float* ctxf           = bufB + 13565952;
    float* Pb             = bufB + 13762560;
    float* qnT            = bufB + 15335424;
    float* obT            = bufB + 15360000;
    float* hmT            = bufB + 15384576;
    float* qT             = bufB + 15482880;
    float* h1T            = bufB + 15507456;
    float* h2T            = bufB + 15532032;
    // score-head buffers carved from c1pad region (free after conv2)
    float* tfa            = c1pad_f;
    __hip_bfloat16* tfabf = (__hip_bfloat16*)(c1pad_f + 1228800);
    __hip_bfloat16* tfbbf = (__hip_bfloat16*)(c1pad_f + 1867776);
    __hip_bfloat16* catbf = (__hip_bfloat16*)(c1pad_f + 2506752);
    __hip_bfloat16* s1bf  = (__hip_bfloat16*)(c1pad_f + 3784704);
    float* s2             = c1pad_f + 4423680;
    __hip_bfloat16* d1pad = (__hip_bfloat16*)(c1pad_f + 8000000);
    (void)ws_size; (void)n_in; (void)in_sizes; (void)out_size;

    const int M_PIX = NB * 1024;

    // ---- prep: borders, input transpose, conv weights ----
    pad_border_k<<<(32 * 132 * 192 + 255) / 256, 256, 0, stream>>>(xpad, c1pad);
    pad_border_k<<<(32 * 132 * 192 + 255) / 256, 256, 0, stream>>>(xpad2, xpad2);
    pad_border64_k<<<(32 * 132 * 16 + 255) / 256, 256, 0, stream>>>(d1pad);
    nchw2pad_bf_k<<<dim3(ND / 32, NTOK / 32, NB), dim3(32, 8), 0, stream>>>(feats_vit, xpad);
    convw_bf_k<<<(768 * 768 * 9 + 255) / 256, 256, 0, stream>>>(va1_w, wTc, 768, 768);

    // ---- conv1 (gelu -> padded bf16) ----
    mfma_gemm_k<1, 1, 1><<<dim3(6, 256), 256, 0, stream>>>(
        xpad, wTc, va1_b, nullptr, nullptr, c1pad, nullptr, M_PIX, ND, ND * 9);
    convw_bf_k<<<(768 * 768 * 9 + 255) / 256, 256, 0, stream>>>(va2_w, wTc, 768, 768);
    // ---- conv2 (-> padded bf16 feats + bf16 tokens with +pos) ----
    mfma_gemm_k<1, 0, 3><<<dim3(6, 256), 256, 0, stream>>>(
        c1pad, wTc, va2_b, nullptr, tokbf, xpad2, pos, M_PIX, ND, ND * 9);

    // ---- depth branch ----
    convw_bf_k<<<(64 * 768 * 9 + 255) / 256, 256, 0, stream>>>(dg1w, dg1wT, 64, 768);
    mfma_dg1_k<<<256, 256, 0, stream>>>(xpad2, dg1wT, dg1b, d1pad);
    convw_bf_k<<<(32 * 64 * 9 + 255) / 256, 256, 0, stream>>>(dg2w, dg2wT, 32, 64);
    mfma_dg2_k<<<1024, 256, 0, stream>>>(d1pad, dg2wT, dg2b, d2);
    depth_k<<<(NB * 16384 + 255) / 256, 256, 0, stream>>>(d2, dg3w, dg3b, out + 1422400);

    // ---- token transpose (xpad2/bufB now dead; tokT overwrites it) ----
    tokT_k<<<dim3(24, 32, 32), dim3(32, 8), 0, stream>>>(tokbf, tokT);

    // ---- q init ----
    build_qa_k<<<(NB * 99 + 255) / 256, 256, 0, stream>>>(intent, past, qA);
    gemm(stream, 0, 0, qA, qi_w, qi_b, nullptr, q, NB, ND, 99);

    const int CB768  = (32 * 768 + 255) / 256;
    const int CB3072 = (32 * 3072 + 255) / 256;
    const int CB3000 = (32 * 3000 + 255) / 256;

    // ---- transformer layers ----
    for (int i = 0; i < NL; i++) {
        const size_t W = (size_t)i * ND * ND;
        ln_k<<<NB, 256, 0, stream>>>(q, ln1_g + i * ND, ln1_b + i * ND, qn, qnT);
        skinny_part_k<<<dim3(6, 16), 256, 0, stream>>>(qnT, wq + W, Pb, 768, 48);
        comb_k<0, 0><<<CB768, 256, 0, stream>>>(Pb, bq + i * ND, nullptr, Qp, nullptr, 768, 16);
        qw2_k<<<dim3(24, 16), 256, 0, stream>>>(Qp, wk + W, qwbf);
        scores_mfma_k<<<dim3(8, 32), 256, 0, stream>>>(tokbf, qwbf, sraw, attbf);
        softmax_row_k<<<NB * NKH, 256, 0, stream>>>(sraw, attbf);
        ctxT_mfma_k<<<dim3(6, 32), 256, 0, stream>>>(tokT, attbf, ctxf);
        ovp_k<<<NB * NKH, 128, 0, stream>>>(ctxf, wv + W, bv + i * ND, ob, obT);
        skinny_part_k<<<dim3(6, 16), 256, 0, stream>>>(obT, wo + W, Pb, 768, 48);
        comb_k<0, 1><<<CB768, 256, 0, stream>>>(Pb, bo + i * ND, q, q, nullptr, 768, 16);
        ln_k<<<NB, 256, 0, stream>>>(q, ln2_g + i * ND, ln2_b + i * ND, qn, qnT);
        skinny_part_k<<<dim3(24, 16), 256, 0, stream>>>(qnT, m1w + (size_t)i * ND * NMLP, Pb, 3072, 48);
        comb_k<1, 0><<<CB3072, 256, 0, stream>>>(Pb, m1b + i * NMLP, nullptr, hm, hmT, 3072, 16);
        skinny_part_k<<<dim3(6, 16), 256, 0, stream>>>(hmT, m2w + (size_t)i * NMLP * ND, Pb, 768, 192);
        comb_k<0, 1><<<CB768, 256, 0, stream>>>(Pb, m2b + i * ND, q, q,
                                                (i == NL - 1) ? qT : nullptr, 768, 16);
    }

    // ---- trajectory decoder ----
    skinny_part_k<<<dim3(6, 16), 256, 0, stream>>>(qT, td1w, Pb, 768, 48);
    comb_k<1, 0><<<CB768, 256, 0, stream>>>(Pb, td1b, nullptr, h1, h1T, 768, 16);
    skinny_part_k<<<dim3(6, 16), 256, 0, stream>>>(h1T, td2w, Pb, 768, 48);
    comb_k<1, 0><<<CB768, 256, 0, stream>>>(Pb, td2b, nullptr, h2, h2T, 768, 16);
    skinny_part_k<<<dim3(24, 16), 256, 0, stream>>>(h2T, td3w, Pb, 3000, 48);
    comb_k<0, 0><<<CB3000, 256, 0, stream>>>(Pb, td3b, nullptr, cp, nullptr, 3000, 16);
    integrate_k<<<(NB * NK + 255) / 256, 256, 0, stream>>>(cp, past, out);

    // ---- score head ----
    qscore_k<<<(NB * NK * ND + 255) / 256, 256, 0, stream>>>(q, out + 192000);
    gemm(stream, 1, 0, out, tf1w, tf1b, nullptr, tfa, NB * NK, ND, 60);
    f2bf_k<<<(1600 * 768 + 255) / 256, 256, 0, stream>>>(tfa, tfabf, 1600 * 768);
    wt_bf_k<<<dim3(24, 24), dim3(32, 8), 0, stream>>>(tf2w, tf2wT, 768, 768);
    mfma_gemm_k<0, 1, 2><<<dim3(6, 13), 256, 0, stream>>>(
        tfabf, tf2wT, tf2b, nullptr, tfbbf, nullptr, nullptr, 1600, 768, 768);
    cat_bf_k<<<(1664 * 1536 + 255) / 256, 256, 0, stream>>>(q, tfbbf, catbf);
    wt_bf_k<<<dim3(24, 48), dim3(32, 8), 0, stream>>>(sd1w, sd1wT, 1536, 768);
    mfma_gemm_k<0, 1, 2><<<dim3(6, 13), 256, 0, stream>>>(
        catbf, sd1wT, sd1b, nullptr, s1bf, nullptr, nullptr, 1600, 768, 1536);
    wt_bf_k<<<dim3(24, 24), dim3(32, 8), 0, stream>>>(sd2w, sd2wT, 768, 768);
    mfma_gemm_k<0, 1, 0><<<dim3(6, 13), 256, 0, stream>>>(
        s1bf, sd2wT, sd2b, s2, nullptr, nullptr, nullptr, 1600, 768, 768);
    score_k<<<(NB * NK + 3) / 4, 256, 0, stream>>>(s2, sd3w, sd3b, out + 1420800);
}

// Round 5
// 2748.976 us; speedup vs baseline: 2.5453x; 1.0910x over previous
//
#include <hip/hip_runtime.h>
#include <hip/hip_bf16.h>
#include <math.h>

// ---------------------------------------------------------------------------
// DeepMonocularModel — r8 resubmit (round-4 bench was an infra failure):
//  * LDS XOR-swizzle on all MFMA tiles: stage source k-slot permuted by
//    ((tid>>3)&3), read koff = ((lane>>4)^((lane>>1)&3))*8. Kills the 8-way
//    bank conflict of 64B-row fragment reads (SQ_LDS_BANK_CONFLICT 4.25e7).
//  * conv K-loop address incrementalization: padded-NHWC makes the 3x3 walk
//    contiguous per tap-row; ptr += 32 each kstep, +31*768 at rr==3/6.
//    Removes ~36 VALU/kstep of recompute (VALUBusy was 55%).
// ---------------------------------------------------------------------------

#define NB   32
#define ND   768
#define NTOK 1024
#define NKH  8
#define NHD  96
#define NL   4
#define NMLP 3072
#define NK   50
#define NT   30

typedef short  s8v __attribute__((ext_vector_type(8)));
typedef float  f4v __attribute__((ext_vector_type(4)));

__device__ __forceinline__ float gelu_f(float x) {
    return 0.5f * x * (1.0f + erff(x * 0.70710678118654752f));
}
__device__ __forceinline__ float softplus_f(float x) {
    return x > 0.f ? x + log1pf(expf(-x)) : log1pf(expf(x));
}
__device__ __forceinline__ void gld_lds16(const void* g, void* l) {
    __builtin_amdgcn_global_load_lds(
        (const __attribute__((address_space(1))) void*)g,
        (__attribute__((address_space(3))) void*)l, 16, 0, 0);
}

// ---------------------------------------------------------------------------
// bf16 MFMA GEMM, 128x128 tile. C = act(A_view @ Bt^T + bias)
// ---------------------------------------------------------------------------
template<int AMODE, int ACT, int OUT>
__global__ __launch_bounds__(256) void mfma_gemm_k(
    const __hip_bfloat16* __restrict__ A,
    const __hip_bfloat16* __restrict__ Bt,
    const float* __restrict__ bias,
    float* __restrict__ Cf,
    __hip_bfloat16* __restrict__ Cb,
    __hip_bfloat16* __restrict__ Cpad,
    const float* __restrict__ pos,
    int M, int N, int K)
{
    __shared__ __hip_bfloat16 As[128 * 32];
    __shared__ __hip_bfloat16 Bs[128 * 32];
    const int tid  = threadIdx.x;
    const int lane = tid & 63;
    const int wave = tid >> 6;
    const int wm = wave >> 1, wn = wave & 1;
    int bxi = blockIdx.x, byi = blockIdx.y;
    {
        const int nbx = gridDim.x;
        const int nwg = nbx * gridDim.y;
        if ((nwg & 7) == 0) {
            int id = byi * nbx + bxi;
            const int cpx = nwg >> 3;
            id = (id & 7) * cpx + (id >> 3);
            bxi = id % nbx; byi = id / nbx;
        }
    }
    const int bm = byi * 128, bn = bxi * 128;
    const int r0 = tid >> 2;
    const int kb_dst = (tid & 3) * 8;                           // linear LDS slot
    const int kb_src = (((tid & 3) ^ ((tid >> 3) & 3)) << 3);   // swizzled src slot

    f4v acc[4][4];
#pragma unroll
    for (int i = 0; i < 4; i++)
#pragma unroll
        for (int j = 0; j < 4; j++) acc[i][j] = (f4v)0.f;

    // incremental global pointers
    const __hip_bfloat16* ga0;
    const __hip_bfloat16* ga1;
    if constexpr (AMODE == 0) {
        ga0 = A + (size_t)(bm + r0) * K + kb_src;
        ga1 = A + (size_t)(bm + r0 + 64) * K + kb_src;
    } else {
        int gm0 = bm + r0;
        int b0 = gm0 >> 10, y0 = (gm0 >> 5) & 31, x0 = gm0 & 31;
        ga0 = A + ((((size_t)b0 * 34 + y0) * 34 + x0) * 768 + kb_src);
        int gm1 = bm + r0 + 64;
        int b1 = gm1 >> 10, y1 = (gm1 >> 5) & 31, x1 = gm1 & 31;
        ga1 = A + ((((size_t)b1 * 34 + y1) * 34 + x1) * 768 + kb_src);
    }
    const __hip_bfloat16* gb0 = Bt + (size_t)(bn + r0) * K + kb_src;
    const __hip_bfloat16* gb1 = Bt + (size_t)(bn + r0 + 64) * K + kb_src;

    const int koff = (((lane >> 4) ^ ((lane >> 1) & 3)) << 3);  // swizzled read slot
    int kin = 0, rr = 0;
    for (int k0 = 0; k0 < K; k0 += 32) {
        gld_lds16(ga0, &As[r0 * 32 + kb_dst]);
        gld_lds16(ga1, &As[(r0 + 64) * 32 + kb_dst]);
        gld_lds16(gb0, &Bs[r0 * 32 + kb_dst]);
        gld_lds16(gb1, &Bs[(r0 + 64) * 32 + kb_dst]);
        __syncthreads();
        s8v af[4], bfv[4];
#pragma unroll
        for (int i = 0; i < 4; i++)
            af[i] = *(const s8v*)(&As[(wm * 64 + i * 16 + (lane & 15)) * 32 + koff]);
#pragma unroll
        for (int j = 0; j < 4; j++)
            bfv[j] = *(const s8v*)(&Bs[(wn * 64 + j * 16 + (lane & 15)) * 32 + koff]);
#pragma unroll
        for (int i = 0; i < 4; i++)
#pragma unroll
            for (int j = 0; j < 4; j++)
                acc[i][j] = __builtin_amdgcn_mfma_f32_16x16x32_bf16(af[i], bfv[j], acc[i][j], 0, 0, 0);
        __syncthreads();
        ga0 += 32; ga1 += 32; gb0 += 32; gb1 += 32;
        if constexpr (AMODE == 1) {
            kin += 32;
            if (kin == 768) {
                kin = 0; rr++;
                if (rr == 3 || rr == 6) { ga0 += 31 * 768; ga1 += 31 * 768; }
            }
        }
    }
#pragma unroll
    for (int i = 0; i < 4; i++) {
        const int mbase = bm + wm * 64 + i * 16 + ((lane >> 4) << 2);
#pragma unroll
        for (int j = 0; j < 4; j++) {
            const int n = bn + wn * 64 + j * 16 + (lane & 15);
            const float bs = bias[n];
#pragma unroll
            for (int g = 0; g < 4; g++) {
                const int m = mbase + g;
                if (m >= M) continue;
                float v = acc[i][j][g] + bs;
                if constexpr (ACT == 1) v = gelu_f(v);
                if constexpr (OUT == 0) {
                    Cf[(size_t)m * N + n] = v;
                } else if constexpr (OUT == 1) {
                    int b = m >> 10, y = (m >> 5) & 31, x = m & 31;
                    Cpad[(((size_t)b * 34 + y + 1) * 34 + (x + 1)) * 768 + n] =
                        __float2bfloat16(v);
                } else if constexpr (OUT == 2) {
                    Cb[(size_t)m * N + n] = __float2bfloat16(v);
                } else {
                    int b = m >> 10, y = (m >> 5) & 31, x = m & 31;
                    Cpad[(((size_t)b * 34 + y + 1) * 34 + (x + 1)) * 768 + n] =
                        __float2bfloat16(v);
                    Cb[(size_t)m * 768 + n] =
                        __float2bfloat16(v + pos[(size_t)(m & 1023) * 768 + n]);
                }
            }
        }
    }
}

// ---------------------------------------------------------------------------
// dg1: 3x3 conv 768->64, gelu, in/out padded bf16. Tile 128(M)x64(N).
// ---------------------------------------------------------------------------
__global__ __launch_bounds__(256) void mfma_dg1_k(
    const __hip_bfloat16* __restrict__ A,
    const __hip_bfloat16* __restrict__ Bt,
    const float* __restrict__ bias,
    __hip_bfloat16* __restrict__ Dpad)
{
    __shared__ __hip_bfloat16 As[128 * 32];
    __shared__ __hip_bfloat16 Bs[64 * 32];
    const int tid = threadIdx.x, lane = tid & 63, wave = tid >> 6;
    const int wm = wave >> 1, wn = wave & 1;
    const int bm = blockIdx.x * 128;
    const int r0 = tid >> 2;
    const int kb_dst = (tid & 3) * 8;
    const int kb_src = (((tid & 3) ^ ((tid >> 3) & 3)) << 3);
    f4v acc[4][2];
#pragma unroll
    for (int i = 0; i < 4; i++)
#pragma unroll
        for (int j = 0; j < 2; j++) acc[i][j] = (f4v)0.f;

    const __hip_bfloat16* ga0;
    const __hip_bfloat16* ga1;
    {
        int gm0 = bm + r0;
        int b0 = gm0 >> 10, y0 = (gm0 >> 5) & 31, x0 = gm0 & 31;
        ga0 = A + ((((size_t)b0 * 34 + y0) * 34 + x0) * 768 + kb_src);
        int gm1 = bm + r0 + 64;
        int b1 = gm1 >> 10, y1 = (gm1 >> 5) & 31, x1 = gm1 & 31;
        ga1 = A + ((((size_t)b1 * 34 + y1) * 34 + x1) * 768 + kb_src);
    }
    const __hip_bfloat16* gb0 = Bt + (size_t)r0 * 6912 + kb_src;

    const int koff = (((lane >> 4) ^ ((lane >> 1) & 3)) << 3);
    int kin = 0, rr = 0;
    for (int k0 = 0; k0 < 6912; k0 += 32) {
        gld_lds16(ga0, &As[r0 * 32 + kb_dst]);
        gld_lds16(ga1, &As[(r0 + 64) * 32 + kb_dst]);
        gld_lds16(gb0, &Bs[r0 * 32 + kb_dst]);
        __syncthreads();
        s8v af[4], bfv[2];
#pragma unroll
        for (int i = 0; i < 4; i++)
            af[i] = *(const s8v*)(&As[(wm * 64 + i * 16 + (lane & 15)) * 32 + koff]);
#pragma unroll
        for (int j = 0; j < 2; j++)
            bfv[j] = *(const s8v*)(&Bs[(wn * 32 + j * 16 + (lane & 15)) * 32 + koff]);
#pragma unroll
        for (int i = 0; i < 4; i++)
#pragma unroll
            for (int j = 0; j < 2; j++)
                acc[i][j] = __builtin_amdgcn_mfma_f32_16x16x32_bf16(af[i], bfv[j], acc[i][j], 0, 0, 0);
        __syncthreads();
        ga0 += 32; ga1 += 32; gb0 += 32;
        kin += 32;
        if (kin == 768) {
            kin = 0; rr++;
            if (rr == 3 || rr == 6) { ga0 += 31 * 768; ga1 += 31 * 768; }
        }
    }
#pragma unroll
    for (int i = 0; i < 4; i++) {
        const int mbase = bm + wm * 64 + i * 16 + ((lane >> 4) << 2);
#pragma unroll
        for (int j = 0; j < 2; j++) {
            const int n = wn * 32 + j * 16 + (lane & 15);
            const float bs = bias[n];
#pragma unroll
            for (int g = 0; g < 4; g++) {
                const int m = mbase + g;
                float v = gelu_f(acc[i][j][g] + bs);
                int b = m >> 10, y = (m >> 5) & 31, x = m & 31;
                Dpad[(((size_t)b * 34 + y + 1) * 34 + (x + 1)) * 64 + n] =
                    __float2bfloat16(v);
            }
        }
    }
}

// ---------------------------------------------------------------------------
// dg2: up2 + 3x3 conv 64->32, gelu. Tile 128(M)x32(N).
// ---------------------------------------------------------------------------
__global__ __launch_bounds__(256) void mfma_dg2_k(
    const __hip_bfloat16* __restrict__ A,
    const __hip_bfloat16* __restrict__ Bt,
    const float* __restrict__ bias,
    float* __restrict__ D)
{
    __shared__ __hip_bfloat16 As[128 * 32];
    __shared__ __hip_bfloat16 Bs[32 * 32];
    const int tid = threadIdx.x, lane = tid & 63, wave = tid >> 6;
    const int bm = blockIdx.x * 128;
    const int r0 = tid >> 2;
    const int kb_dst = (tid & 3) * 8;
    const int kb_src = (((tid & 3) ^ ((tid >> 3) & 3)) << 3);
    f4v acc[2][2];
#pragma unroll
    for (int i = 0; i < 2; i++)
#pragma unroll
        for (int j = 0; j < 2; j++) acc[i][j] = (f4v)0.f;

    const int koff = (((lane >> 4) ^ ((lane >> 1) & 3)) << 3);
    int rr = 0, kin = 0;
    for (int k0 = 0; k0 < 576; k0 += 32) {
#pragma unroll
        for (int c = 0; c < 2; c++) {
            const int row = r0 + c * 64;
            int gm = bm + row;
            int b = gm >> 12, y = (gm >> 6) & 63, x = gm & 63;
            int dy = rr / 3, dx = rr - dy * 3;
            int iy = (y + dy + 1) >> 1, ix = (x + dx + 1) >> 1;
            gld_lds16(A + (((size_t)b * 34 + iy) * 34 + ix) * 64 + kin + kb_src,
                      &As[row * 32 + kb_dst]);
        }
        if (tid < 128)
            gld_lds16(Bt + (size_t)r0 * 576 + k0 + kb_src, &Bs[r0 * 32 + kb_dst]);
        __syncthreads();
        s8v af[2], bfv[2];
#pragma unroll
        for (int i = 0; i < 2; i++)
            af[i] = *(const s8v*)(&As[(wave * 32 + i * 16 + (lane & 15)) * 32 + koff]);
#pragma unroll
        for (int j = 0; j < 2; j++)
            bfv[j] = *(const s8v*)(&Bs[(j * 16 + (lane & 15)) * 32 + koff]);
#pragma unroll
        for (int i = 0; i < 2; i++)
#pragma unroll
            for (int j = 0; j < 2; j++)
                acc[i][j] = __builtin_amdgcn_mfma_f32_16x16x32_bf16(af[i], bfv[j], acc[i][j], 0, 0, 0);
        __syncthreads();
        kin += 32; if (kin == 64) { kin = 0; rr++; }
    }
#pragma unroll
    for (int i = 0; i < 2; i++) {
        const int mbase = bm + wave * 32 + i * 16 + ((lane >> 4) << 2);
#pragma unroll
        for (int j = 0; j < 2; j++) {
            const int n = j * 16 + (lane & 15);
            const float bs = bias[n];
#pragma unroll
            for (int g = 0; g < 4; g++) {
                const int m = mbase + g;
                D[(size_t)m * 32 + n] = gelu_f(acc[i][j][g] + bs);
            }
        }
    }
}

// NCHW fp32 -> padded NHWC bf16 interior
__global__ void nchw2pad_bf_k(const float* __restrict__ src, __hip_bfloat16* __restrict__ dst)
{
    __shared__ float tile[32][33];
    int b = blockIdx.z, n0 = blockIdx.y * 32, c0 = blockIdx.x * 32;
    int tx = threadIdx.x, ty = threadIdx.y;
#pragma unroll
    for (int i = ty; i < 32; i += 8)
        tile[i][tx] = src[((size_t)b * ND + c0 + i) * NTOK + n0 + tx];
    __syncthreads();
#pragma unroll
    for (int i = ty; i < 32; i += 8) {
        int n = n0 + i, y = n >> 5, x = n & 31;
        dst[(((size_t)b * 34 + y + 1) * 34 + (x + 1)) * 768 + c0 + tx] =
            __float2bfloat16(tile[tx][i]);
    }
}

// zero borders of two padded-768 bf16 buffers
__global__ void pad_border_k(__hip_bfloat16* __restrict__ p1, __hip_bfloat16* __restrict__ p2)
{
    int idx = blockIdx.x * 256 + threadIdx.x;
    if (idx >= 32 * 132 * 192) return;
    int c4 = idx % 192;
    int cell = (idx / 192) % 132;
    int b = idx / (192 * 132);
    int yy, xx;
    if      (cell < 34)  { yy = 0;  xx = cell; }
    else if (cell < 68)  { yy = 33; xx = cell - 34; }
    else if (cell < 100) { yy = cell - 68 + 1;  xx = 0; }
    else                 { yy = cell - 100 + 1; xx = 33; }
    size_t o = (((size_t)b * 34 + yy) * 34 + xx) * 768 + c4 * 4;
    *reinterpret_cast<uint2*>(p1 + o) = make_uint2(0u, 0u);
    *reinterpret_cast<uint2*>(p2 + o) = make_uint2(0u, 0u);
}

// zero border of padded-64 bf16 buffer
__global__ void pad_border64_k(__hip_bfloat16* __restrict__ p)
{
    int idx = blockIdx.x * 256 + threadIdx.x;
    if (idx >= 32 * 132 * 16) return;
    int c4 = idx % 16;
    int cell = (idx / 16) % 132;
    int b = idx / (16 * 132);
    int yy, xx;
    if      (cell < 34)  { yy = 0;  xx = cell; }
    else if (cell < 68)  { yy = 33; xx = cell - 34; }
    else if (cell < 100) { yy = cell - 68 + 1;  xx = 0; }
    else                 { yy = cell - 100 + 1; xx = 33; }
    size_t o = (((size_t)b * 34 + yy) * 34 + xx) * 64 + c4 * 4;
    *reinterpret_cast<uint2*>(p + o) = make_uint2(0u, 0u);
}

// conv weight OIHW fp32 -> bf16 [n][tap*Cin+ci]
__global__ void convw_bf_k(const float* __restrict__ w, __hip_bfloat16* __restrict__ wT,
                           int Cout, int Cin)
{
    int idx = blockIdx.x * 256 + threadIdx.x;
    if (idx >= Cout * Cin * 9) return;
    int n = idx / (Cin * 9), k = idx - n * (Cin * 9);
    int r = k / Cin, ci = k - r * Cin;
    wT[idx] = __float2bfloat16(w[((size_t)n * Cin + ci) * 9 + r]);
}

// [K][N] fp32 -> [N][K] bf16, tiled transpose
__global__ void wt_bf_k(const float* __restrict__ w, __hip_bfloat16* __restrict__ wT,
                        int K, int N)
{
    __shared__ float t[32][33];
    int k0 = blockIdx.y * 32, n0 = blockIdx.x * 32;
    int tx = threadIdx.x, ty = threadIdx.y;
#pragma unroll
    for (int i = ty; i < 32; i += 8)
        t[i][tx] = w[(size_t)(k0 + i) * N + n0 + tx];
    __syncthreads();
#pragma unroll
    for (int i = ty; i < 32; i += 8)
        wT[(size_t)(n0 + i) * K + k0 + tx] = __float2bfloat16(t[tx][i]);
}

// tokens [b][1024][768] bf16 -> tokT [b][768][1024] bf16
__global__ void tokT_k(const __hip_bfloat16* __restrict__ tok, __hip_bfloat16* __restrict__ tokT)
{
    __shared__ __hip_bfloat16 tl[32][33];
    int b = blockIdx.z, k0 = blockIdx.y * 32, c0 = blockIdx.x * 32;
    int tx = threadIdx.x, ty = threadIdx.y;
#pragma unroll
    for (int i = ty; i < 32; i += 8)
        tl[i][tx] = tok[((size_t)(b * 1024 + k0 + i)) * 768 + c0 + tx];
    __syncthreads();
#pragma unroll
    for (int i = ty; i < 32; i += 8)
        tokT[((size_t)(b * 768 + c0 + i)) * 1024 + k0 + tx] = tl[tx][i];
}

// fp32 -> bf16 flat convert
__global__ void f2bf_k(const float* __restrict__ s, __hip_bfloat16* __restrict__ d, int n)
{
    int i = blockIdx.x * 256 + threadIdx.x;
    if (i < n) d[i] = __float2bfloat16(s[i]);
}

// catbf[r][0:768] = bf16(q[r/50]); catbf[r][768:1536] = tfbbf[r]; rows>=1600 -> 0
__global__ void cat_bf_k(const float* __restrict__ q, const __hip_bfloat16* __restrict__ tf,
                         __hip_bfloat16* __restrict__ cat)
{
    int idx = blockIdx.x * 256 + threadIdx.x;
    if (idx >= 1664 * 1536) return;
    int r = idx / 1536, c = idx - r * 1536;
    __hip_bfloat16 v;
    if (r < 1600)
        v = (c < 768) ? __float2bfloat16(q[(size_t)(r / 50) * 768 + c])
                      : tf[(size_t)r * 768 + (c - 768)];
    else v = __float2bfloat16(0.f);
    cat[idx] = v;
}

// ---------------------------------------------------------------------------
// fp32 tiled GEMM — kept for qi (K=99) and tf1 (M=1600)
// ---------------------------------------------------------------------------
template<int ACT, int RES>
__global__ __launch_bounds__(256) void gemm_k(
    const float* __restrict__ A, const float* __restrict__ Bw,
    const float* __restrict__ bias, const float* __restrict__ res,
    float* __restrict__ C, int M, int N, int K)
{
    __shared__ float As[16][68];
    __shared__ float Bs[16][68];
    const int tx = threadIdx.x, ty = threadIdx.y;
    const int tid = ty * 16 + tx;
    const int bm = blockIdx.y * 64, bn = blockIdx.x * 64;
    float acc[4][4] = {};

    for (int k0 = 0; k0 < K; k0 += 16) {
#pragma unroll
        for (int i = 0; i < 4; i++) {
            int idx = i * 256 + tid;
            int ml = idx >> 4, kl = idx & 15;
            int m = bm + ml, k = k0 + kl;
            As[kl][ml] = (m < M && k < K) ? A[(size_t)m * K + k] : 0.f;
        }
#pragma unroll
        for (int i = 0; i < 4; i++) {
            int idx = i * 256 + tid;
            int nl = idx & 63, kl = idx >> 6;
            int k = k0 + kl, n = bn + nl;
            Bs[kl][nl] = (k < K && n < N) ? Bw[(size_t)k * N + n] : 0.f;
        }
        __syncthreads();
#pragma unroll
        for (int kk = 0; kk < 16; kk++) {
            const float4 av = *reinterpret_cast<const float4*>(&As[kk][ty * 4]);
            const float4 bv = *reinterpret_cast<const float4*>(&Bs[kk][tx * 4]);
            const float a4[4] = {av.x, av.y, av.z, av.w};
            const float b4[4] = {bv.x, bv.y, bv.z, bv.w};
#pragma unroll
            for (int i = 0; i < 4; i++)
#pragma unroll
                for (int j = 0; j < 4; j++)
                    acc[i][j] = fmaf(a4[i], b4[j], acc[i][j]);
        }
        __syncthreads();
    }
#pragma unroll
    for (int i = 0; i < 4; i++) {
        int m = bm + ty * 4 + i;
        if (m >= M) continue;
#pragma unroll
        for (int j = 0; j < 4; j++) {
            int n = bn + tx * 4 + j;
            if (n >= N) continue;
            float v = acc[i][j] + bias[n];
            if constexpr (ACT == 1) v = gelu_f(v);
            if constexpr (RES == 1) v += res[(size_t)m * N + n];
            C[(size_t)m * N + n] = v;
        }
    }
}

// ---------------------------------------------------------------------------
// Skinny fp32 GEMM, M=32, KSPLIT partials. A transposed: At[K][32].
// ---------------------------------------------------------------------------
__global__ __launch_bounds__(256) void skinny_part_k(
    const float* __restrict__ At, const float* __restrict__ Bw,
    float* __restrict__ P, int N, int Kc)
{
    const int bn = blockIdx.x * 128;
    const int s  = blockIdx.y;
    const int k0 = s * Kc;
    const int t = threadIdx.x, tn = t & 63, tm = t >> 6;
    const int n0 = bn + tn * 2;
    float2 acc[8];
#pragma unroll
    for (int i = 0; i < 8; i++) { acc[i].x = 0.f; acc[i].y = 0.f; }

    if (n0 + 2 <= N) {
#pragma unroll 2
        for (int k = 0; k < Kc; k++) {
            const float* ar = At + (size_t)(k0 + k) * 32 + tm * 8;
            f4v a0 = *(const f4v*)ar;
            f4v a1 = *(const f4v*)(ar + 4);
            float2 bv = *(const float2*)&Bw[(size_t)(k0 + k) * N + n0];
#pragma unroll
            for (int i = 0; i < 4; i++) {
                acc[i].x     = fmaf(a0[i], bv.x, acc[i].x);
                acc[i].y     = fmaf(a0[i], bv.y, acc[i].y);
                acc[i + 4].x = fmaf(a1[i], bv.x, acc[i + 4].x);
                acc[i + 4].y = fmaf(a1[i], bv.y, acc[i + 4].y);
            }
        }
#pragma unroll
        for (int i = 0; i < 8; i++)
            *(float2*)&P[((size_t)s * 32 + tm * 8 + i) * N + n0] = acc[i];
    } else {
        if (n0 >= N) return;
        bool v1 = (n0 + 1) < N;
        for (int k = 0; k < Kc; k++) {
            const float* ar = At + (size_t)(k0 + k) * 32 + tm * 8;
            f4v a0 = *(const f4v*)ar;
            f4v a1 = *(const f4v*)(ar + 4);
            float b0 = Bw[(size_t)(k0 + k) * N + n0];
            float b1 = v1 ? Bw[(size_t)(k0 + k) * N + n0 + 1] : 0.f;
#pragma unroll
            for (int i = 0; i < 4; i++) {
                acc[i].x     = fmaf(a0[i], b0, acc[i].x);
                acc[i].y     = fmaf(a0[i], b1, acc[i].y);
                acc[i + 4].x = fmaf(a1[i], b0, acc[i + 4].x);
                acc[i + 4].y = fmaf(a1[i], b1, acc[i + 4].y);
            }
        }
        for (int i = 0; i < 8; i++) {
            P[((size_t)s * 32 + tm * 8 + i) * N + n0] = acc[i].x;
            if (v1) P[((size_t)s * 32 + tm * 8 + i) * N + n0 + 1] = acc[i].y;
        }
    }
}

// combine partials: C[32][N] = act(sum_s P + bias) [+res]; optional CT[N][32]
template<int ACT, int RES>
__global__ void comb_k(const float* __restrict__ P, const float* __restrict__ bias,
                       const float* res, float* C, float* CT, int N, int KS)
{
    int idx = blockIdx.x * 256 + threadIdx.x;
    if (idx >= 32 * N) return;
    int m = idx / N, n = idx - m * N;
    float v = bias[n];
    for (int ss = 0; ss < KS; ss++) v += P[((size_t)ss * 32 + m) * N + n];
    if constexpr (ACT == 1) v = gelu_f(v);
    if constexpr (RES == 1) v += res[idx];
    C[idx] = v;
    if (CT) CT[(size_t)n * 32 + m] = v;
}

__global__ void depth_k(const float* __restrict__ d2,
                        const float* __restrict__ w3, const float* __restrict__ b3,
                        float* __restrict__ out)
{
    int idx = blockIdx.x * 256 + threadIdx.x;
    if (idx >= NB * 128 * 128) return;
    int b = idx >> 14;
    int rem = idx & 16383;
    int y = rem >> 7, x = rem & 127;
    const float* base = d2 + (((size_t)b * 64 + (y >> 1)) * 64 + (x >> 1)) * 32;
    float acc = b3[0];
#pragma unroll
    for (int ci = 0; ci < 32; ci++) acc = fmaf(base[ci], w3[ci], acc);
    out[idx] = softplus_f(acc);
}

// layernorm row; writes y [32][768] and yT [768][32]
__global__ void ln_k(const float* __restrict__ x, const float* __restrict__ g,
                     const float* __restrict__ bb, float* __restrict__ y,
                     float* __restrict__ yT)
{
    int r = blockIdx.x, t = threadIdx.x;
    __shared__ float red[256];
    float v0 = x[(size_t)r * ND + t];
    float v1 = x[(size_t)r * ND + 256 + t];
    float v2 = x[(size_t)r * ND + 512 + t];
    red[t] = v0 + v1 + v2;
    __syncthreads();
    for (int s = 128; s > 0; s >>= 1) { if (t < s) red[t] += red[t + s]; __syncthreads(); }
    float mean = red[0] * (1.0f / ND);
    __syncthreads();
    float d0 = v0 - mean, d1 = v1 - mean, d2 = v2 - mean;
    red[t] = d0 * d0 + d1 * d1 + d2 * d2;
    __syncthreads();
    for (int s = 128; s > 0; s >>= 1) { if (t < s) red[t] += red[t + s]; __syncthreads(); }
    float inv = 1.0f / sqrtf(red[0] * (1.0f / ND) + 1e-5f);
    float o0 = d0 * inv * g[t]       + bb[t];
    float o1 = d1 * inv * g[256 + t] + bb[256 + t];
    float o2 = d2 * inv * g[512 + t] + bb[512 + t];
    y[(size_t)r * ND + t]       = o0;
    y[(size_t)r * ND + 256 + t] = o1;
    y[(size_t)r * ND + 512 + t] = o2;
    yT[(size_t)t * 32 + r]         = o0;
    yT[(size_t)(256 + t) * 32 + r] = o1;
    yT[(size_t)(512 + t) * 32 + r] = o2;
}

// ---------------------------------------------------------------------------
// Attention (q-seq-len 1, wk/wv folded).
// ---------------------------------------------------------------------------
__global__ __launch_bounds__(256) void qw2_k(const float* __restrict__ Qp,
                                             const float* __restrict__ wk,
                                             __hip_bfloat16* __restrict__ qwbf)
{
    int c0 = blockIdx.x * 32, h = blockIdx.y;
    int t = threadIdx.x;
    if (h >= 8) {
        for (int i = t; i < 32 * 32; i += 256) {
            int b = i >> 5, c = i & 31;
            qwbf[((size_t)(b * 16 + h)) * 768 + c0 + c] = __float2bfloat16(0.f);
        }
        return;
    }
    __shared__ float Qps[32][100];
    __shared__ float wks[32][100];
    for (int i = t; i < 32 * 96; i += 256) {
        int b = i / 96, d = i - b * 96;
        Qps[b][d] = Qp[(size_t)b * 768 + h * 96 + d];
    }
    for (int i = t; i < 32 * 96; i += 256) {
        int c = i / 96, d = i - c * 96;
        wks[c][d] = wk[(size_t)(c0 + c) * 768 + h * 96 + d];
    }
    __syncthreads();
    int b = t & 31, cl = t >> 5;
#pragma unroll
    for (int cc = 0; cc < 4; cc++) {
        int c = cl * 4 + cc;
        float a = 0.f;
#pragma unroll
        for (int d = 0; d < 96; d += 4) {
            f4v qv = *(const f4v*)&Qps[b][d];
            f4v wv2 = *(const f4v*)&wks[c][d];
            a += qv[0] * wv2[0] + qv[1] * wv2[1] + qv[2] * wv2[2] + qv[3] * wv2[3];
        }
        qwbf[((size_t)(b * 16 + h)) * 768 + c0 + c] = __float2bfloat16(a);
    }
}

// scores: sraw[b][h][k] = tok[b,k,:]·qw[b,h,:]  (MFMA, 128 tok x 16 heads)
__global__ __launch_bounds__(256) void scores_mfma_k(
    const __hip_bfloat16* __restrict__ tok, const __hip_bfloat16* __restrict__ qwbf,
    float* __restrict__ sraw, __hip_bfloat16* __restrict__ attbf)
{
    __shared__ __hip_bfloat16 As[128 * 32];
    __shared__ __hip_bfloat16 Bs[16 * 32];
    const int b = blockIdx.y, bm = blockIdx.x * 128;
    const int tid = threadIdx.x, lane = tid & 63, wave = tid >> 6;
    const int r0 = tid >> 2;
    const int kb_dst = (tid & 3) * 8;
    const int kb_src = (((tid & 3) ^ ((tid >> 3) & 3)) << 3);
    f4v acc[2];
    acc[0] = (f4v)0.f; acc[1] = (f4v)0.f;
    const __hip_bfloat16* ga0 = tok + ((size_t)(b * 1024 + bm + r0)) * 768 + kb_src;
    const __hip_bfloat16* ga1 = tok + ((size_t)(b * 1024 + bm + r0 + 64)) * 768 + kb_src;
    const __hip_bfloat16* gq  = qwbf + ((size_t)(b * 16 + r0)) * 768 + kb_src;  // tid<64
    const int koff = (((lane >> 4) ^ ((lane >> 1) & 3)) << 3);
    for (int k0 = 0; k0 < 768; k0 += 32) {
        gld_lds16(ga0, &As[r0 * 32 + kb_dst]);
        gld_lds16(ga1, &As[(r0 + 64) * 32 + kb_dst]);
        if (tid < 64)
            gld_lds16(gq, &Bs[r0 * 32 + kb_dst]);
        __syncthreads();
        s8v bf = *(const s8v*)&Bs[(lane & 15) * 32 + koff];
#pragma unroll
        for (int i = 0; i < 2; i++) {
            s8v af = *(const s8v*)&As[(wave * 32 + i * 16 + (lane & 15)) * 32 + koff];
            acc[i] = __builtin_amdgcn_mfma_f32_16x16x32_bf16(af, bf, acc[i], 0, 0, 0);
        }
        __syncthreads();
        ga0 += 32; ga1 += 32; gq += 32;
    }
    const int n = lane & 15;
#pragma unroll
    for (int i = 0; i < 2; i++) {
        const int mb = bm + wave * 32 + i * 16 + ((lane >> 4) << 2);
#pragma unroll
        for (int g = 0; g < 4; g++) {
            const int m = mb + g;
            if (n < 8)
                sraw[(((size_t)(b * 16 + n)) << 10) + m] = acc[i][g];
            else
                attbf[(((size_t)(b * 16 + n)) << 10) + m] = __float2bfloat16(0.f);
        }
    }
}

// softmax over k for one (b,h) row; writes attbf bf16
__global__ __launch_bounds__(256) void softmax_row_k(
    const float* __restrict__ sraw, __hip_bfloat16* __restrict__ attbf)
{
    int r = blockIdx.x;
    int b = r >> 3, h = r & 7;
    size_t base = ((size_t)(b * 16 + h)) << 10;
    int t = threadIdx.x, lane = t & 63, w = t >> 6;
    const float scale = 0.1020620726159658f;
    f4v v = *(const f4v*)&sraw[base + (t << 2)];
    float x0 = v[0] * scale, x1 = v[1] * scale, x2 = v[2] * scale, x3 = v[3] * scale;
    __shared__ float red[4];
    __shared__ float gm, gs;
    float m = fmaxf(fmaxf(x0, x1), fmaxf(x2, x3));
#pragma unroll
    for (int off = 32; off > 0; off >>= 1) m = fmaxf(m, __shfl_xor(m, off, 64));
    if (lane == 0) red[w] = m;
    __syncthreads();
    if (t == 0) gm = fmaxf(fmaxf(red[0], red[1]), fmaxf(red[2], red[3]));
    __syncthreads();
    float M = gm;
    float e0 = expf(x0 - M), e1 = expf(x1 - M), e2 = expf(x2 - M), e3 = expf(x3 - M);
    float s = e0 + e1 + e2 + e3;
#pragma unroll
    for (int off = 32; off > 0; off >>= 1) s += __shfl_xor(s, off, 64);
    __syncthreads();
    if (lane == 0) red[w] = s;
    __syncthreads();
    if (t == 0) gs = 1.0f / (red[0] + red[1] + red[2] + red[3]);
    __syncthreads();
    float inv = gs;
    union { __hip_bfloat16 h4[4]; short4 s4; } u;
    u.h4[0] = __float2bfloat16(e0 * inv);
    u.h4[1] = __float2bfloat16(e1 * inv);
    u.h4[2] = __float2bfloat16(e2 * inv);
    u.h4[3] = __float2bfloat16(e3 * inv);
    *(short4*)&attbf[base + (t << 2)] = u.s4;
}

// ctx^T: ctxf[b][h][c] = sum_k att[b,h,k] * tokT[b,c,k]  (MFMA, 128 c x 16 h)
__global__ __launch_bounds__(256) void ctxT_mfma_k(
    const __hip_bfloat16* __restrict__ tokT, const __hip_bfloat16* __restrict__ attbf,
    float* __restrict__ ctxf)
{
    __shared__ __hip_bfloat16 As[128 * 32];
    __shared__ __hip_bfloat16 Bs[16 * 32];
    const int b = blockIdx.y, bm = blockIdx.x * 128;
    const int tid = threadIdx.x, lane = tid & 63, wave = tid >> 6;
    const int r0 = tid >> 2;
    const int kb_dst = (tid & 3) * 8;
    const int kb_src = (((tid & 3) ^ ((tid >> 3) & 3)) << 3);
    f4v acc[2];
    acc[0] = (f4v)0.f; acc[1] = (f4v)0.f;
    const __hip_bfloat16* ga0 = tokT + ((size_t)(b * 768 + bm + r0)) * 1024 + kb_src;
    const __hip_bfloat16* ga1 = tokT + ((size_t)(b * 768 + bm + r0 + 64)) * 1024 + kb_src;
    const __hip_bfloat16* gq  = attbf + ((size_t)(b * 16 + r0)) * 1024 + kb_src;  // tid<64
    const int koff = (((lane >> 4) ^ ((lane >> 1) & 3)) << 3);
    for (int k0 = 0; k0 < 1024; k0 += 32) {
        gld_lds16(ga0, &As[r0 * 32 + kb_dst]);
        gld_lds16(ga1, &As[(r0 + 64) * 32 + kb_dst]);
        if (tid < 64)
            gld_lds16(gq, &Bs[r0 * 32 + kb_dst]);
        __syncthreads();
        s8v bf = *(const s8v*)&Bs[(lane & 15) * 32 + koff];
#pragma unroll
        for (int i = 0; i < 2; i++) {
            s8v af = *(const s8v*)&As[(wave * 32 + i * 16 + (lane & 15)) * 32 + koff];
            acc[i] = __builtin_amdgcn_mfma_f32_16x16x32_bf16(af, bf, acc[i], 0, 0, 0);
        }
        __syncthreads();
        ga0 += 32; ga1 += 32; gq += 32;
    }
    const int n = lane & 15;
    if (n < 8) {
#pragma unroll
        for (int i = 0; i < 2; i++) {
            const int mb = bm + wave * 32 + i * 16 + ((lane >> 4) << 2);
#pragma unroll
            for (int g = 0; g < 4; g++)
                ctxf[((size_t)(b * 8 + n)) * 768 + mb + g] = acc[i][g];
        }
    }
}

// o[b, h*96+d] = sum_c ctx[b,h,c] * wv[c, h*96+d] + bv; writes ob and obT
__global__ __launch_bounds__(128) void ovp_k(
    const float* __restrict__ ctxf, const float* __restrict__ wv,
    const float* __restrict__ bv, float* __restrict__ ob, float* __restrict__ obT)
{
    int bh = blockIdx.x; int b = bh >> 3, h = bh & 7;
    __shared__ float cs[768];
    int t = threadIdx.x;
    for (int i = t; i < 768; i += 128)
        cs[i] = ctxf[(size_t)(b * 8 + h) * 768 + i];
    __syncthreads();
    if (t < 96) {
        const float* wp = wv + h * 96 + t;
        float a = bv[h * 96 + t];
#pragma unroll 8
        for (int c = 0; c < ND; c++)
            a = fmaf(cs[c], wp[(size_t)c * ND], a);
        ob[(size_t)b * ND + h * 96 + t] = a;
        obT[(size_t)(h * 96 + t) * 32 + b] = a;
    }
}

__global__ void build_qa_k(const int* __restrict__ intent,
                           const float* __restrict__ past,
                           float* __restrict__ qA)
{
    int idx = blockIdx.x * 256 + threadIdx.x;
    if (idx >= NB * 99) return;
    int b = idx / 99, j = idx - b * 99;
    float v;
    if (j < 3) v = (intent[b] - 1 == j) ? 1.f : 0.f;
    else       v = past[b * 96 + (j - 3)];
    qA[idx] = v;
}

__global__ void integrate_k(const float* __restrict__ cp,
                            const float* __restrict__ past,
                            float* __restrict__ out)
{
    int idx = blockIdx.x * 256 + threadIdx.x;
    if (idx >= NB * NK) return;
    int b = idx / NK, k = idx - b * NK;
    const float* pl = past + b * 96 + 90;
    float x = pl[0], y = pl[1], vx = pl[2], vy = pl[3];
    float s  = sqrtf(vx * vx + vy * vy + 1e-6f);
    float hd = atan2f(vy, vx);
    const float* cpk = cp + (size_t)b * 3000 + k * 60;
    float* o0 = out +        (size_t)b * 3000 + k * 60;
    float* o1 = out + 96000 + (size_t)b * 3000 + k * 60;
    float* c5 = out + 1946688 + (size_t)b * 3000 + k * 60;
    float* c6 = out + 2042688 + (size_t)b * 3000 + k * 60;
    const float DT = 0.25f;
    for (int t = 0; t < NT; t++) {
        float a = tanhf(cpk[t * 2 + 0]) * 8.0f;
        float w = tanhf(cpk[t * 2 + 1]) * 1.0f;
        x += s * cosf(hd) * DT;
        y += s * sinf(hd) * DT;
        o0[t * 2 + 0] = x; o0[t * 2 + 1] = y;
        o1[t * 2 + 0] = x; o1[t * 2 + 1] = y;
        c5[t * 2 + 0] = a; c5[t * 2 + 1] = w;
        c6[t * 2 + 0] = a; c6[t * 2 + 1] = w;
        hd += w * DT;
        s = fmaxf(s + a * DT, 0.f);
    }
}

__global__ void qscore_k(const float* __restrict__ q, float* __restrict__ out2)
{
    int idx = blockIdx.x * 256 + threadIdx.x;
    if (idx >= NB * NK * ND) return;
    int r = idx / ND, d = idx - r * ND;
    int b = r / NK;
    out2[idx] = q[(size_t)b * ND + d];
}

__global__ void score_k(const float* __restrict__ sc2, const float* __restrict__ w,
                        const float* __restrict__ bias, float* __restrict__ out)
{
    int r = blockIdx.x * 4 + (threadIdx.x >> 6);
    int lane = threadIdx.x & 63;
    if (r >= NB * NK) return;
    float acc = 0.f;
    for (int d = lane; d < ND; d += 64) acc = fmaf(sc2[(size_t)r * ND + d], w[d], acc);
    for (int off = 32; off > 0; off >>= 1) acc += __shfl_down(acc, off, 64);
    if (lane == 0) out[r] = acc + bias[0];
}

// ---------------------------------------------------------------------------
static inline void gemm(hipStream_t st, int act, int hasres,
                        const float* A, const float* Bw, const float* bias,
                        const float* res, float* C, int M, int N, int K)
{
    dim3 blk(16, 16), grd((N + 63) / 64, (M + 63) / 64);
    if      (act == 0 && !hasres) gemm_k<0, 0><<<grd, blk, 0, st>>>(A, Bw, bias, res, C, M, N, K);
    else if (act == 0 &&  hasres) gemm_k<0, 1><<<grd, blk, 0, st>>>(A, Bw, bias, res, C, M, N, K);
    else                          gemm_k<1, 0><<<grd, blk, 0, st>>>(A, Bw, bias, res, C, M, N, K);
}

extern "C" void kernel_launch(void* const* d_in, const int* in_sizes, int n_in,
                              void* d_out, int out_size, void* d_ws, size_t ws_size,
                              hipStream_t stream)
{
    const float* feats_vit = (const float*)d_in[0];
    const float* past      = (const float*)d_in[1];
    const int*   intent    = (const int*)  d_in[2];
    const float* qi_w   = (const float*)d_in[3];
    const float* qi_b   = (const float*)d_in[4];
    const float* va1_w  = (const float*)d_in[5];
    const float* va1_b  = (const float*)d_in[6];
    const float* va2_w  = (const float*)d_in[7];
    const float* va2_b  = (const float*)d_in[8];
    const float* pos    = (const float*)d_in[9];
    const float* ln1_g  = (const float*)d_in[10];
    const float* ln1_b  = (const float*)d_in[11];
    const float* wq     = (const float*)d_in[12];
    const float* bq     = (const float*)d_in[13];
    const float* wk     = (const float*)d_in[14];
    const float* bk     = (const float*)d_in[15];
    const float* wv     = (const float*)d_in[16];
    const float* bv     = (const float*)d_in[17];
    const float* wo     = (const float*)d_in[18];
    const float* bo     = (const float*)d_in[19];
    const float* ln2_g  = (const float*)d_in[20];
    const float* ln2_b  = (const float*)d_in[21];
    const float* m1w    = (const float*)d_in[22];
    const float* m1b    = (const float*)d_in[23];
    const float* m2w    = (const float*)d_in[24];
    const float* m2b    = (const float*)d_in[25];
    const float* dg1w   = (const float*)d_in[26];
    const float* dg1b   = (const float*)d_in[27];
    const float* dg2w   = (const float*)d_in[28];
    const float* dg2b   = (const float*)d_in[29];
    const float* dg3w   = (const float*)d_in[30];
    const float* dg3b   = (const float*)d_in[31];
    const float* td1w   = (const float*)d_in[32];
    const float* td1b   = (const float*)d_in[33];
    const float* td2w   = (const float*)d_in[34];
    const float* td2b   = (const float*)d_in[35];
    const float* td3w   = (const float*)d_in[36];
    const float* td3b   = (const float*)d_in[37];
    const float* tf1w   = (const float*)d_in[38];
    const float* tf1b   = (const float*)d_in[39];
    const float* tf2w   = (const float*)d_in[40];
    const float* tf2b   = (const float*)d_in[41];
    const float* sd1w   = (const float*)d_in[42];
    const float* sd1b   = (const float*)d_in[43];
    const float* sd2w   = (const float*)d_in[44];
    const float* sd2b   = (const float*)d_in[45];
    const float* sd3w   = (const float*)d_in[46];
    const float* sd3b   = (const float*)d_in[47];

    float* out = (float*)d_out;
    float* ws  = (float*)d_ws;

    // workspace layout (float units)
    size_t off = 0;
    float* bufB    = ws + off; off += (size_t)NB * ND * NTOK;   // early: xpad2; late: tokT + attn scratch
    float* xpad_f  = ws + off; off += 14201856;                 // input padded bf16 / tokens bf16
    float* c1pad_f = ws + off; off += 14201856;                 // conv1 padded bf16 / late: score bufs + d1pad
    float* wTc_f   = ws + off; off += 2654208;
    float* dg1wT_f = ws + off; off += 221184;
    float* dg2wT_f = ws + off; off += 9216;
    float* tf2wT_f = ws + off; off += 294912;
    float* sd1wT_f = ws + off; off += 589824;
    float* sd2wT_f = ws + off; off += 294912;
    float* d2      = ws + off; off += (size_t)NB * 4096 * 32;
    float* q       = ws + off; off += NB * ND;
    float* qn      = ws + off; off += NB * ND;
    float* Qp      = ws + off; off += NB * ND;
    float* ob      = ws + off; off += NB * ND;
    float* hm      = ws + off; off += NB * NMLP;
    float* qA      = ws + off; off += NB * 128;
    float* h1      = ws + off; off += NB * ND;
    float* h2      = ws + off; off += NB * ND;
    float* cp      = ws + off; off += NB * 3000;
    // bf16 aliases
    __hip_bfloat16* xpad   = (__hip_bfloat16*)xpad_f;
    __hip_bfloat16* c1pad  = (__hip_bfloat16*)c1pad_f;
    __hip_bfloat16* xpad2  = (__hip_bfloat16*)bufB;             // feats padded bf16 (pre-transformer)
    __hip_bfloat16* tokbf  = (__hip_bfloat16*)xpad_f;           // tokens bf16 (after conv1 frees xpad)
    __hip_bfloat16* wTc    = (__hip_bfloat16*)wTc_f;
    __hip_bfloat16* dg1wT  = (__hip_bfloat16*)dg1wT_f;
    __hip_bfloat16* dg2wT  = (__hip_bfloat16*)dg2wT_f;
    __hip_bfloat16* tf2wT  = (__hip_bfloat16*)tf2wT_f;
    __hip_bfloat16* sd1wT  = (__hip_bfloat16*)sd1wT_f;
    __hip_bfloat16* sd2wT  = (__hip_bfloat16*)sd2wT_f;
    // attention + skinny scratch carved from bufB (xpad2 dead after dg1).
    __hip_bfloat16* tokT  = (__hip_bfloat16*)bufB;
    __hip_bfloat16* qwbf  = (__hip_bfloat16*)(bufB + 12582912);
    float* sraw           = bufB + 12779520;
    __hip_bfloat16* attbf = (__hip_bfloat16*)(bufB + 13303808);
    float* ctxf           = bufB + 13565952;
    float* Pb             = bufB + 13762560;
    float* qnT            = bufB + 15335424;
    float* obT            = bufB + 15360000;
    float* hmT            = bufB + 15384576;
    float* qT             = bufB + 15482880;
    float* h1T            = bufB + 15507456;
    float* h2T            = bufB + 15532032;
    // score-head buffers carved from c1pad region (free after conv2)
    float* tfa            = c1pad_f;
    __hip_bfloat16* tfabf = (__hip_bfloat16*)(c1pad_f + 1228800);
    __hip_bfloat16* tfbbf = (__hip_bfloat16*)(c1pad_f + 1867776);
    __hip_bfloat16* catbf = (__hip_bfloat16*)(c1pad_f + 2506752);
    __hip_bfloat16* s1bf  = (__hip_bfloat16*)(c1pad_f + 3784704);
    float* s2             = c1pad_f + 4423680;
    __hip_bfloat16* d1pad = (__hip_bfloat16*)(c1pad_f + 8000000);
    (void)ws_size; (void)n_in; (void)in_sizes; (void)out_size;

    const int M_PIX = NB * 1024;

    // ---- prep: borders, input transpose, conv weights ----
    pad_border_k<<<(32 * 132 * 192 + 255) / 256, 256, 0, stream>>>(xpad, c1pad);
    pad_border_k<<<(32 * 132 * 192 + 255) / 256, 256, 0, stream>>>(xpad2, xpad2);
    pad_border64_k<<<(32 * 132 * 16 + 255) / 256, 256, 0, stream>>>(d1pad);
    nchw2pad_bf_k<<<dim3(ND / 32, NTOK / 32, NB), dim3(32, 8), 0, stream>>>(feats_vit, xpad);
    convw_bf_k<<<(768 * 768 * 9 + 255) / 256, 256, 0, stream>>>(va1_w, wTc, 768, 768);

    // ---- conv1 (gelu -> padded bf16) ----
    mfma_gemm_k<1, 1, 1><<<dim3(6, 256), 256, 0, stream>>>(
        xpad, wTc, va1_b, nullptr, nullptr, c1pad, nullptr, M_PIX, ND, ND * 9);
    convw_bf_k<<<(768 * 768 * 9 + 255) / 256, 256, 0, stream>>>(va2_w, wTc, 768, 768);
    // ---- conv2 (-> padded bf16 feats + bf16 tokens with +pos) ----
    mfma_gemm_k<1, 0, 3><<<dim3(6, 256), 256, 0, stream>>>(
        c1pad, wTc, va2_b, nullptr, tokbf, xpad2, pos, M_PIX, ND, ND * 9);

    // ---- depth branch ----
    convw_bf_k<<<(64 * 768 * 9 + 255) / 256, 256, 0, stream>>>(dg1w, dg1wT, 64, 768);
    mfma_dg1_k<<<256, 256, 0, stream>>>(xpad2, dg1wT, dg1b, d1pad);
    convw_bf_k<<<(32 * 64 * 9 + 255) / 256, 256, 0, stream>>>(dg2w, dg2wT, 32, 64);
    mfma_dg2_k<<<1024, 256, 0, stream>>>(d1pad, dg2wT, dg2b, d2);
    depth_k<<<(NB * 16384 + 255) / 256, 256, 0, stream>>>(d2, dg3w, dg3b, out + 1422400);

    // ---- token transpose (xpad2/bufB now dead; tokT overwrites it) ----
    tokT_k<<<dim3(24, 32, 32), dim3(32, 8), 0, stream>>>(tokbf, tokT);

    // ---- q init ----
    build_qa_k<<<(NB * 99 + 255) / 256, 256, 0, stream>>>(intent, past, qA);
    gemm(stream, 0, 0, qA, qi_w, qi_b, nullptr, q, NB, ND, 99);

    const int CB768  = (32 * 768 + 255) / 256;
    const int CB3072 = (32 * 3072 + 255) / 256;
    const int CB3000 = (32 * 3000 + 255) / 256;

    // ---- transformer layers ----
    for (int i = 0; i < NL; i++) {
        const size_t W = (size_t)i * ND * ND;
        ln_k<<<NB, 256, 0, stream>>>(q, ln1_g + i * ND, ln1_b + i * ND, qn, qnT);
        skinny_part_k<<<dim3(6, 16), 256, 0, stream>>>(qnT, wq + W, Pb, 768, 48);
        comb_k<0, 0><<<CB768, 256, 0, stream>>>(Pb, bq + i * ND, nullptr, Qp, nullptr, 768, 16);
        qw2_k<<<dim3(24, 16), 256, 0, stream>>>(Qp, wk + W, qwbf);
        scores_mfma_k<<<dim3(8, 32), 256, 0, stream>>>(tokbf, qwbf, sraw, attbf);
        softmax_row_k<<<NB * NKH, 256, 0, stream>>>(sraw, attbf);
        ctxT_mfma_k<<<dim3(6, 32), 256, 0, stream>>>(tokT, attbf, ctxf);
        ovp_k<<<NB * NKH, 128, 0, stream>>>(ctxf, wv + W, bv + i * ND, ob, obT);
        skinny_part_k<<<dim3(6, 16), 256, 0, stream>>>(obT, wo + W, Pb, 768, 48);
        comb_k<0, 1><<<CB768, 256, 0, stream>>>(Pb, bo + i * ND, q, q, nullptr, 768, 16);
        ln_k<<<NB, 256, 0, stream>>>(q, ln2_g + i * ND, ln2_b + i * ND, qn, qnT);
        skinny_part_k<<<dim3(24, 16), 256, 0, stream>>>(qnT, m1w + (size_t)i * ND * NMLP, Pb, 3072, 48);
        comb_k<1, 0><<<CB3072, 256, 0, stream>>>(Pb, m1b + i * NMLP, nullptr, hm, hmT, 3072, 16);
        skinny_part_k<<<dim3(6, 16), 256, 0, stream>>>(hmT, m2w + (size_t)i * NMLP * ND, Pb, 768, 192);
        comb_k<0, 1><<<CB768, 256, 0, stream>>>(Pb, m2b + i * ND, q, q,
                                                (i == NL - 1) ? qT : nullptr, 768, 16);
    }

    // ---- trajectory decoder ----
    skinny_part_k<<<dim3(6, 16), 256, 0, stream>>>(qT, td1w, Pb, 768, 48);
    comb_k<1, 0><<<CB768, 256, 0, stream>>>(Pb, td1b, nullptr, h1, h1T, 768, 16);
    skinny_part_k<<<dim3(6, 16), 256, 0, stream>>>(h1T, td2w, Pb, 768, 48);
    comb_k<1, 0><<<CB768, 256, 0, stream>>>(Pb, td2b, nullptr, h2, h2T, 768, 16);
    skinny_part_k<<<dim3(24, 16), 256, 0, stream>>>(h2T, td3w, Pb, 3000, 48);
    comb_k<0, 0><<<CB3000, 256, 0, stream>>>(Pb, td3b, nullptr, cp, nullptr, 3000, 16);
    integrate_k<<<(NB * NK + 255) / 256, 256, 0, stream>>>(cp, past, out);

    // ---- score head ----
    qscore_k<<<(NB * NK * ND + 255) / 256, 256, 0, stream>>>(q, out + 192000);
    gemm(stream, 1, 0, out, tf1w, tf1b, nullptr, tfa, NB * NK, ND, 60);
    f2bf_k<<<(1600 * 768 + 255) / 256, 256, 0, stream>>>(tfa, tfabf, 1600 * 768);
    wt_bf_k<<<dim3(24, 24), dim3(32, 8), 0, stream>>>(tf2w, tf2wT, 768, 768);
    mfma_gemm_k<0, 1, 2><<<dim3(6, 13), 256, 0, stream>>>(
        tfabf, tf2wT, tf2b, nullptr, tfbbf, nullptr, nullptr, 1600, 768, 768);
    cat_bf_k<<<(1664 * 1536 + 255) / 256, 256, 0, stream>>>(q, tfbbf, catbf);
    wt_bf_k<<<dim3(24, 48), dim3(32, 8), 0, stream>>>(sd1w, sd1wT, 1536, 768);
    mfma_gemm_k<0, 1, 2><<<dim3(6, 13), 256, 0, stream>>>(
        catbf, sd1wT, sd1b, nullptr, s1bf, nullptr, nullptr, 1600, 768, 1536);
    wt_bf_k<<<dim3(24, 24), dim3(32, 8), 0, stream>>>(sd2w, sd2wT, 768, 768);
    mfma_gemm_k<0, 1, 0><<<dim3(6, 13), 256, 0, stream>>>(
        s1bf, sd2wT, sd2b, s2, nullptr, nullptr, nullptr, 1600, 768, 768);
    score_k<<<(NB * NK + 3) / 4, 256, 0, stream>>>(s2, sd3w, sd3b, out + 1420800);
}

// Round 6
// 2665.373 us; speedup vs baseline: 2.6251x; 1.0314x over previous
//
#include <hip/hip_runtime.h>
#include <hip/hip_bf16.h>
#include <math.h>

// ---------------------------------------------------------------------------
// DeepMonocularModel — r9 (= r8 + LDS-BW-bound conv fix):
//  * convs were LDS-read-bandwidth-bound (32KB/CU-kstep vs MFMA 80cyc ->
//    MfmaUtil 29.5% == predicted 30%). New conv kernel: 256x128 block tile,
//    128x64 wave tile (acc 8x4) -> 0.75x LDS bytes per FLOP.
//  * everything else unchanged from r8 (swizzle, incremental pointers,
//    skinny-KSPLIT transformer, MFMA attention).
// ---------------------------------------------------------------------------

#define NB   32
#define ND   768
#define NTOK 1024
#define NKH  8
#define NHD  96
#define NL   4
#define NMLP 3072
#define NK   50
#define NT   30

typedef short  s8v __attribute__((ext_vector_type(8)));
typedef float  f4v __attribute__((ext_vector_type(4)));

__device__ __forceinline__ float gelu_f(float x) {
    return 0.5f * x * (1.0f + erff(x * 0.70710678118654752f));
}
__device__ __forceinline__ float softplus_f(float x) {
    return x > 0.f ? x + log1pf(expf(-x)) : log1pf(expf(x));
}
__device__ __forceinline__ void gld_lds16(const void* g, void* l) {
    __builtin_amdgcn_global_load_lds(
        (const __attribute__((address_space(1))) void*)g,
        (__attribute__((address_space(3))) void*)l, 16, 0, 0);
}

// ---------------------------------------------------------------------------
// conv-only MFMA kernel: 256(M)x128(N) tile, wave tile 128x64, BK=32.
// A padded NHWC [32][34][34][768], 3x3 conv (K=6912), M=32768 exact.
// OUT 1: padded bf16 out (conv1). OUT 3: padded bf16 + tokens(+pos) (conv2).
// ---------------------------------------------------------------------------
template<int ACT, int OUT>
__global__ __launch_bounds__(256, 2) void mfma_conv_k(
    const __hip_bfloat16* __restrict__ A,
    const __hip_bfloat16* __restrict__ Bt,
    const float* __restrict__ bias,
    __hip_bfloat16* __restrict__ Cpad,
    __hip_bfloat16* __restrict__ Cb,
    const float* __restrict__ pos)
{
    __shared__ __hip_bfloat16 As[256 * 32];
    __shared__ __hip_bfloat16 Bs[128 * 32];
    const int tid = threadIdx.x, lane = tid & 63, wave = tid >> 6;
    const int wm = wave >> 1, wn = wave & 1;
    int bxi = blockIdx.x, byi = blockIdx.y;
    {   // XCD chunked swizzle (grid 6x128 = 768, 768%8==0)
        int id = byi * 6 + bxi;
        const int cpx = (6 * 128) >> 3;
        id = (id & 7) * cpx + (id >> 3);
        bxi = id % 6; byi = id / 6;
    }
    const int bm = byi * 256, bn = bxi * 128;
    const int r0 = tid >> 2;
    const int kb_dst = (tid & 3) * 8;
    const int kb_src = (((tid & 3) ^ ((tid >> 3) & 3)) << 3);

    f4v acc[8][4];
#pragma unroll
    for (int i = 0; i < 8; i++)
#pragma unroll
        for (int j = 0; j < 4; j++) acc[i][j] = (f4v)0.f;

    const __hip_bfloat16* ga[4];
#pragma unroll
    for (int c = 0; c < 4; c++) {
        int gm = bm + r0 + c * 64;
        int b = gm >> 10, y = (gm >> 5) & 31, x = gm & 31;
        ga[c] = A + ((((size_t)b * 34 + y) * 34 + x) * 768 + kb_src);
    }
    const __hip_bfloat16* gb0 = Bt + (size_t)(bn + r0) * 6912 + kb_src;
    const __hip_bfloat16* gb1 = Bt + (size_t)(bn + r0 + 64) * 6912 + kb_src;

    const int koff = (((lane >> 4) ^ ((lane >> 1) & 3)) << 3);
    int kin = 0, rr = 0;
    for (int k0 = 0; k0 < 6912; k0 += 32) {
#pragma unroll
        for (int c = 0; c < 4; c++)
            gld_lds16(ga[c], &As[(r0 + c * 64) * 32 + kb_dst]);
        gld_lds16(gb0, &Bs[r0 * 32 + kb_dst]);
        gld_lds16(gb1, &Bs[(r0 + 64) * 32 + kb_dst]);
        __syncthreads();
        s8v af[8], bfv[4];
#pragma unroll
        for (int i = 0; i < 8; i++)
            af[i] = *(const s8v*)(&As[(wm * 128 + i * 16 + (lane & 15)) * 32 + koff]);
#pragma unroll
        for (int j = 0; j < 4; j++)
            bfv[j] = *(const s8v*)(&Bs[(wn * 64 + j * 16 + (lane & 15)) * 32 + koff]);
#pragma unroll
        for (int i = 0; i < 8; i++)
#pragma unroll
            for (int j = 0; j < 4; j++)
                acc[i][j] = __builtin_amdgcn_mfma_f32_16x16x32_bf16(af[i], bfv[j], acc[i][j], 0, 0, 0);
        __syncthreads();
#pragma unroll
        for (int c = 0; c < 4; c++) ga[c] += 32;
        gb0 += 32; gb1 += 32;
        kin += 32;
        if (kin == 768) {
            kin = 0; rr++;
            if (rr == 3 || rr == 6) {
#pragma unroll
                for (int c = 0; c < 4; c++) ga[c] += 31 * 768;
            }
        }
    }
#pragma unroll
    for (int i = 0; i < 8; i++) {
        const int mbase = bm + wm * 128 + i * 16 + ((lane >> 4) << 2);
#pragma unroll
        for (int j = 0; j < 4; j++) {
            const int n = bn + wn * 64 + j * 16 + (lane & 15);
            const float bs = bias[n];
#pragma unroll
            for (int g = 0; g < 4; g++) {
                const int m = mbase + g;
                float v = acc[i][j][g] + bs;
                if constexpr (ACT == 1) v = gelu_f(v);
                int b = m >> 10, y = (m >> 5) & 31, x = m & 31;
                Cpad[(((size_t)b * 34 + y + 1) * 34 + (x + 1)) * 768 + n] =
                    __float2bfloat16(v);
                if constexpr (OUT == 3) {
                    Cb[(size_t)m * 768 + n] =
                        __float2bfloat16(v + pos[(size_t)(m & 1023) * 768 + n]);
                }
            }
        }
    }
}

// ---------------------------------------------------------------------------
// bf16 MFMA GEMM, 128x128 tile (score head, AMODE0 only now)
// ---------------------------------------------------------------------------
template<int AMODE, int ACT, int OUT>
__global__ __launch_bounds__(256) void mfma_gemm_k(
    const __hip_bfloat16* __restrict__ A,
    const __hip_bfloat16* __restrict__ Bt,
    const float* __restrict__ bias,
    float* __restrict__ Cf,
    __hip_bfloat16* __restrict__ Cb,
    __hip_bfloat16* __restrict__ Cpad,
    const float* __restrict__ pos,
    int M, int N, int K)
{
    __shared__ __hip_bfloat16 As[128 * 32];
    __shared__ __hip_bfloat16 Bs[128 * 32];
    const int tid  = threadIdx.x;
    const int lane = tid & 63;
    const int wave = tid >> 6;
    const int wm = wave >> 1, wn = wave & 1;
    int bxi = blockIdx.x, byi = blockIdx.y;
    {
        const int nbx = gridDim.x;
        const int nwg = nbx * gridDim.y;
        if ((nwg & 7) == 0) {
            int id = byi * nbx + bxi;
            const int cpx = nwg >> 3;
            id = (id & 7) * cpx + (id >> 3);
            bxi = id % nbx; byi = id / nbx;
        }
    }
    const int bm = byi * 128, bn = bxi * 128;
    const int r0 = tid >> 2;
    const int kb_dst = (tid & 3) * 8;
    const int kb_src = (((tid & 3) ^ ((tid >> 3) & 3)) << 3);

    f4v acc[4][4];
#pragma unroll
    for (int i = 0; i < 4; i++)
#pragma unroll
        for (int j = 0; j < 4; j++) acc[i][j] = (f4v)0.f;

    const __hip_bfloat16* ga0;
    const __hip_bfloat16* ga1;
    if constexpr (AMODE == 0) {
        ga0 = A + (size_t)(bm + r0) * K + kb_src;
        ga1 = A + (size_t)(bm + r0 + 64) * K + kb_src;
    } else {
        int gm0 = bm + r0;
        int b0 = gm0 >> 10, y0 = (gm0 >> 5) & 31, x0 = gm0 & 31;
        ga0 = A + ((((size_t)b0 * 34 + y0) * 34 + x0) * 768 + kb_src);
        int gm1 = bm + r0 + 64;
        int b1 = gm1 >> 10, y1 = (gm1 >> 5) & 31, x1 = gm1 & 31;
        ga1 = A + ((((size_t)b1 * 34 + y1) * 34 + x1) * 768 + kb_src);
    }
    const __hip_bfloat16* gb0 = Bt + (size_t)(bn + r0) * K + kb_src;
    const __hip_bfloat16* gb1 = Bt + (size_t)(bn + r0 + 64) * K + kb_src;

    const int koff = (((lane >> 4) ^ ((lane >> 1) & 3)) << 3);
    int kin = 0, rr = 0;
    for (int k0 = 0; k0 < K; k0 += 32) {
        gld_lds16(ga0, &As[r0 * 32 + kb_dst]);
        gld_lds16(ga1, &As[(r0 + 64) * 32 + kb_dst]);
        gld_lds16(gb0, &Bs[r0 * 32 + kb_dst]);
        gld_lds16(gb1, &Bs[(r0 + 64) * 32 + kb_dst]);
        __syncthreads();
        s8v af[4], bfv[4];
#pragma unroll
        for (int i = 0; i < 4; i++)
            af[i] = *(const s8v*)(&As[(wm * 64 + i * 16 + (lane & 15)) * 32 + koff]);
#pragma unroll
        for (int j = 0; j < 4; j++)
            bfv[j] = *(const s8v*)(&Bs[(wn * 64 + j * 16 + (lane & 15)) * 32 + koff]);
#pragma unroll
        for (int i = 0; i < 4; i++)
#pragma unroll
            for (int j = 0; j < 4; j++)
                acc[i][j] = __builtin_amdgcn_mfma_f32_16x16x32_bf16(af[i], bfv[j], acc[i][j], 0, 0, 0);
        __syncthreads();
        ga0 += 32; ga1 += 32; gb0 += 32; gb1 += 32;
        if constexpr (AMODE == 1) {
            kin += 32;
            if (kin == 768) {
                kin = 0; rr++;
                if (rr == 3 || rr == 6) { ga0 += 31 * 768; ga1 += 31 * 768; }
            }
        }
    }
#pragma unroll
    for (int i = 0; i < 4; i++) {
        const int mbase = bm + wm * 64 + i * 16 + ((lane >> 4) << 2);
#pragma unroll
        for (int j = 0; j < 4; j++) {
            const int n = bn + wn * 64 + j * 16 + (lane & 15);
            const float bs = bias[n];
#pragma unroll
            for (int g = 0; g < 4; g++) {
                const int m = mbase + g;
                if (m >= M) continue;
                float v = acc[i][j][g] + bs;
                if constexpr (ACT == 1) v = gelu_f(v);
                if constexpr (OUT == 0) {
                    Cf[(size_t)m * N + n] = v;
                } else if constexpr (OUT == 1) {
                    int b = m >> 10, y = (m >> 5) & 31, x = m & 31;
                    Cpad[(((size_t)b * 34 + y + 1) * 34 + (x + 1)) * 768 + n] =
                        __float2bfloat16(v);
                } else if constexpr (OUT == 2) {
                    Cb[(size_t)m * N + n] = __float2bfloat16(v);
                } else {
                    int b = m >> 10, y = (m >> 5) & 31, x = m & 31;
                    Cpad[(((size_t)b * 34 + y + 1) * 34 + (x + 1)) * 768 + n] =
                        __float2bfloat16(v);
                    Cb[(size_t)m * 768 + n] =
                        __float2bfloat16(v + pos[(size_t)(m & 1023) * 768 + n]);
                }
            }
        }
    }
}

// ---------------------------------------------------------------------------
// dg1: 3x3 conv 768->64, gelu, in/out padded bf16. Tile 128(M)x64(N).
// ---------------------------------------------------------------------------
__global__ __launch_bounds__(256) void mfma_dg1_k(
    const __hip_bfloat16* __restrict__ A,
    const __hip_bfloat16* __restrict__ Bt,
    const float* __restrict__ bias,
    __hip_bfloat16* __restrict__ Dpad)
{
    __shared__ __hip_bfloat16 As[128 * 32];
    __shared__ __hip_bfloat16 Bs[64 * 32];
    const int tid = threadIdx.x, lane = tid & 63, wave = tid >> 6;
    const int wm = wave >> 1, wn = wave & 1;
    const int bm = blockIdx.x * 128;
    const int r0 = tid >> 2;
    const int kb_dst = (tid & 3) * 8;
    const int kb_src = (((tid & 3) ^ ((tid >> 3) & 3)) << 3);
    f4v acc[4][2];
#pragma unroll
    for (int i = 0; i < 4; i++)
#pragma unroll
        for (int j = 0; j < 2; j++) acc[i][j] = (f4v)0.f;

    const __hip_bfloat16* ga0;
    const __hip_bfloat16* ga1;
    {
        int gm0 = bm + r0;
        int b0 = gm0 >> 10, y0 = (gm0 >> 5) & 31, x0 = gm0 & 31;
        ga0 = A + ((((size_t)b0 * 34 + y0) * 34 + x0) * 768 + kb_src);
        int gm1 = bm + r0 + 64;
        int b1 = gm1 >> 10, y1 = (gm1 >> 5) & 31, x1 = gm1 & 31;
        ga1 = A + ((((size_t)b1 * 34 + y1) * 34 + x1) * 768 + kb_src);
    }
    const __hip_bfloat16* gb0 = Bt + (size_t)r0 * 6912 + kb_src;

    const int koff = (((lane >> 4) ^ ((lane >> 1) & 3)) << 3);
    int kin = 0, rr = 0;
    for (int k0 = 0; k0 < 6912; k0 += 32) {
        gld_lds16(ga0, &As[r0 * 32 + kb_dst]);
        gld_lds16(ga1, &As[(r0 + 64) * 32 + kb_dst]);
        gld_lds16(gb0, &Bs[r0 * 32 + kb_dst]);
        __syncthreads();
        s8v af[4], bfv[2];
#pragma unroll
        for (int i = 0; i < 4; i++)
            af[i] = *(const s8v*)(&As[(wm * 64 + i * 16 + (lane & 15)) * 32 + koff]);
#pragma unroll
        for (int j = 0; j < 2; j++)
            bfv[j] = *(const s8v*)(&Bs[(wn * 32 + j * 16 + (lane & 15)) * 32 + koff]);
#pragma unroll
        for (int i = 0; i < 4; i++)
#pragma unroll
            for (int j = 0; j < 2; j++)
                acc[i][j] = __builtin_amdgcn_mfma_f32_16x16x32_bf16(af[i], bfv[j], acc[i][j], 0, 0, 0);
        __syncthreads();
        ga0 += 32; ga1 += 32; gb0 += 32;
        kin += 32;
        if (kin == 768) {
            kin = 0; rr++;
            if (rr == 3 || rr == 6) { ga0 += 31 * 768; ga1 += 31 * 768; }
        }
    }
#pragma unroll
    for (int i = 0; i < 4; i++) {
        const int mbase = bm + wm * 64 + i * 16 + ((lane >> 4) << 2);
#pragma unroll
        for (int j = 0; j < 2; j++) {
            const int n = wn * 32 + j * 16 + (lane & 15);
            const float bs = bias[n];
#pragma unroll
            for (int g = 0; g < 4; g++) {
                const int m = mbase + g;
                float v = gelu_f(acc[i][j][g] + bs);
                int b = m >> 10, y = (m >> 5) & 31, x = m & 31;
                Dpad[(((size_t)b * 34 + y + 1) * 34 + (x + 1)) * 64 + n] =
                    __float2bfloat16(v);
            }
        }
    }
}

// ---------------------------------------------------------------------------
// dg2: up2 + 3x3 conv 64->32, gelu. Tile 128(M)x32(N).
// ---------------------------------------------------------------------------
__global__ __launch_bounds__(256) void mfma_dg2_k(
    const __hip_bfloat16* __restrict__ A,
    const __hip_bfloat16* __restrict__ Bt,
    const float* __restrict__ bias,
    float* __restrict__ D)
{
    __shared__ __hip_bfloat16 As[128 * 32];
    __shared__ __hip_bfloat16 Bs[32 * 32];
    const int tid = threadIdx.x, lane = tid & 63, wave = tid >> 6;
    const int bm = blockIdx.x * 128;
    const int r0 = tid >> 2;
    const int kb_dst = (tid & 3) * 8;
    const int kb_src = (((tid & 3) ^ ((tid >> 3) & 3)) << 3);
    f4v acc[2][2];
#pragma unroll
    for (int i = 0; i < 2; i++)
#pragma unroll
        for (int j = 0; j < 2; j++) acc[i][j] = (f4v)0.f;

    const int koff = (((lane >> 4) ^ ((lane >> 1) & 3)) << 3);
    int rr = 0, kin = 0;
    for (int k0 = 0; k0 < 576; k0 += 32) {
#pragma unroll
        for (int c = 0; c < 2; c++) {
            const int row = r0 + c * 64;
            int gm = bm + row;
            int b = gm >> 12, y = (gm >> 6) & 63, x = gm & 63;
            int dy = rr / 3, dx = rr - dy * 3;
            int iy = (y + dy + 1) >> 1, ix = (x + dx + 1) >> 1;
            gld_lds16(A + (((size_t)b * 34 + iy) * 34 + ix) * 64 + kin + kb_src,
                      &As[row * 32 + kb_dst]);
        }
        if (tid < 128)
            gld_lds16(Bt + (size_t)r0 * 576 + k0 + kb_src, &Bs[r0 * 32 + kb_dst]);
        __syncthreads();
        s8v af[2], bfv[2];
#pragma unroll
        for (int i = 0; i < 2; i++)
            af[i] = *(const s8v*)(&As[(wave * 32 + i * 16 + (lane & 15)) * 32 + koff]);
#pragma unroll
        for (int j = 0; j < 2; j++)
            bfv[j] = *(const s8v*)(&Bs[(j * 16 + (lane & 15)) * 32 + koff]);
#pragma unroll
        for (int i = 0; i < 2; i++)
#pragma unroll
            for (int j = 0; j < 2; j++)
                acc[i][j] = __builtin_amdgcn_mfma_f32_16x16x32_bf16(af[i], bfv[j], acc[i][j], 0, 0, 0);
        __syncthreads();
        kin += 32; if (kin == 64) { kin = 0; rr++; }
    }
#pragma unroll
    for (int i = 0; i < 2; i++) {
        const int mbase = bm + wave * 32 + i * 16 + ((lane >> 4) << 2);
#pragma unroll
        for (int j = 0; j < 2; j++) {
            const int n = j * 16 + (lane & 15);
            const float bs = bias[n];
#pragma unroll
            for (int g = 0; g < 4; g++) {
                const int m = mbase + g;
                D[(size_t)m * 32 + n] = gelu_f(acc[i][j][g] + bs);
            }
        }
    }
}

// NCHW fp32 -> padded NHWC bf16 interior
__global__ void nchw2pad_bf_k(const float* __restrict__ src, __hip_bfloat16* __restrict__ dst)
{
    __shared__ float tile[32][33];
    int b = blockIdx.z, n0 = blockIdx.y * 32, c0 = blockIdx.x * 32;
    int tx = threadIdx.x, ty = threadIdx.y;
#pragma unroll
    for (int i = ty; i < 32; i += 8)
        tile[i][tx] = src[((size_t)b * ND + c0 + i) * NTOK + n0 + tx];
    __syncthreads();
#pragma unroll
    for (int i = ty; i < 32; i += 8) {
        int n = n0 + i, y = n >> 5, x = n & 31;
        dst[(((size_t)b * 34 + y + 1) * 34 + (x + 1)) * 768 + c0 + tx] =
            __float2bfloat16(tile[tx][i]);
    }
}

// zero borders of two padded-768 bf16 buffers
__global__ void pad_border_k(__hip_bfloat16* __restrict__ p1, __hip_bfloat16* __restrict__ p2)
{
    int idx = blockIdx.x * 256 + threadIdx.x;
    if (idx >= 32 * 132 * 192) return;
    int c4 = idx % 192;
    int cell = (idx / 192) % 132;
    int b = idx / (192 * 132);
    int yy, xx;
    if      (cell < 34)  { yy = 0;  xx = cell; }
    else if (cell < 68)  { yy = 33; xx = cell - 34; }
    else if (cell < 100) { yy = cell - 68 + 1;  xx = 0; }
    else                 { yy = cell - 100 + 1; xx = 33; }
    size_t o = (((size_t)b * 34 + yy) * 34 + xx) * 768 + c4 * 4;
    *reinterpret_cast<uint2*>(p1 + o) = make_uint2(0u, 0u);
    *reinterpret_cast<uint2*>(p2 + o) = make_uint2(0u, 0u);
}

// zero border of padded-64 bf16 buffer
__global__ void pad_border64_k(__hip_bfloat16* __restrict__ p)
{
    int idx = blockIdx.x * 256 + threadIdx.x;
    if (idx >= 32 * 132 * 16) return;
    int c4 = idx % 16;
    int cell = (idx / 16) % 132;
    int b = idx / (16 * 132);
    int yy, xx;
    if      (cell < 34)  { yy = 0;  xx = cell; }
    else if (cell < 68)  { yy = 33; xx = cell - 34; }
    else if (cell < 100) { yy = cell - 68 + 1;  xx = 0; }
    else                 { yy = cell - 100 + 1; xx = 33; }
    size_t o = (((size_t)b * 34 + yy) * 34 + xx) * 64 + c4 * 4;
    *reinterpret_cast<uint2*>(p + o) = make_uint2(0u, 0u);
}

// conv weight OIHW fp32 -> bf16 [n][tap*Cin+ci]
__global__ void convw_bf_k(const float* __restrict__ w, __hip_bfloat16* __restrict__ wT,
                           int Cout, int Cin)
{
    int idx = blockIdx.x * 256 + threadIdx.x;
    if (idx >= Cout * Cin * 9) return;
    int n = idx / (Cin * 9), k = idx - n * (Cin * 9);
    int r = k / Cin, ci = k - r * Cin;
    wT[idx] = __float2bfloat16(w[((size_t)n * Cin + ci) * 9 + r]);
}

// [K][N] fp32 -> [N][K] bf16, tiled transpose
__global__ void wt_bf_k(const float* __restrict__ w, __hip_bfloat16* __restrict__ wT,
                        int K, int N)
{
    __shared__ float t[32][33];
    int k0 = blockIdx.y * 32, n0 = blockIdx.x * 32;
    int tx = threadIdx.x, ty = threadIdx.y;
#pragma unroll
    for (int i = ty; i < 32; i += 8)
        t[i][tx] = w[(size_t)(k0 + i) * N + n0 + tx];
    __syncthreads();
#pragma unroll
    for (int i = ty; i < 32; i += 8)
        wT[(size_t)(n0 + i) * K + k0 + tx] = __float2bfloat16(t[tx][i]);
}

// tokens [b][1024][768] bf16 -> tokT [b][768][1024] bf16
__global__ void tokT_k(const __hip_bfloat16* __restrict__ tok, __hip_bfloat16* __restrict__ tokT)
{
    __shared__ __hip_bfloat16 tl[32][33];
    int b = blockIdx.z, k0 = blockIdx.y * 32, c0 = blockIdx.x * 32;
    int tx = threadIdx.x, ty = threadIdx.y;
#pragma unroll
    for (int i = ty; i < 32; i += 8)
        tl[i][tx] = tok[((size_t)(b * 1024 + k0 + i)) * 768 + c0 + tx];
    __syncthreads();
#pragma unroll
    for (int i = ty; i < 32; i += 8)
        tokT[((size_t)(b * 768 + c0 + i)) * 1024 + k0 + tx] = tl[tx][i];
}

// fp32 -> bf16 flat convert
__global__ void f2bf_k(const float* __restrict__ s, __hip_bfloat16* __restrict__ d, int n)
{
    int i = blockIdx.x * 256 + threadIdx.x;
    if (i < n) d[i] = __float2bfloat16(s[i]);
}

// catbf[r][0:768] = bf16(q[r/50]); catbf[r][768:1536] = tfbbf[r]; rows>=1600 -> 0
__global__ void cat_bf_k(const float* __restrict__ q, const __hip_bfloat16* __restrict__ tf,
                         __hip_bfloat16* __restrict__ cat)
{
    int idx = blockIdx.x * 256 + threadIdx.x;
    if (idx >= 1664 * 1536) return;
    int r = idx / 1536, c = idx - r * 1536;
    __hip_bfloat16 v;
    if (r < 1600)
        v = (c < 768) ? __float2bfloat16(q[(size_t)(r / 50) * 768 + c])
                      : tf[(size_t)r * 768 + (c - 768)];
    else v = __float2bfloat16(0.f);
    cat[idx] = v;
}

// ---------------------------------------------------------------------------
// fp32 tiled GEMM — kept for qi (K=99) and tf1 (M=1600)
// ---------------------------------------------------------------------------
template<int ACT, int RES>
__global__ __launch_bounds__(256) void gemm_k(
    const float* __restrict__ A, const float* __restrict__ Bw,
    const float* __restrict__ bias, const float* __restrict__ res,
    float* __restrict__ C, int M, int N, int K)
{
    __shared__ float As[16][68];
    __shared__ float Bs[16][68];
    const int tx = threadIdx.x, ty = threadIdx.y;
    const int tid = ty * 16 + tx;
    const int bm = blockIdx.y * 64, bn = blockIdx.x * 64;
    float acc[4][4] = {};

    for (int k0 = 0; k0 < K; k0 += 16) {
#pragma unroll
        for (int i = 0; i < 4; i++) {
            int idx = i * 256 + tid;
            int ml = idx >> 4, kl = idx & 15;
            int m = bm + ml, k = k0 + kl;
            As[kl][ml] = (m < M && k < K) ? A[(size_t)m * K + k] : 0.f;
        }
#pragma unroll
        for (int i = 0; i < 4; i++) {
            int idx = i * 256 + tid;
            int nl = idx & 63, kl = idx >> 6;
            int k = k0 + kl, n = bn + nl;
            Bs[kl][nl] = (k < K && n < N) ? Bw[(size_t)k * N + n] : 0.f;
        }
        __syncthreads();
#pragma unroll
        for (int kk = 0; kk < 16; kk++) {
            const float4 av = *reinterpret_cast<const float4*>(&As[kk][ty * 4]);
            const float4 bv = *reinterpret_cast<const float4*>(&Bs[kk][tx * 4]);
            const float a4[4] = {av.x, av.y, av.z, av.w};
            const float b4[4] = {bv.x, bv.y, bv.z, bv.w};
#pragma unroll
            for (int i = 0; i < 4; i++)
#pragma unroll
                for (int j = 0; j < 4; j++)
                    acc[i][j] = fmaf(a4[i], b4[j], acc[i][j]);
        }
        __syncthreads();
    }
#pragma unroll
    for (int i = 0; i < 4; i++) {
        int m = bm + ty * 4 + i;
        if (m >= M) continue;
#pragma unroll
        for (int j = 0; j < 4; j++) {
            int n = bn + tx * 4 + j;
            if (n >= N) continue;
            float v = acc[i][j] + bias[n];
            if constexpr (ACT == 1) v = gelu_f(v);
            if constexpr (RES == 1) v += res[(size_t)m * N + n];
            C[(size_t)m * N + n] = v;
        }
    }
}

// ---------------------------------------------------------------------------
// Skinny fp32 GEMM, M=32, KSPLIT partials. A transposed: At[K][32].
// ---------------------------------------------------------------------------
__global__ __launch_bounds__(256) void skinny_part_k(
    const float* __restrict__ At, const float* __restrict__ Bw,
    float* __restrict__ P, int N, int Kc)
{
    const int bn = blockIdx.x * 128;
    const int s  = blockIdx.y;
    const int k0 = s * Kc;
    const int t = threadIdx.x, tn = t & 63, tm = t >> 6;
    const int n0 = bn + tn * 2;
    float2 acc[8];
#pragma unroll
    for (int i = 0; i < 8; i++) { acc[i].x = 0.f; acc[i].y = 0.f; }

    if (n0 + 2 <= N) {
#pragma unroll 2
        for (int k = 0; k < Kc; k++) {
            const float* ar = At + (size_t)(k0 + k) * 32 + tm * 8;
            f4v a0 = *(const f4v*)ar;
            f4v a1 = *(const f4v*)(ar + 4);
            float2 bv = *(const float2*)&Bw[(size_t)(k0 + k) * N + n0];
#pragma unroll
            for (int i = 0; i < 4; i++) {
                acc[i].x     = fmaf(a0[i], bv.x, acc[i].x);
                acc[i].y     = fmaf(a0[i], bv.y, acc[i].y);
                acc[i + 4].x = fmaf(a1[i], bv.x, acc[i + 4].x);
                acc[i + 4].y = fmaf(a1[i], bv.y, acc[i + 4].y);
            }
        }
#pragma unroll
        for (int i = 0; i < 8; i++)
            *(float2*)&P[((size_t)s * 32 + tm * 8 + i) * N + n0] = acc[i];
    } else {
        if (n0 >= N) return;
        bool v1 = (n0 + 1) < N;
        for (int k = 0; k < Kc; k++) {
            const float* ar = At + (size_t)(k0 + k) * 32 + tm * 8;
            f4v a0 = *(const f4v*)ar;
            f4v a1 = *(const f4v*)(ar + 4);
            float b0 = Bw[(size_t)(k0 + k) * N + n0];
            float b1 = v1 ? Bw[(size_t)(k0 + k) * N + n0 + 1] : 0.f;
#pragma unroll
            for (int i = 0; i < 4; i++) {
                acc[i].x     = fmaf(a0[i], b0, acc[i].x);
                acc[i].y     = fmaf(a0[i], b1, acc[i].y);
                acc[i + 4].x = fmaf(a1[i], b0, acc[i + 4].x);
                acc[i + 4].y = fmaf(a1[i], b1, acc[i + 4].y);
            }
        }
        for (int i = 0; i < 8; i++) {
            P[((size_t)s * 32 + tm * 8 + i) * N + n0] = acc[i].x;
            if (v1) P[((size_t)s * 32 + tm * 8 + i) * N + n0 + 1] = acc[i].y;
        }
    }
}

// combine partials: C[32][N] = act(sum_s P + bias) [+res]; optional CT[N][32]
template<int ACT, int RES>
__global__ void comb_k(const float* __restrict__ P, const float* __restrict__ bias,
                       const float* res, float* C, float* CT, int N, int KS)
{
    int idx = blockIdx.x * 256 + threadIdx.x;
    if (idx >= 32 * N) return;
    int m = idx / N, n = idx - m * N;
    float v = bias[n];
    for (int ss = 0; ss < KS; ss++) v += P[((size_t)ss * 32 + m) * N + n];
    if constexpr (ACT == 1) v = gelu_f(v);
    if constexpr (RES == 1) v += res[idx];
    C[idx] = v;
    if (CT) CT[(size_t)n * 32 + m] = v;
}

__global__ void depth_k(const float* __restrict__ d2,
                        const float* __restrict__ w3, const float* __restrict__ b3,
                        float* __restrict__ out)
{
    int idx = blockIdx.x * 256 + threadIdx.x;
    if (idx >= NB * 128 * 128) return;
    int b = idx >> 14;
    int rem = idx & 16383;
    int y = rem >> 7, x = rem & 127;
    const float* base = d2 + (((size_t)b * 64 + (y >> 1)) * 64 + (x >> 1)) * 32;
    float acc = b3[0];
#pragma unroll
    for (int ci = 0; ci < 32; ci++) acc = fmaf(base[ci], w3[ci], acc);
    out[idx] = softplus_f(acc);
}

// layernorm row; writes y [32][768] and yT [768][32]
__global__ void ln_k(const float* __restrict__ x, const float* __restrict__ g,
                     const float* __restrict__ bb, float* __restrict__ y,
                     float* __restrict__ yT)
{
    int r = blockIdx.x, t = threadIdx.x;
    __shared__ float red[256];
    float v0 = x[(size_t)r * ND + t];
    float v1 = x[(size_t)r * ND + 256 + t];
    float v2 = x[(size_t)r * ND + 512 + t];
    red[t] = v0 + v1 + v2;
    __syncthreads();
    for (int s = 128; s > 0; s >>= 1) { if (t < s) red[t] += red[t + s]; __syncthreads(); }
    float mean = red[0] * (1.0f / ND);
    __syncthreads();
    float d0 = v0 - mean, d1 = v1 - mean, d2 = v2 - mean;
    red[t] = d0 * d0 + d1 * d1 + d2 * d2;
    __syncthreads();
    for (int s = 128; s > 0; s >>= 1) { if (t < s) red[t] += red[t + s]; __syncthreads(); }
    float inv = 1.0f / sqrtf(red[0] * (1.0f / ND) + 1e-5f);
    float o0 = d0 * inv * g[t]       + bb[t];
    float o1 = d1 * inv * g[256 + t] + bb[256 + t];
    float o2 = d2 * inv * g[512 + t] + bb[512 + t];
    y[(size_t)r * ND + t]       = o0;
    y[(size_t)r * ND + 256 + t] = o1;
    y[(size_t)r * ND + 512 + t] = o2;
    yT[(size_t)t * 32 + r]         = o0;
    yT[(size_t)(256 + t) * 32 + r] = o1;
    yT[(size_t)(512 + t) * 32 + r] = o2;
}

// ---------------------------------------------------------------------------
// Attention (q-seq-len 1, wk/wv folded).
// ---------------------------------------------------------------------------
__global__ __launch_bounds__(256) void qw2_k(const float* __restrict__ Qp,
                                             const float* __restrict__ wk,
                                             __hip_bfloat16* __restrict__ qwbf)
{
    int c0 = blockIdx.x * 32, h = blockIdx.y;
    int t = threadIdx.x;
    if (h >= 8) {
        for (int i = t; i < 32 * 32; i += 256) {
            int b = i >> 5, c = i & 31;
            qwbf[((size_t)(b * 16 + h)) * 768 + c0 + c] = __float2bfloat16(0.f);
        }
        return;
    }
    __shared__ float Qps[32][100];
    __shared__ float wks[32][100];
    for (int i = t; i < 32 * 96; i += 256) {
        int b = i / 96, d = i - b * 96;
        Qps[b][d] = Qp[(size_t)b * 768 + h * 96 + d];
    }
    for (int i = t; i < 32 * 96; i += 256) {
        int c = i / 96, d = i - c * 96;
        wks[c][d] = wk[(size_t)(c0 + c) * 768 + h * 96 + d];
    }
    __syncthreads();
    int b = t & 31, cl = t >> 5;
#pragma unroll
    for (int cc = 0; cc < 4; cc++) {
        int c = cl * 4 + cc;
        float a = 0.f;
#pragma unroll
        for (int d = 0; d < 96; d += 4) {
            f4v qv = *(const f4v*)&Qps[b][d];
            f4v wv2 = *(const f4v*)&wks[c][d];
            a += qv[0] * wv2[0] + qv[1] * wv2[1] + qv[2] * wv2[2] + qv[3] * wv2[3];
        }
        qwbf[((size_t)(b * 16 + h)) * 768 + c0 + c] = __float2bfloat16(a);
    }
}

// scores: sraw[b][h][k] = tok[b,k,:]·qw[b,h,:]  (MFMA, 128 tok x 16 heads)
__global__ __launch_bounds__(256) void scores_mfma_k(
    const __hip_bfloat16* __restrict__ tok, const __hip_bfloat16* __restrict__ qwbf,
    float* __restrict__ sraw, __hip_bfloat16* __restrict__ attbf)
{
    __shared__ __hip_bfloat16 As[128 * 32];
    __shared__ __hip_bfloat16 Bs[16 * 32];
    const int b = blockIdx.y, bm = blockIdx.x * 128;
    const int tid = threadIdx.x, lane = tid & 63, wave = tid >> 6;
    const int r0 = tid >> 2;
    const int kb_dst = (tid & 3) * 8;
    const int kb_src = (((tid & 3) ^ ((tid >> 3) & 3)) << 3);
    f4v acc[2];
    acc[0] = (f4v)0.f; acc[1] = (f4v)0.f;
    const __hip_bfloat16* ga0 = tok + ((size_t)(b * 1024 + bm + r0)) * 768 + kb_src;
    const __hip_bfloat16* ga1 = tok + ((size_t)(b * 1024 + bm + r0 + 64)) * 768 + kb_src;
    const __hip_bfloat16* gq  = qwbf + ((size_t)(b * 16 + r0)) * 768 + kb_src;  // tid<64
    const int koff = (((lane >> 4) ^ ((lane >> 1) & 3)) << 3);
    for (int k0 = 0; k0 < 768; k0 += 32) {
        gld_lds16(ga0, &As[r0 * 32 + kb_dst]);
        gld_lds16(ga1, &As[(r0 + 64) * 32 + kb_dst]);
        if (tid < 64)
            gld_lds16(gq, &Bs[r0 * 32 + kb_dst]);
        __syncthreads();
        s8v bf = *(const s8v*)&Bs[(lane & 15) * 32 + koff];
#pragma unroll
        for (int i = 0; i < 2; i++) {
            s8v af = *(const s8v*)&As[(wave * 32 + i * 16 + (lane & 15)) * 32 + koff];
            acc[i] = __builtin_amdgcn_mfma_f32_16x16x32_bf16(af, bf, acc[i], 0, 0, 0);
        }
        __syncthreads();
        ga0 += 32; ga1 += 32; gq += 32;
    }
    const int n = lane & 15;
#pragma unroll
    for (int i = 0; i < 2; i++) {
        const int mb = bm + wave * 32 + i * 16 + ((lane >> 4) << 2);
#pragma unroll
        for (int g = 0; g < 4; g++) {
            const int m = mb + g;
            if (n < 8)
                sraw[(((size_t)(b * 16 + n)) << 10) + m] = acc[i][g];
            else
                attbf[(((size_t)(b * 16 + n)) << 10) + m] = __float2bfloat16(0.f);
        }
    }
}

// softmax over k for one (b,h) row; writes attbf bf16
__global__ __launch_bounds__(256) void softmax_row_k(
    const float* __restrict__ sraw, __hip_bfloat16* __restrict__ attbf)
{
    int r = blockIdx.x;
    int b = r >> 3, h = r & 7;
    size_t base = ((size_t)(b * 16 + h)) << 10;
    int t = threadIdx.x, lane = t & 63, w = t >> 6;
    const float scale = 0.1020620726159658f;
    f4v v = *(const f4v*)&sraw[base + (t << 2)];
    float x0 = v[0] * scale, x1 = v[1] * scale, x2 = v[2] * scale, x3 = v[3] * scale;
    __shared__ float red[4];
    __shared__ float gm, gs;
    float m = fmaxf(fmaxf(x0, x1), fmaxf(x2, x3));
#pragma unroll
    for (int off = 32; off > 0; off >>= 1) m = fmaxf(m, __shfl_xor(m, off, 64));
    if (lane == 0) red[w] = m;
    __syncthreads();
    if (t == 0) gm = fmaxf(fmaxf(red[0], red[1]), fmaxf(red[2], red[3]));
    __syncthreads();
    float M = gm;
    float e0 = expf(x0 - M), e1 = expf(x1 - M), e2 = expf(x2 - M), e3 = expf(x3 - M);
    float s = e0 + e1 + e2 + e3;
#pragma unroll
    for (int off = 32; off > 0; off >>= 1) s += __shfl_xor(s, off, 64);
    __syncthreads();
    if (lane == 0) red[w] = s;
    __syncthreads();
    if (t == 0) gs = 1.0f / (red[0] + red[1] + red[2] + red[3]);
    __syncthreads();
    float inv = gs;
    union { __hip_bfloat16 h4[4]; short4 s4; } u;
    u.h4[0] = __float2bfloat16(e0 * inv);
    u.h4[1] = __float2bfloat16(e1 * inv);
    u.h4[2] = __float2bfloat16(e2 * inv);
    u.h4[3] = __float2bfloat16(e3 * inv);
    *(short4*)&attbf[base + (t << 2)] = u.s4;
}

// ctx^T: ctxf[b][h][c] = sum_k att[b,h,k] * tokT[b,c,k]  (MFMA, 128 c x 16 h)
__global__ __launch_bounds__(256) void ctxT_mfma_k(
    const __hip_bfloat16* __restrict__ tokT, const __hip_bfloat16* __restrict__ attbf,
    float* __restrict__ ctxf)
{
    __shared__ __hip_bfloat16 As[128 * 32];
    __shared__ __hip_bfloat16 Bs[16 * 32];
    const int b = blockIdx.y, bm = blockIdx.x * 128;
    const int tid = threadIdx.x, lane = tid & 63, wave = tid >> 6;
    const int r0 = tid >> 2;
    const int kb_dst = (tid & 3) * 8;
    const int kb_src = (((tid & 3) ^ ((tid >> 3) & 3)) << 3);
    f4v acc[2];
    acc[0] = (f4v)0.f; acc[1] = (f4v)0.f;
    const __hip_bfloat16* ga0 = tokT + ((size_t)(b * 768 + bm + r0)) * 1024 + kb_src;
    const __hip_bfloat16* ga1 = tokT + ((size_t)(b * 768 + bm + r0 + 64)) * 1024 + kb_src;
    const __hip_bfloat16* gq  = attbf + ((size_t)(b * 16 + r0)) * 1024 + kb_src;  // tid<64
    const int koff = (((lane >> 4) ^ ((lane >> 1) & 3)) << 3);
    for (int k0 = 0; k0 < 1024; k0 += 32) {
        gld_lds16(ga0, &As[r0 * 32 + kb_dst]);
        gld_lds16(ga1, &As[(r0 + 64) * 32 + kb_dst]);
        if (tid < 64)
            gld_lds16(gq, &Bs[r0 * 32 + kb_dst]);
        __syncthreads();
        s8v bf = *(const s8v*)&Bs[(lane & 15) * 32 + koff];
#pragma unroll
        for (int i = 0; i < 2; i++) {
            s8v af = *(const s8v*)&As[(wave * 32 + i * 16 + (lane & 15)) * 32 + koff];
            acc[i] = __builtin_amdgcn_mfma_f32_16x16x32_bf16(af, bf, acc[i], 0, 0, 0);
        }
        __syncthreads();
        ga0 += 32; ga1 += 32; gq += 32;
    }
    const int n = lane & 15;
    if (n < 8) {
#pragma unroll
        for (int i = 0; i < 2; i++) {
            const int mb = bm + wave * 32 + i * 16 + ((lane >> 4) << 2);
#pragma unroll
            for (int g = 0; g < 4; g++)
                ctxf[((size_t)(b * 8 + n)) * 768 + mb + g] = acc[i][g];
        }
    }
}

// o[b, h*96+d] = sum_c ctx[b,h,c] * wv[c, h*96+d] + bv; writes ob and obT
__global__ __launch_bounds__(128) void ovp_k(
    const float* __restrict__ ctxf, const float* __restrict__ wv,
    const float* __restrict__ bv, float* __restrict__ ob, float* __restrict__ obT)
{
    int bh = blockIdx.x; int b = bh >> 3, h = bh & 7;
    __shared__ float cs[768];
    int t = threadIdx.x;
    for (int i = t; i < 768; i += 128)
        cs[i] = ctxf[(size_t)(b * 8 + h) * 768 + i];
    __syncthreads();
    if (t < 96) {
        const float* wp = wv + h * 96 + t;
        float a = bv[h * 96 + t];
#pragma unroll 8
        for (int c = 0; c < ND; c++)
            a = fmaf(cs[c], wp[(size_t)c * ND], a);
        ob[(size_t)b * ND + h * 96 + t] = a;
        obT[(size_t)(h * 96 + t) * 32 + b] = a;
    }
}

__global__ void build_qa_k(const int* __restrict__ intent,
                           const float* __restrict__ past,
                           float* __restrict__ qA)
{
    int idx = blockIdx.x * 256 + threadIdx.x;
    if (idx >= NB * 99) return;
    int b = idx / 99, j = idx - b * 99;
    float v;
    if (j < 3) v = (intent[b] - 1 == j) ? 1.f : 0.f;
    else       v = past[b * 96 + (j - 3)];
    qA[idx] = v;
}

__global__ void integrate_k(const float* __restrict__ cp,
                            const float* __restrict__ past,
                            float* __restrict__ out)
{
    int idx = blockIdx.x * 256 + threadIdx.x;
    if (idx >= NB * NK) return;
    int b = idx / NK, k = idx - b * NK;
    const float* pl = past + b * 96 + 90;
    float x = pl[0], y = pl[1], vx = pl[2], vy = pl[3];
    float s  = sqrtf(vx * vx + vy * vy + 1e-6f);
    float hd = atan2f(vy, vx);
    const float* cpk = cp + (size_t)b * 3000 + k * 60;
    float* o0 = out +        (size_t)b * 3000 + k * 60;
    float* o1 = out + 96000 + (size_t)b * 3000 + k * 60;
    float* c5 = out + 1946688 + (size_t)b * 3000 + k * 60;
    float* c6 = out + 2042688 + (size_t)b * 3000 + k * 60;
    const float DT = 0.25f;
    for (int t = 0; t < NT; t++) {
        float a = tanhf(cpk[t * 2 + 0]) * 8.0f;
        float w = tanhf(cpk[t * 2 + 1]) * 1.0f;
        x += s * cosf(hd) * DT;
        y += s * sinf(hd) * DT;
        o0[t * 2 + 0] = x; o0[t * 2 + 1] = y;
        o1[t * 2 + 0] = x; o1[t * 2 + 1] = y;
        c5[t * 2 + 0] = a; c5[t * 2 + 1] = w;
        c6[t * 2 + 0] = a; c6[t * 2 + 1] = w;
        hd += w * DT;
        s = fmaxf(s + a * DT, 0.f);
    }
}

__global__ void qscore_k(const float* __restrict__ q, float* __restrict__ out2)
{
    int idx = blockIdx.x * 256 + threadIdx.x;
    if (idx >= NB * NK * ND) return;
    int r = idx / ND, d = idx - r * ND;
    int b = r / NK;
    out2[idx] = q[(size_t)b * ND + d];
}

__global__ void score_k(const float* __restrict__ sc2, const float* __restrict__ w,
                        const float* __restrict__ bias, float* __restrict__ out)
{
    int r = blockIdx.x * 4 + (threadIdx.x >> 6);
    int lane = threadIdx.x & 63;
    if (r >= NB * NK) return;
    float acc = 0.f;
    for (int d = lane; d < ND; d += 64) acc = fmaf(sc2[(size_t)r * ND + d], w[d], acc);
    for (int off = 32; off > 0; off >>= 1) acc += __shfl_down(acc, off, 64);
    if (lane == 0) out[r] = acc + bias[0];
}

// ---------------------------------------------------------------------------
static inline void gemm(hipStream_t st, int act, int hasres,
                        const float* A, const float* Bw, const float* bias,
                        const float* res, float* C, int M, int N, int K)
{
    dim3 blk(16, 16), grd((N + 63) / 64, (M + 63) / 64);
    if      (act == 0 && !hasres) gemm_k<0, 0><<<grd, blk, 0, st>>>(A, Bw, bias, res, C, M, N, K);
    else if (act == 0 &&  hasres) gemm_k<0, 1><<<grd, blk, 0, st>>>(A, Bw, bias, res, C, M, N, K);
    else                          gemm_k<1, 0><<<grd, blk, 0, st>>>(A, Bw, bias, res, C, M, N, K);
}

extern "C" void kernel_launch(void* const* d_in, const int* in_sizes, int n_in,
                              void* d_out, int out_size, void* d_ws, size_t ws_size,
                              hipStream_t stream)
{
    const float* feats_vit = (const float*)d_in[0];
    const float* past      = (const float*)d_in[1];
    const int*   intent    = (const int*)  d_in[2];
    const float* qi_w   = (const float*)d_in[3];
    const float* qi_b   = (const float*)d_in[4];
    const float* va1_w  = (const float*)d_in[5];
    const float* va1_b  = (const float*)d_in[6];
    const float* va2_w  = (const float*)d_in[7];
    const float* va2_b  = (const float*)d_in[8];
    const float* pos    = (const float*)d_in[9];
    const float* ln1_g  = (const float*)d_in[10];
    const float* ln1_b  = (const float*)d_in[11];
    const float* wq     = (const float*)d_in[12];
    const float* bq     = (const float*)d_in[13];
    const float* wk     = (const float*)d_in[14];
    const float* bk     = (const float*)d_in[15];
    const float* wv     = (const float*)d_in[16];
    const float* bv     = (const float*)d_in[17];
    const float* wo     = (const float*)d_in[18];
    const float* bo     = (const float*)d_in[19];
    const float* ln2_g  = (const float*)d_in[20];
    const float* ln2_b  = (const float*)d_in[21];
    const float* m1w    = (const float*)d_in[22];
    const float* m1b    = (const float*)d_in[23];
    const float* m2w    = (const float*)d_in[24];
    const float* m2b    = (const float*)d_in[25];
    const float* dg1w   = (const float*)d_in[26];
    const float* dg1b   = (const float*)d_in[27];
    const float* dg2w   = (const float*)d_in[28];
    const float* dg2b   = (const float*)d_in[29];
    const float* dg3w   = (const float*)d_in[30];
    const float* dg3b   = (const float*)d_in[31];
    const float* td1w   = (const float*)d_in[32];
    const float* td1b   = (const float*)d_in[33];
    const float* td2w   = (const float*)d_in[34];
    const float* td2b   = (const float*)d_in[35];
    const float* td3w   = (const float*)d_in[36];
    const float* td3b   = (const float*)d_in[37];
    const float* tf1w   = (const float*)d_in[38];
    const float* tf1b   = (const float*)d_in[39];
    const float* tf2w   = (const float*)d_in[40];
    const float* tf2b   = (const float*)d_in[41];
    const float* sd1w   = (const float*)d_in[42];
    const float* sd1b   = (const float*)d_in[43];
    const float* sd2w   = (const float*)d_in[44];
    const float* sd2b   = (const float*)d_in[45];
    const float* sd3w   = (const float*)d_in[46];
    const float* sd3b   = (const float*)d_in[47];

    float* out = (float*)d_out;
    float* ws  = (float*)d_ws;

    // workspace layout (float units)
    size_t off = 0;
    float* bufB    = ws + off; off += (size_t)NB * ND * NTOK;   // early: xpad2; late: tokT + attn scratch
    float* xpad_f  = ws + off; off += 14201856;                 // input padded bf16 / tokens bf16
    float* c1pad_f = ws + off; off += 14201856;                 // conv1 padded bf16 / late: score bufs + d1pad
    float* wTc_f   = ws + off; off += 2654208;
    float* dg1wT_f = ws + off; off += 221184;
    float* dg2wT_f = ws + off; off += 9216;
    float* tf2wT_f = ws + off; off += 294912;
    float* sd1wT_f = ws + off; off += 589824;
    float* sd2wT_f = ws + off; off += 294912;
    float* d2      = ws + off; off += (size_t)NB * 4096 * 32;
    float* q       = ws + off; off += NB * ND;
    float* qn      = ws + off; off += NB * ND;
    float* Qp      = ws + off; off += NB * ND;
    float* ob      = ws + off; off += NB * ND;
    float* hm      = ws + off; off += NB * NMLP;
    float* qA      = ws + off; off += NB * 128;
    float* h1      = ws + off; off += NB * ND;
    float* h2      = ws + off; off += NB * ND;
    float* cp      = ws + off; off += NB * 3000;
    // bf16 aliases
    __hip_bfloat16* xpad   = (__hip_bfloat16*)xpad_f;
    __hip_bfloat16* c1pad  = (__hip_bfloat16*)c1pad_f;
    __hip_bfloat16* xpad2  = (__hip_bfloat16*)bufB;             // feats padded bf16 (pre-transformer)
    __hip_bfloat16* tokbf  = (__hip_bfloat16*)xpad_f;           // tokens bf16 (after conv1 frees xpad)
    __hip_bfloat16* wTc    = (__hip_bfloat16*)wTc_f;
    __hip_bfloat16* dg1wT  = (__hip_bfloat16*)dg1wT_f;
    __hip_bfloat16* dg2wT  = (__hip_bfloat16*)dg2wT_f;
    __hip_bfloat16* tf2wT  = (__hip_bfloat16*)tf2wT_f;
    __hip_bfloat16* sd1wT  = (__hip_bfloat16*)sd1wT_f;
    __hip_bfloat16* sd2wT  = (__hip_bfloat16*)sd2wT_f;
    // attention + skinny scratch carved from bufB (xpad2 dead after dg1).
    __hip_bfloat16* tokT  = (__hip_bfloat16*)bufB;
    __hip_bfloat16* qwbf  = (__hip_bfloat16*)(bufB + 12582912);
    float* sraw           = bufB + 12779520;
    __hip_bfloat16* attbf = (__hip_bfloat16*)(bufB + 13303808);
    float* ctxf           = bufB + 13565952;
    float* Pb             = bufB + 13762560;
    float* qnT            = bufB + 15335424;
    float* obT            = bufB + 15360000;
    float* hmT            = bufB + 15384576;
    float* qT             = bufB + 15482880;
    float* h1T            = bufB + 15507456;
    float* h2T            = bufB + 15532032;
    // score-head buffers carved from c1pad region (free after conv2)
    float* tfa            = c1pad_f;
    __hip_bfloat16* tfabf = (__hip_bfloat16*)(c1pad_f + 1228800);
    __hip_bfloat16* tfbbf = (__hip_bfloat16*)(c1pad_f + 1867776);
    __hip_bfloat16* catbf = (__hip_bfloat16*)(c1pad_f + 2506752);
    __hip_bfloat16* s1bf  = (__hip_bfloat16*)(c1pad_f + 3784704);
    float* s2             = c1pad_f + 4423680;
    __hip_bfloat16* d1pad = (__hip_bfloat16*)(c1pad_f + 8000000);
    (void)ws_size; (void)n_in; (void)in_sizes; (void)out_size;

    // ---- prep: borders, input transpose, conv weights ----
    pad_border_k<<<(32 * 132 * 192 + 255) / 256, 256, 0, stream>>>(xpad, c1pad);
    pad_border_k<<<(32 * 132 * 192 + 255) / 256, 256, 0, stream>>>(xpad2, xpad2);
    pad_border64_k<<<(32 * 132 * 16 + 255) / 256, 256, 0, stream>>>(d1pad);
    nchw2pad_bf_k<<<dim3(ND / 32, NTOK / 32, NB), dim3(32, 8), 0, stream>>>(feats_vit, xpad);
    convw_bf_k<<<(768 * 768 * 9 + 255) / 256, 256, 0, stream>>>(va1_w, wTc, 768, 768);

    // ---- conv1 (gelu -> padded bf16), 256x128 tile ----
    mfma_conv_k<1, 1><<<dim3(6, 128), 256, 0, stream>>>(
        xpad, wTc, va1_b, c1pad, nullptr, nullptr);
    convw_bf_k<<<(768 * 768 * 9 + 255) / 256, 256, 0, stream>>>(va2_w, wTc, 768, 768);
    // ---- conv2 (-> padded bf16 feats + bf16 tokens with +pos) ----
    mfma_conv_k<0, 3><<<dim3(6, 128), 256, 0, stream>>>(
        c1pad, wTc, va2_b, xpad2, tokbf, pos);

    // ---- depth branch ----
    convw_bf_k<<<(64 * 768 * 9 + 255) / 256, 256, 0, stream>>>(dg1w, dg1wT, 64, 768);
    mfma_dg1_k<<<256, 256, 0, stream>>>(xpad2, dg1wT, dg1b, d1pad);
    convw_bf_k<<<(32 * 64 * 9 + 255) / 256, 256, 0, stream>>>(dg2w, dg2wT, 32, 64);
    mfma_dg2_k<<<1024, 256, 0, stream>>>(d1pad, dg2wT, dg2b, d2);
    depth_k<<<(NB * 16384 + 255) / 256, 256, 0, stream>>>(d2, dg3w, dg3b, out + 1422400);

    // ---- token transpose (xpad2/bufB now dead; tokT overwrites it) ----
    tokT_k<<<dim3(24, 32, 32), dim3(32, 8), 0, stream>>>(tokbf, tokT);

    // ---- q init ----
    build_qa_k<<<(NB * 99 + 255) / 256, 256, 0, stream>>>(intent, past, qA);
    gemm(stream, 0, 0, qA, qi_w, qi_b, nullptr, q, NB, ND, 99);

    const int CB768  = (32 * 768 + 255) / 256;
    const int CB3072 = (32 * 3072 + 255) / 256;
    const int CB3000 = (32 * 3000 + 255) / 256;

    // ---- transformer layers ----
    for (int i = 0; i < NL; i++) {
        const size_t W = (size_t)i * ND * ND;
        ln_k<<<NB, 256, 0, stream>>>(q, ln1_g + i * ND, ln1_b + i * ND, qn, qnT);
        skinny_part_k<<<dim3(6, 16), 256, 0, stream>>>(qnT, wq + W, Pb, 768, 48);
        comb_k<0, 0><<<CB768, 256, 0, stream>>>(Pb, bq + i * ND, nullptr, Qp, nullptr, 768, 16);
        qw2_k<<<dim3(24, 16), 256, 0, stream>>>(Qp, wk + W, qwbf);
        scores_mfma_k<<<dim3(8, 32), 256, 0, stream>>>(tokbf, qwbf, sraw, attbf);
        softmax_row_k<<<NB * NKH, 256, 0, stream>>>(sraw, attbf);
        ctxT_mfma_k<<<dim3(6, 32), 256, 0, stream>>>(tokT, attbf, ctxf);
        ovp_k<<<NB * NKH, 128, 0, stream>>>(ctxf, wv + W, bv + i * ND, ob, obT);
        skinny_part_k<<<dim3(6, 16), 256, 0, stream>>>(obT, wo + W, Pb, 768, 48);
        comb_k<0, 1><<<CB768, 256, 0, stream>>>(Pb, bo + i * ND, q, q, nullptr, 768, 16);
        ln_k<<<NB, 256, 0, stream>>>(q, ln2_g + i * ND, ln2_b + i * ND, qn, qnT);
        skinny_part_k<<<dim3(24, 16), 256, 0, stream>>>(qnT, m1w + (size_t)i * ND * NMLP, Pb, 3072, 48);
        comb_k<1, 0><<<CB3072, 256, 0, stream>>>(Pb, m1b + i * NMLP, nullptr, hm, hmT, 3072, 16);
        skinny_part_k<<<dim3(6, 16), 256, 0, stream>>>(hmT, m2w + (size_t)i * NMLP * ND, Pb, 768, 192);
        comb_k<0, 1><<<CB768, 256, 0, stream>>>(Pb, m2b + i * ND, q, q,
                                                (i == NL - 1) ? qT : nullptr, 768, 16);
    }

    // ---- trajectory decoder ----
    skinny_part_k<<<dim3(6, 16), 256, 0, stream>>>(qT, td1w, Pb, 768, 48);
    comb_k<1, 0><<<CB768, 256, 0, stream>>>(Pb, td1b, nullptr, h1, h1T, 768, 16);
    skinny_part_k<<<dim3(6, 16), 256, 0, stream>>>(h1T, td2w, Pb, 768, 48);
    comb_k<1, 0><<<CB768, 256, 0, stream>>>(Pb, td2b, nullptr, h2, h2T, 768, 16);
    skinny_part_k<<<dim3(24, 16), 256, 0, stream>>>(h2T, td3w, Pb, 3000, 48);
    comb_k<0, 0><<<CB3000, 256, 0, stream>>>(Pb, td3b, nullptr, cp, nullptr, 3000, 16);
    integrate_k<<<(NB * NK + 255) / 256, 256, 0, stream>>>(cp, past, out);

    // ---- score head ----
    qscore_k<<<(NB * NK * ND + 255) / 256, 256, 0, stream>>>(q, out + 192000);
    gemm(stream, 1, 0, out, tf1w, tf1b, nullptr, tfa, NB * NK, ND, 60);
    f2bf_k<<<(1600 * 768 + 255) / 256, 256, 0, stream>>>(tfa, tfabf, 1600 * 768);
    wt_bf_k<<<dim3(24, 24), dim3(32, 8), 0, stream>>>(tf2w, tf2wT, 768, 768);
    mfma_gemm_k<0, 1, 2><<<dim3(6, 13), 256, 0, stream>>>(
        tfabf, tf2wT, tf2b, nullptr, tfbbf, nullptr, nullptr, 1600, 768, 768);
    cat_bf_k<<<(1664 * 1536 + 255) / 256, 256, 0, stream>>>(q, tfbbf, catbf);
    wt_bf_k<<<dim3(24, 48), dim3(32, 8), 0, stream>>>(sd1w, sd1wT, 1536, 768);
    mfma_gemm_k<0, 1, 2><<<dim3(6, 13), 256, 0, stream>>>(
        catbf, sd1wT, sd1b, nullptr, s1bf, nullptr, nullptr, 1600, 768, 1536);
    wt_bf_k<<<dim3(24, 24), dim3(32, 8), 0, stream>>>(sd2w, sd2wT, 768, 768);
    mfma_gemm_k<0, 1, 0><<<dim3(6, 13), 256, 0, stream>>>(
        s1bf, sd2wT, sd2b, s2, nullptr, nullptr, nullptr, 1600, 768, 768);
    score_k<<<(NB * NK + 3) / 4, 256, 0, stream>>>(s2, sd3w, sd3b, out + 1420800);
}